// Round 9
// baseline (592.014 us; speedup 1.0000x reference)
//
#include <hip/hip_runtime.h>
#include <hip/hip_bf16.h>

#define B 8
#define N 2048
#define BN (B*N)
#define KNBR 32
#define NKP 15
#define VCH 16   // n-chunks per batch in VLAD accumulation

__device__ __forceinline__ float lrelu(float x){ return x > 0.f ? x : 0.1f*x; }
__device__ __forceinline__ unsigned umin_(unsigned a, unsigned b){ return a < b ? a : b; }
__device__ __forceinline__ unsigned umax_(unsigned a, unsigned b){ return a < b ? b : a; }

// MFMA fragment types (per guide: short8 = 8 bf16 = 4 VGPRs)
typedef __attribute__((ext_vector_type(8))) short bf16x8;
typedef __attribute__((ext_vector_type(4))) float fx4;

__device__ __forceinline__ short bfr(float f){
    union { __hip_bfloat16 h; short s; } u;
    u.h = __float2bfloat16(f);
    return u.s;
}
__device__ __forceinline__ bf16x8 to_bf8(fx4 lo, fx4 hi){
    bf16x8 r;
    r[0]=bfr(lo.x); r[1]=bfr(lo.y); r[2]=bfr(lo.z); r[3]=bfr(lo.w);
    r[4]=bfr(hi.x); r[5]=bfr(hi.y); r[6]=bfr(hi.z); r[7]=bfr(hi.w);
    return r;
}

// ---------------------------------------------------------------------------
// Weight prep: WkT[n][k] = bf16(Wk[k][n])  (n<64, k<960)
__global__ __launch_bounds__(256) void k_prep_wkT(
    const float* __restrict__ wk, short* __restrict__ wkT)
{
    const int i = blockIdx.x * 256 + threadIdx.x;
    if (i < 64*960) {
        const int n = i / 960, k = i % 960;
        wkT[i] = bfr(wk[k*64 + n]);
    }
}
// WcatT[n][k] = bf16( k<64 ? W2[k][n] : Ws[k-64][n] )  (n<128, k<KC)
template<int KC>
__global__ __launch_bounds__(256) void k_prep_catT(
    const float* __restrict__ w2, const float* __restrict__ ws_, short* __restrict__ catT)
{
    const int i = blockIdx.x * 256 + threadIdx.x;
    if (i < 128*KC) {
        const int n = i / KC, k = i % KC;
        catT[i] = bfr(k < 64 ? w2[k*128 + n] : ws_[(k-64)*128 + n]);
    }
}

// ---------------------------------------------------------------------------
// Compaction: per batch, append unmasked point indices (order-free — each KNN
// query is independent & deterministic). Masked rows get idx = 0..31 (their
// KP weights are all zero downstream: dist(1e6-coord - nbr) >> extent).
__global__ __launch_bounds__(256) void k_compact(
    const int* __restrict__ m, int* __restrict__ compact, int* __restrict__ cnt,
    int* __restrict__ idx)
{
    const int p = blockIdx.x * 256 + threadIdx.x;
    const int b = p >> 11, n = p & (N-1);
    if (m[p] != 0) {
        #pragma unroll
        for (int k = 0; k < KNBR; k++) idx[(size_t)p*KNBR + k] = k;
    } else {
        const int pos = atomicAdd(&cnt[b], 1);
        compact[b*N + pos] = n;
    }
}

// ---------------------------------------------------------------------------
// PointNet: f = relu(relu(x@W1+b1)@W2+b2); emits coords4 = (masked xyz, sq).
__global__ __launch_bounds__(256) void k_pointnet(
    const float* __restrict__ x, const int* __restrict__ m,
    const float* __restrict__ w1, const float* __restrict__ b1,
    const float* __restrict__ w2, const float* __restrict__ b2,
    float* __restrict__ feat, float4* __restrict__ coords4)
{
    __shared__ float s_x[32][3];
    __shared__ __align__(16) float s_hT[64*40];
    const int tid = threadIdx.x;
    const int pbase = blockIdx.x * 32;
    if (tid < 32) {
        const int p = pbase + tid;
        const float x0 = x[p*3+0], x1v = x[p*3+1], x2v = x[p*3+2];
        s_x[tid][0] = x0; s_x[tid][1] = x1v; s_x[tid][2] = x2v;
        const bool mm = (m[p] != 0);
        const float cx = mm ? 1e6f : x0, cy = mm ? 1e6f : x1v, cz = mm ? 1e6f : x2v;
        coords4[p] = make_float4(cx, cy, cz, cx*cx + cy*cy + cz*cz);
    }
    __syncthreads();
    const int w = tid >> 6, c = tid & 63;
    const int pb = w * 8;
    {
        const float w10 = w1[c], w11 = w1[64+c], w12 = w1[128+c], bb = b1[c];
        #pragma unroll
        for (int pl = 0; pl < 8; pl++) {
            float s = bb;
            s = fmaf(s_x[pb+pl][0], w10, s);
            s = fmaf(s_x[pb+pl][1], w11, s);
            s = fmaf(s_x[pb+pl][2], w12, s);
            s_hT[c*40 + pb + pl] = fmaxf(s, 0.f);
        }
    }
    {
        float acc[8];
        const float bb = b2[c];
        #pragma unroll
        for (int pl = 0; pl < 8; pl++) acc[pl] = bb;
        for (int j = 0; j < 64; j++) {
            const float wv = w2[j*64 + c];
            const float4 h0 = *(const float4*)&s_hT[j*40 + pb];
            const float4 h1 = *(const float4*)&s_hT[j*40 + pb + 4];
            acc[0] = fmaf(h0.x, wv, acc[0]); acc[1] = fmaf(h0.y, wv, acc[1]);
            acc[2] = fmaf(h0.z, wv, acc[2]); acc[3] = fmaf(h0.w, wv, acc[3]);
            acc[4] = fmaf(h1.x, wv, acc[4]); acc[5] = fmaf(h1.y, wv, acc[5]);
            acc[6] = fmaf(h1.z, wv, acc[6]); acc[7] = fmaf(h1.w, wv, acc[7]);
        }
        #pragma unroll
        for (int pl = 0; pl < 8; pl++)
            feat[(size_t)(pbase + pb + pl)*64 + c] = fmaxf(acc[pl], 0.f);
    }
}

// ---------------------------------------------------------------------------
// KNN on COMPACTED unmasked queries. In-lane sorted runs + hypercube merge;
// final re-merge dropped (set semantics suffice — downstream is
// permutation-invariant; lanes 0-31 share identical post-merge ordering).
// 512 blocks per batch; blocks fully past cnt[b] exit before any barrier.
__global__ __launch_bounds__(256, 2) void k_knn(
    const float4* __restrict__ c4, const int* __restrict__ compact,
    const int* __restrict__ cnt, int* __restrict__ idx)
{
    const int b = blockIdx.x >> 9;
    const int slot0 = (blockIdx.x & 511) * 4;
    const int cn = cnt[b];
    if (slot0 >= cn) return;                 // uniform whole-block early exit
    __shared__ float4 s_c[N];
    const int tid = threadIdx.x;
    const int w = tid >> 6, lane = tid & 63;
    for (int i = tid; i < N; i += 256) s_c[i] = c4[(size_t)b*N + i];
    __syncthreads();
    const int slot = slot0 + w;
    const bool active = slot < cn;
    const int n = active ? compact[b*N + slot] : 0;
    const float4 me = s_c[n];

    unsigned A[32];
    #pragma unroll
    for (int j = 0; j < 32; j++) {
        const float4 s = s_c[j*64 + lane];
        float d2 = me.w + s.w - 2.f*(me.x*s.x + me.y*s.y + me.z*s.z);
        d2 = fmaxf(d2, 0.f);
        A[j] = (__float_as_uint(d2) & 0xFFFFF800u) | (unsigned)(j*64 + lane);
    }
    // in-lane bitonic sort ascending
    #pragma unroll
    for (int k = 2; k <= 32; k <<= 1) {
        #pragma unroll
        for (int j = k >> 1; j > 0; j >>= 1) {
            #pragma unroll
            for (int i = 0; i < 32; i++) {
                const int l = i ^ j;
                if (l > i) {
                    const unsigned lo = umin_(A[i], A[l]);
                    const unsigned hi = umax_(A[i], A[l]);
                    const bool up = ((i & k) == 0);
                    A[i] = up ? lo : hi;
                    A[l] = up ? hi : lo;
                }
            }
        }
    }
    // hypercube merge; rounds 0..4 re-merge for the next round, round 5 only
    // keeps the lowest-32 (order within lanes 0-31 identical; set is exact).
    #pragma unroll
    for (int r = 0; r < 6; r++) {
        const int mask = 1 << r;
        #pragma unroll
        for (int i = 0; i < 16; i++) {
            const unsigned t1 = (unsigned)__shfl_xor((int)A[31-i], mask, 64);
            const unsigned t2 = (unsigned)__shfl_xor((int)A[i],    mask, 64);
            A[i]    = umin_(A[i],    t1);
            A[31-i] = umin_(A[31-i], t2);
        }
        if (r < 5) {
            #pragma unroll
            for (int j = 16; j > 0; j >>= 1) {
                #pragma unroll
                for (int i = 0; i < 32; i++) {
                    const int l = i ^ j;
                    if (l > i) {
                        const unsigned lo = umin_(A[i], A[l]);
                        A[l] = umax_(A[i], A[l]);
                        A[i] = lo;
                    }
                }
            }
        }
    }
    // lanes 0-31 hold identical arrays; pick A[lane] via cndmask tree
    #pragma unroll
    for (int s = 16; s >= 1; s >>= 1) {
        #pragma unroll
        for (int i = 0; i < s; i++)
            A[i] = (lane & s) ? A[i+s] : A[i];
    }
    if (active && lane < 32)
        idx[(size_t)(b*N + n)*KNBR + lane] = (int)(A[0] & 0x7FFu);
}

// ---------------------------------------------------------------------------
// x1 = lrelu(feat @ W1) : [BN,CIN] -> [BN,64]. 32 points/block, 8/wave.
template<int CIN>
__global__ __launch_bounds__(256) void k_unary1(
    const float* __restrict__ feat, const float* __restrict__ w1,
    float* __restrict__ x1)
{
    __shared__ __align__(16) float s_fT[128*36 + 8];
    const int tid = threadIdx.x;
    const int pbase = blockIdx.x * 32;
    for (int i = tid; i < 32*CIN; i += 256) {
        const int p = i / CIN, j = i % CIN;
        s_fT[j*36 + p] = feat[(size_t)pbase*CIN + i];
    }
    __syncthreads();
    const int w = tid >> 6, c = tid & 63;
    const int pb = w * 8;
    float acc[8] = {0.f,0.f,0.f,0.f,0.f,0.f,0.f,0.f};
    for (int j = 0; j < CIN; j++) {
        const float wv = w1[j*64 + c];
        const float4 f0 = *(const float4*)&s_fT[j*36 + pb];
        const float4 f1 = *(const float4*)&s_fT[j*36 + pb + 4];
        acc[0] = fmaf(f0.x, wv, acc[0]); acc[1] = fmaf(f0.y, wv, acc[1]);
        acc[2] = fmaf(f0.z, wv, acc[2]); acc[3] = fmaf(f0.w, wv, acc[3]);
        acc[4] = fmaf(f1.x, wv, acc[4]); acc[5] = fmaf(f1.y, wv, acc[5]);
        acc[6] = fmaf(f1.z, wv, acc[6]); acc[7] = fmaf(f1.w, wv, acc[7]);
    }
    #pragma unroll
    for (int pl = 0; pl < 8; pl++)
        x1[(size_t)(pbase + pb + pl)*64 + c] = lrelu(acc[pl]);
}

// ---------------------------------------------------------------------------
// KPConv with MFMA phases 2+3 (round-8 verified).
template<int CIN>
__global__ __launch_bounds__(256) void k_kpconv(
    const float* __restrict__ x1, const float4* __restrict__ c4,
    const float* __restrict__ kp,
    const int* __restrict__ idx, const float* __restrict__ feat_in,
    const short* __restrict__ WkT, const short* __restrict__ WcatT,
    float* __restrict__ out)
{
    constexpr int KC = 64 + CIN;
    constexpr int FS = CIN + 4;
    __shared__ __align__(16) float smem[7712 + 3840];
    __shared__ int   s_idx[256];
    __shared__ float skp[48];
    float* s_agg   = smem;
    float* s_w     = smem + 7712;
    float* s_x2f   = smem + 7712;
    float* s_featf = smem + 7712 + 544;

    const int tid   = threadIdx.x;
    const int pbase = blockIdx.x * 8;
    const int brow  = pbase & ~(N-1);

    if (tid < NKP*3) skp[tid] = kp[tid];
    s_idx[tid] = idx[(size_t)pbase*KNBR + tid];
    __syncthreads();

    {
        const int pl = tid >> 5, k = tid & 31;
        const float4 cp = c4[pbase + pl];
        const float4 cn = c4[brow + s_idx[pl*KNBR + k]];
        const float dx = cn.x - cp.x, dy = cn.y - cp.y, dz = cn.z - cp.z;
        #pragma unroll
        for (int K = 0; K < NKP; K++) {
            const float ex = dx - skp[K*3+0], ey = dy - skp[K*3+1], ez = dz - skp[K*3+2];
            const float dist = sqrtf(ex*ex + ey*ey + ez*ez);
            s_w[pl*480 + K*32 + k] = fmaxf(0.f, 1.f - dist*2.f);
        }
    }
    __syncthreads();

    const int w = tid >> 6, lane = tid & 63;
    #pragma unroll
    for (int sub = 0; sub < 2; sub++) {
        const int pl = w*2 + sub;
        float ag[NKP];
        #pragma unroll
        for (int K = 0; K < NKP; K++) ag[K] = 0.f;
        const float* wp = &s_w[pl*480];
        for (int k = 0; k < KNBR; k++) {
            const float val = x1[(size_t)(brow + s_idx[pl*KNBR + k])*64 + lane];
            #pragma unroll
            for (int K = 0; K < NKP; K++) ag[K] = fmaf(wp[K*32 + k], val, ag[K]);
        }
        #pragma unroll
        for (int K = 0; K < NKP; K++) s_agg[pl*964 + K*64 + lane] = ag[K];
    }
    __syncthreads();

    for (int i = tid; i < 8*CIN; i += 256) {
        const int p = i / CIN, j = i % CIN;
        s_featf[p*FS + j] = feat_in[(size_t)pbase*CIN + i];
    }

    const int nlane = lane & 15, q = lane >> 4;
    {
        fx4 acc = {0.f,0.f,0.f,0.f};
        const float* arow = &s_agg[(nlane & 7)*964];
        const short* brw  = &WkT[(size_t)(w*16 + nlane)*960];
        for (int t = 0; t < 30; t++) {
            const int k0 = t*32 + q*8;
            const fx4 lo = *(const fx4*)&arow[k0];
            const fx4 hi = *(const fx4*)&arow[k0+4];
            const bf16x8 af = to_bf8(lo, hi);
            const bf16x8 bf = *(const bf16x8*)&brw[k0];
            acc = __builtin_amdgcn_mfma_f32_16x16x32_bf16(af, bf, acc, 0, 0, 0);
        }
        if (q < 2) {
            #pragma unroll
            for (int r = 0; r < 4; r++)
                s_x2f[(q*4+r)*68 + w*16 + nlane] = lrelu(acc[r]);
        }
    }
    __syncthreads();

    {
        fx4 acc0 = {0.f,0.f,0.f,0.f}, acc1 = {0.f,0.f,0.f,0.f};
        const short* b0r = &WcatT[(size_t)(w*32 + nlane)*KC];
        const short* b1r = &WcatT[(size_t)(w*32 + 16 + nlane)*KC];
        const int pt = nlane & 7;
        #pragma unroll
        for (int t = 0; t < KC/32; t++) {
            const int k0 = t*32 + q*8;
            const float* src = (t < 2) ? &s_x2f[pt*68 + k0] : &s_featf[pt*FS + (k0 - 64)];
            const fx4 lo = *(const fx4*)&src[0];
            const fx4 hi = *(const fx4*)&src[4];
            const bf16x8 af = to_bf8(lo, hi);
            const bf16x8 b0 = *(const bf16x8*)&b0r[k0];
            const bf16x8 b1 = *(const bf16x8*)&b1r[k0];
            acc0 = __builtin_amdgcn_mfma_f32_16x16x32_bf16(af, b0, acc0, 0, 0, 0);
            acc1 = __builtin_amdgcn_mfma_f32_16x16x32_bf16(af, b1, acc1, 0, 0, 0);
        }
        if (q < 2) {
            #pragma unroll
            for (int r = 0; r < 4; r++) {
                const size_t p = (size_t)(pbase + q*4 + r)*128;
                out[p + w*32 + nlane]      = lrelu(acc0[r]);
                out[p + w*32 + 16 + nlane] = lrelu(acc1[r]);
            }
        }
    }
}

// ---------------------------------------------------------------------------
__global__ __launch_bounds__(256) void k_vlad_a(
    const float* __restrict__ f, const float* __restrict__ wa,
    const int* __restrict__ m, float* __restrict__ a, float* __restrict__ sumA)
{
    __shared__ __align__(16) float s_fT[128*36 + 8];
    __shared__ float s_m[32];
    const int tid = threadIdx.x;
    const int pbase = blockIdx.x * 32;
    const int b = pbase >> 11;
    for (int i = tid; i < 32*128; i += 256) {
        const int p = i >> 7, j = i & 127;
        s_fT[j*36 + p] = f[(size_t)pbase*128 + i];
    }
    if (tid < 32) s_m[tid] = (m[pbase + tid] != 0) ? 0.f : 1.f;
    __syncthreads();
    const int w = tid >> 6, kc = tid & 63;
    const int pb = w * 8;
    float acc[8] = {0.f,0.f,0.f,0.f,0.f,0.f,0.f,0.f};
    for (int j = 0; j < 128; j++) {
        const float wv = wa[j*64 + kc];
        const float4 f0 = *(const float4*)&s_fT[j*36 + pb];
        const float4 f1 = *(const float4*)&s_fT[j*36 + pb + 4];
        acc[0] = fmaf(f0.x, wv, acc[0]); acc[1] = fmaf(f0.y, wv, acc[1]);
        acc[2] = fmaf(f0.z, wv, acc[2]); acc[3] = fmaf(f0.w, wv, acc[3]);
        acc[4] = fmaf(f1.x, wv, acc[4]); acc[5] = fmaf(f1.y, wv, acc[5]);
        acc[6] = fmaf(f1.z, wv, acc[6]); acc[7] = fmaf(f1.w, wv, acc[7]);
    }
    float part = 0.f;
    #pragma unroll
    for (int pl = 0; pl < 8; pl++) {
        float mx = acc[pl];
        #pragma unroll
        for (int off = 32; off > 0; off >>= 1) mx = fmaxf(mx, __shfl_xor(mx, off, 64));
        const float e = expf(acc[pl] - mx);
        float se = e;
        #pragma unroll
        for (int off = 32; off > 0; off >>= 1) se += __shfl_xor(se, off, 64);
        const float av = (e / se) * s_m[pb + pl];
        a[(size_t)(pbase + pb + pl)*64 + kc] = av;
        part += av;
    }
    atomicAdd(&sumA[b*64 + kc], part);
}

// ---------------------------------------------------------------------------
__global__ __launch_bounds__(256) void k_vlad_acc(
    const float* __restrict__ a, const float* __restrict__ f,
    float* __restrict__ vpart)
{
    __shared__ __align__(16) float s_a[32*64];
    __shared__ __align__(16) float s_f[32*128];
    const int b  = blockIdx.x >> 4;
    const int ch = blockIdx.x & 15;
    const int n0 = ch * (N / VCH);
    const int tid = threadIdx.x;
    const int kc0 = (tid >> 5) * 8;
    const int d0  = (tid & 31) * 4;
    float acc[8][4];
    #pragma unroll
    for (int i = 0; i < 8; i++)
        #pragma unroll
        for (int j = 0; j < 4; j++) acc[i][j] = 0.f;
    for (int t = 0; t < N/VCH; t += 32) {
        __syncthreads();
        const size_t base = (size_t)(b*N + n0 + t);
        for (int i = tid; i < 32*64; i += 256)  s_a[i] = a[(base << 6) + i];
        for (int i = tid; i < 32*128; i += 256) s_f[i] = f[(base << 7) + i];
        __syncthreads();
        for (int n = 0; n < 32; n++) {
            const float4 a0 = *(const float4*)&s_a[n*64 + kc0];
            const float4 a1 = *(const float4*)&s_a[n*64 + kc0 + 4];
            const float4 fv = *(const float4*)&s_f[n*128 + d0];
            const float av[8] = {a0.x,a0.y,a0.z,a0.w,a1.x,a1.y,a1.z,a1.w};
            const float fw[4] = {fv.x,fv.y,fv.z,fv.w};
            #pragma unroll
            for (int i = 0; i < 8; i++)
                #pragma unroll
                for (int j = 0; j < 4; j++) acc[i][j] = fmaf(av[i], fw[j], acc[i][j]);
        }
    }
    float* vp = vpart + ((size_t)ch*B + b)*8192;
    #pragma unroll
    for (int i = 0; i < 8; i++)
        #pragma unroll
        for (int j = 0; j < 4; j++) vp[(kc0+i)*128 + d0 + j] = acc[i][j];
}

// ---------------------------------------------------------------------------
__global__ __launch_bounds__(128) void k_vlad_norm(
    const float* __restrict__ vpart, const float* __restrict__ sumA,
    const float* __restrict__ centers, float* __restrict__ v)
{
    const int b = blockIdx.x >> 6, kc = blockIdx.x & 63, d = threadIdx.x;
    float acc = 0.f;
    #pragma unroll
    for (int c = 0; c < VCH; c++)
        acc += vpart[((size_t)c*B + b)*8192 + kc*128 + d];
    const float vv = acc - sumA[b*64 + kc] * centers[kc*128 + d];
    float s2 = vv*vv;
    #pragma unroll
    for (int off = 32; off > 0; off >>= 1) s2 += __shfl_xor(s2, off, 64);
    __shared__ float red[2];
    if ((d & 63) == 0) red[d >> 6] = s2;
    __syncthreads();
    const float tot = red[0] + red[1];
    v[((size_t)b*64 + kc)*128 + d] = vv / (sqrtf(tot) + 1e-8f);
}

__global__ __launch_bounds__(256) void k_vnorm(
    const float* __restrict__ v, float* __restrict__ scale)
{
    const int b = blockIdx.x;
    float s = 0.f;
    for (int i = threadIdx.x; i < 8192; i += 256) { const float t = v[(size_t)b*8192 + i]; s = fmaf(t, t, s); }
    #pragma unroll
    for (int off = 32; off > 0; off >>= 1) s += __shfl_xor(s, off, 64);
    __shared__ float red[4];
    if ((threadIdx.x & 63) == 0) red[threadIdx.x >> 6] = s;
    __syncthreads();
    if (threadIdx.x == 0) {
        const float tot = red[0] + red[1] + red[2] + red[3];
        scale[b] = 1.f / (sqrtf(tot) + 1e-8f);
    }
}

__global__ __launch_bounds__(256) void k_zero(float* __restrict__ p, int n)
{
    const int i = blockIdx.x * 256 + threadIdx.x;
    if (i < n) p[i] = 0.f;
}

__global__ __launch_bounds__(256) void k_proj(
    const float* __restrict__ v, const float* __restrict__ scale,
    const float* __restrict__ proj, float* __restrict__ outacc)
{
    __shared__ __align__(16) float s_v[8*256];
    __shared__ float s_sc[8];
    const int jc = blockIdx.x, o = threadIdx.x;
    const int j0 = jc * 256;
    for (int i = o; i < 8*256; i += 256) {
        const int bb = i >> 8, jj = i & 255;
        s_v[i] = v[(size_t)bb*8192 + j0 + jj];
    }
    if (o < 8) s_sc[o] = scale[o];
    __syncthreads();
    float acc[8] = {0.f,0.f,0.f,0.f,0.f,0.f,0.f,0.f};
    for (int jj = 0; jj < 256; jj += 4) {
        float pv[4];
        #pragma unroll
        for (int q = 0; q < 4; q++) pv[q] = proj[(size_t)(j0+jj+q)*256 + o];
        #pragma unroll
        for (int bb = 0; bb < 8; bb++) {
            const float4 vv = *(const float4*)&s_v[bb*256 + jj];
            acc[bb] = fmaf(vv.x, pv[0], acc[bb]);
            acc[bb] = fmaf(vv.y, pv[1], acc[bb]);
            acc[bb] = fmaf(vv.z, pv[2], acc[bb]);
            acc[bb] = fmaf(vv.w, pv[3], acc[bb]);
        }
    }
    #pragma unroll
    for (int bb = 0; bb < 8; bb++) atomicAdd(&outacc[bb*256 + o], acc[bb] * s_sc[bb]);
}

__global__ __launch_bounds__(256) void k_outnorm(
    const float* __restrict__ outacc, float* __restrict__ out)
{
    const int b = blockIdx.x, o = threadIdx.x;
    const float val = outacc[b*256 + o];
    float s = val*val;
    #pragma unroll
    for (int off = 32; off > 0; off >>= 1) s += __shfl_xor(s, off, 64);
    __shared__ float red[4];
    if ((o & 63) == 0) red[o >> 6] = s;
    __syncthreads();
    const float tot = red[0] + red[1] + red[2] + red[3];
    out[b*256 + o] = val / (sqrtf(tot) + 1e-12f);
}

// ---------------------------------------------------------------------------
extern "C" void kernel_launch(void* const* d_in, const int* in_sizes, int n_in,
                              void* d_out, int out_size, void* d_ws, size_t ws_size,
                              hipStream_t stream)
{
    (void)in_sizes; (void)n_in; (void)out_size; (void)ws_size;
    const float* x     = (const float*)d_in[0];
    const int*   m     = (const int*)  d_in[1];
    const float* pn_w1 = (const float*)d_in[2];
    const float* pn_b1 = (const float*)d_in[3];
    const float* pn_w2 = (const float*)d_in[4];
    const float* pn_b2 = (const float*)d_in[5];
    const float* kp    = (const float*)d_in[6];
    const float* bw1[3] = {(const float*)d_in[7],  (const float*)d_in[11], (const float*)d_in[15]};
    const float* bwk[3] = {(const float*)d_in[8],  (const float*)d_in[12], (const float*)d_in[16]};
    const float* bw2[3] = {(const float*)d_in[9],  (const float*)d_in[13], (const float*)d_in[17]};
    const float* bws[3] = {(const float*)d_in[10], (const float*)d_in[14], (const float*)d_in[18]};
    const float* vlad_wa      = (const float*)d_in[19];
    const float* vlad_centers = (const float*)d_in[20];
    const float* vlad_proj    = (const float*)d_in[21];
    float* out = (float*)d_out;

    char* ws = (char*)d_ws;
    size_t off = 0;
    auto alloc = [&](size_t bytes) -> void* {
        void* p = ws + off;
        off = (off + bytes + 255) & ~(size_t)255;
        return p;
    };
    float4* coords4 = (float4*)alloc((size_t)BN*16);
    float*  feat0   = (float*)alloc((size_t)BN*64*4);
    int*    idxb    = (int*)  alloc((size_t)BN*KNBR*4);
    float*  x1b     = (float*)alloc((size_t)BN*64*4);     // aliased by vpart later
    float*  fA      = (float*)alloc((size_t)BN*128*4);
    float*  fB      = (float*)alloc((size_t)BN*128*4);
    float*  abuf    = (float*)alloc((size_t)BN*64*4);
    float*  vbuf    = (float*)alloc((size_t)B*8192*4);
    float*  scaleb  = (float*)alloc((size_t)B*4);
    // sumA(512f)+outacc(2048f)+cnt(8i) contiguous (each 256B-aligned size) ->
    // zeroed by one k_zero of 2568 elements.
    float*  sumA    = (float*)alloc((size_t)B*64*4);
    float*  outacc  = (float*)alloc((size_t)B*256*4);
    int*    cntb    = (int*)  alloc((size_t)B*4);
    int*    compact = (int*)  alloc((size_t)BN*4);
    short*  wkT[3]  = {(short*)alloc(64*960*2), (short*)alloc(64*960*2), (short*)alloc(64*960*2)};
    short*  catT[3] = {(short*)alloc(128*192*2), (short*)alloc(128*192*2), (short*)alloc(128*192*2)};
    float*  vpart   = x1b;

    for (int l = 0; l < 3; l++)
        k_prep_wkT<<<(64*960 + 255)/256, 256, 0, stream>>>(bwk[l], wkT[l]);
    k_prep_catT<128><<<(128*128 + 255)/256, 256, 0, stream>>>(bw2[0], bws[0], catT[0]);
    k_prep_catT<192><<<(128*192 + 255)/256, 256, 0, stream>>>(bw2[1], bws[1], catT[1]);
    k_prep_catT<192><<<(128*192 + 255)/256, 256, 0, stream>>>(bw2[2], bws[2], catT[2]);

    k_zero<<<(B*64 + B*256 + B + 255)/256, 256, 0, stream>>>(sumA, B*64 + B*256 + B);
    k_compact<<<BN/256, 256, 0, stream>>>(m, compact, cntb, idxb);
    k_pointnet<<<BN/32, 256, 0, stream>>>(x, m, pn_w1, pn_b1, pn_w2, pn_b2, feat0, coords4);
    k_knn<<<B*512, 256, 0, stream>>>(coords4, compact, cntb, idxb);

    k_unary1<64> <<<BN/32, 256, 0, stream>>>(feat0, bw1[0], x1b);
    k_kpconv<64> <<<BN/8, 256, 0, stream>>>(x1b, coords4, kp, idxb, feat0, wkT[0], catT[0], fA);
    k_unary1<128><<<BN/32, 256, 0, stream>>>(fA, bw1[1], x1b);
    k_kpconv<128><<<BN/8, 256, 0, stream>>>(x1b, coords4, kp, idxb, fA, wkT[1], catT[1], fB);
    k_unary1<128><<<BN/32, 256, 0, stream>>>(fB, bw1[2], x1b);
    k_kpconv<128><<<BN/8, 256, 0, stream>>>(x1b, coords4, kp, idxb, fB, wkT[2], catT[2], fA);

    k_vlad_a<<<BN/32, 256, 0, stream>>>(fA, vlad_wa, m, abuf, sumA);
    k_vlad_acc<<<B*VCH, 256, 0, stream>>>(abuf, fA, vpart);
    k_vlad_norm<<<B*64, 128, 0, stream>>>(vpart, sumA, vlad_centers, vbuf);
    k_vnorm<<<B, 256, 0, stream>>>(vbuf, scaleb);
    k_proj<<<32, 256, 0, stream>>>(vbuf, scaleb, vlad_proj, outacc);
    k_outnorm<<<B, 256, 0, stream>>>(outacc, out);
}

// Round 10
// 499.407 us; speedup vs baseline: 1.1854x; 1.1854x over previous
//
#include <hip/hip_runtime.h>
#include <hip/hip_bf16.h>

#define B 8
#define N 2048
#define BN (B*N)
#define KNBR 32
#define NKP 15
#define VCH 16   // n-chunks per batch in VLAD accumulation

__device__ __forceinline__ float lrelu(float x){ return x > 0.f ? x : 0.1f*x; }
__device__ __forceinline__ unsigned umin_(unsigned a, unsigned b){ return a < b ? a : b; }
__device__ __forceinline__ unsigned umax_(unsigned a, unsigned b){ return a < b ? b : a; }

// MFMA fragment types (per guide: short8 = 8 bf16 = 4 VGPRs)
typedef __attribute__((ext_vector_type(8))) short bf16x8;
typedef __attribute__((ext_vector_type(4))) float fx4;

__device__ __forceinline__ short bfr(float f){
    union { __hip_bfloat16 h; short s; } u;
    u.h = __float2bfloat16(f);
    return u.s;
}
__device__ __forceinline__ bf16x8 to_bf8(fx4 lo, fx4 hi){
    bf16x8 r;
    r[0]=bfr(lo.x); r[1]=bfr(lo.y); r[2]=bfr(lo.z); r[3]=bfr(lo.w);
    r[4]=bfr(hi.x); r[5]=bfr(hi.y); r[6]=bfr(hi.z); r[7]=bfr(hi.w);
    return r;
}

// ---------------------------------------------------------------------------
// Weight prep: WkT[n][k] = bf16(Wk[k][n])  (n<64, k<960)
__global__ __launch_bounds__(256) void k_prep_wkT(
    const float* __restrict__ wk, short* __restrict__ wkT)
{
    const int i = blockIdx.x * 256 + threadIdx.x;
    if (i < 64*960) {
        const int n = i / 960, k = i % 960;
        wkT[i] = bfr(wk[k*64 + n]);
    }
}
// WcatT[n][k] = bf16( k<64 ? W2[k][n] : Ws[k-64][n] )  (n<128, k<KC)
template<int KC>
__global__ __launch_bounds__(256) void k_prep_catT(
    const float* __restrict__ w2, const float* __restrict__ ws_, short* __restrict__ catT)
{
    const int i = blockIdx.x * 256 + threadIdx.x;
    if (i < 128*KC) {
        const int n = i / KC, k = i % KC;
        catT[i] = bfr(k < 64 ? w2[k*128 + n] : ws_[(k-64)*128 + n]);
    }
}

// ---------------------------------------------------------------------------
// Compaction with WAVE-AGGREGATED atomics (round-9's per-lane atomicAdd to 8
// addresses serialized ~1024 deep -> 95 us). ballot -> one atomicAdd/wave ->
// prefix-popcount slots. Batch index is wave-uniform (blocks don't straddle
// batches). Masked rows get idx = 0..31 (their KP weights vanish downstream).
__global__ __launch_bounds__(256) void k_compact(
    const int* __restrict__ m, int* __restrict__ compact, int* __restrict__ cnt,
    int* __restrict__ idx)
{
    const int p = blockIdx.x * 256 + threadIdx.x;
    const int b = p >> 11, n = p & (N-1);
    const int lane = threadIdx.x & 63;
    const bool unm = (m[p] == 0);
    const unsigned long long mask = __ballot(unm);
    int base = 0;
    if (lane == 0) base = atomicAdd(&cnt[b], __popcll(mask));
    base = __shfl(base, 0, 64);
    if (unm) {
        const int pos = base + __popcll(mask & ((1ull << lane) - 1ull));
        compact[b*N + pos] = n;
    } else {
        #pragma unroll
        for (int k = 0; k < KNBR; k++) idx[(size_t)p*KNBR + k] = k;
    }
}

// ---------------------------------------------------------------------------
// PointNet: f = relu(relu(x@W1+b1)@W2+b2); emits coords4 = (masked xyz, sq).
__global__ __launch_bounds__(256) void k_pointnet(
    const float* __restrict__ x, const int* __restrict__ m,
    const float* __restrict__ w1, const float* __restrict__ b1,
    const float* __restrict__ w2, const float* __restrict__ b2,
    float* __restrict__ feat, float4* __restrict__ coords4)
{
    __shared__ float s_x[32][3];
    __shared__ __align__(16) float s_hT[64*40];
    const int tid = threadIdx.x;
    const int pbase = blockIdx.x * 32;
    if (tid < 32) {
        const int p = pbase + tid;
        const float x0 = x[p*3+0], x1v = x[p*3+1], x2v = x[p*3+2];
        s_x[tid][0] = x0; s_x[tid][1] = x1v; s_x[tid][2] = x2v;
        const bool mm = (m[p] != 0);
        const float cx = mm ? 1e6f : x0, cy = mm ? 1e6f : x1v, cz = mm ? 1e6f : x2v;
        coords4[p] = make_float4(cx, cy, cz, cx*cx + cy*cy + cz*cz);
    }
    __syncthreads();
    const int w = tid >> 6, c = tid & 63;
    const int pb = w * 8;
    {
        const float w10 = w1[c], w11 = w1[64+c], w12 = w1[128+c], bb = b1[c];
        #pragma unroll
        for (int pl = 0; pl < 8; pl++) {
            float s = bb;
            s = fmaf(s_x[pb+pl][0], w10, s);
            s = fmaf(s_x[pb+pl][1], w11, s);
            s = fmaf(s_x[pb+pl][2], w12, s);
            s_hT[c*40 + pb + pl] = fmaxf(s, 0.f);
        }
    }
    {
        float acc[8];
        const float bb = b2[c];
        #pragma unroll
        for (int pl = 0; pl < 8; pl++) acc[pl] = bb;
        for (int j = 0; j < 64; j++) {
            const float wv = w2[j*64 + c];
            const float4 h0 = *(const float4*)&s_hT[j*40 + pb];
            const float4 h1 = *(const float4*)&s_hT[j*40 + pb + 4];
            acc[0] = fmaf(h0.x, wv, acc[0]); acc[1] = fmaf(h0.y, wv, acc[1]);
            acc[2] = fmaf(h0.z, wv, acc[2]); acc[3] = fmaf(h0.w, wv, acc[3]);
            acc[4] = fmaf(h1.x, wv, acc[4]); acc[5] = fmaf(h1.y, wv, acc[5]);
            acc[6] = fmaf(h1.z, wv, acc[6]); acc[7] = fmaf(h1.w, wv, acc[7]);
        }
        #pragma unroll
        for (int pl = 0; pl < 8; pl++)
            feat[(size_t)(pbase + pb + pl)*64 + c] = fmaxf(acc[pl], 0.f);
    }
}

// ---------------------------------------------------------------------------
// KNN on COMPACTED unmasked queries (round-9 verified fast path).
__global__ __launch_bounds__(256, 2) void k_knn(
    const float4* __restrict__ c4, const int* __restrict__ compact,
    const int* __restrict__ cnt, int* __restrict__ idx)
{
    const int b = blockIdx.x >> 9;
    const int slot0 = (blockIdx.x & 511) * 4;
    const int cn = cnt[b];
    if (slot0 >= cn) return;                 // uniform whole-block early exit
    __shared__ float4 s_c[N];
    const int tid = threadIdx.x;
    const int w = tid >> 6, lane = tid & 63;
    for (int i = tid; i < N; i += 256) s_c[i] = c4[(size_t)b*N + i];
    __syncthreads();
    const int slot = slot0 + w;
    const bool active = slot < cn;
    const int n = active ? compact[b*N + slot] : 0;
    const float4 me = s_c[n];

    unsigned A[32];
    #pragma unroll
    for (int j = 0; j < 32; j++) {
        const float4 s = s_c[j*64 + lane];
        float d2 = me.w + s.w - 2.f*(me.x*s.x + me.y*s.y + me.z*s.z);
        d2 = fmaxf(d2, 0.f);
        A[j] = (__float_as_uint(d2) & 0xFFFFF800u) | (unsigned)(j*64 + lane);
    }
    #pragma unroll
    for (int k = 2; k <= 32; k <<= 1) {
        #pragma unroll
        for (int j = k >> 1; j > 0; j >>= 1) {
            #pragma unroll
            for (int i = 0; i < 32; i++) {
                const int l = i ^ j;
                if (l > i) {
                    const unsigned lo = umin_(A[i], A[l]);
                    const unsigned hi = umax_(A[i], A[l]);
                    const bool up = ((i & k) == 0);
                    A[i] = up ? lo : hi;
                    A[l] = up ? hi : lo;
                }
            }
        }
    }
    #pragma unroll
    for (int r = 0; r < 6; r++) {
        const int mask = 1 << r;
        #pragma unroll
        for (int i = 0; i < 16; i++) {
            const unsigned t1 = (unsigned)__shfl_xor((int)A[31-i], mask, 64);
            const unsigned t2 = (unsigned)__shfl_xor((int)A[i],    mask, 64);
            A[i]    = umin_(A[i],    t1);
            A[31-i] = umin_(A[31-i], t2);
        }
        if (r < 5) {
            #pragma unroll
            for (int j = 16; j > 0; j >>= 1) {
                #pragma unroll
                for (int i = 0; i < 32; i++) {
                    const int l = i ^ j;
                    if (l > i) {
                        const unsigned lo = umin_(A[i], A[l]);
                        A[l] = umax_(A[i], A[l]);
                        A[i] = lo;
                    }
                }
            }
        }
    }
    #pragma unroll
    for (int s = 16; s >= 1; s >>= 1) {
        #pragma unroll
        for (int i = 0; i < s; i++)
            A[i] = (lane & s) ? A[i+s] : A[i];
    }
    if (active && lane < 32)
        idx[(size_t)(b*N + n)*KNBR + lane] = (int)(A[0] & 0x7FFu);
}

// ---------------------------------------------------------------------------
// x1 = lrelu(feat @ W1) : [BN,CIN] -> [BN,64]. 32 points/block, 8/wave.
template<int CIN>
__global__ __launch_bounds__(256) void k_unary1(
    const float* __restrict__ feat, const float* __restrict__ w1,
    float* __restrict__ x1)
{
    __shared__ __align__(16) float s_fT[128*36 + 8];
    const int tid = threadIdx.x;
    const int pbase = blockIdx.x * 32;
    for (int i = tid; i < 32*CIN; i += 256) {
        const int p = i / CIN, j = i % CIN;
        s_fT[j*36 + p] = feat[(size_t)pbase*CIN + i];
    }
    __syncthreads();
    const int w = tid >> 6, c = tid & 63;
    const int pb = w * 8;
    float acc[8] = {0.f,0.f,0.f,0.f,0.f,0.f,0.f,0.f};
    for (int j = 0; j < CIN; j++) {
        const float wv = w1[j*64 + c];
        const float4 f0 = *(const float4*)&s_fT[j*36 + pb];
        const float4 f1 = *(const float4*)&s_fT[j*36 + pb + 4];
        acc[0] = fmaf(f0.x, wv, acc[0]); acc[1] = fmaf(f0.y, wv, acc[1]);
        acc[2] = fmaf(f0.z, wv, acc[2]); acc[3] = fmaf(f0.w, wv, acc[3]);
        acc[4] = fmaf(f1.x, wv, acc[4]); acc[5] = fmaf(f1.y, wv, acc[5]);
        acc[6] = fmaf(f1.z, wv, acc[6]); acc[7] = fmaf(f1.w, wv, acc[7]);
    }
    #pragma unroll
    for (int pl = 0; pl < 8; pl++)
        x1[(size_t)(pbase + pb + pl)*64 + c] = lrelu(acc[pl]);
}

// ---------------------------------------------------------------------------
// KPConv with MFMA phases 2+3 (round-8 verified).
template<int CIN>
__global__ __launch_bounds__(256) void k_kpconv(
    const float* __restrict__ x1, const float4* __restrict__ c4,
    const float* __restrict__ kp,
    const int* __restrict__ idx, const float* __restrict__ feat_in,
    const short* __restrict__ WkT, const short* __restrict__ WcatT,
    float* __restrict__ out)
{
    constexpr int KC = 64 + CIN;
    constexpr int FS = CIN + 4;
    __shared__ __align__(16) float smem[7712 + 3840];
    __shared__ int   s_idx[256];
    __shared__ float skp[48];
    float* s_agg   = smem;
    float* s_w     = smem + 7712;
    float* s_x2f   = smem + 7712;
    float* s_featf = smem + 7712 + 544;

    const int tid   = threadIdx.x;
    const int pbase = blockIdx.x * 8;
    const int brow  = pbase & ~(N-1);

    if (tid < NKP*3) skp[tid] = kp[tid];
    s_idx[tid] = idx[(size_t)pbase*KNBR + tid];
    __syncthreads();

    {
        const int pl = tid >> 5, k = tid & 31;
        const float4 cp = c4[pbase + pl];
        const float4 cn = c4[brow + s_idx[pl*KNBR + k]];
        const float dx = cn.x - cp.x, dy = cn.y - cp.y, dz = cn.z - cp.z;
        #pragma unroll
        for (int K = 0; K < NKP; K++) {
            const float ex = dx - skp[K*3+0], ey = dy - skp[K*3+1], ez = dz - skp[K*3+2];
            const float dist = sqrtf(ex*ex + ey*ey + ez*ez);
            s_w[pl*480 + K*32 + k] = fmaxf(0.f, 1.f - dist*2.f);
        }
    }
    __syncthreads();

    const int w = tid >> 6, lane = tid & 63;
    #pragma unroll
    for (int sub = 0; sub < 2; sub++) {
        const int pl = w*2 + sub;
        float ag[NKP];
        #pragma unroll
        for (int K = 0; K < NKP; K++) ag[K] = 0.f;
        const float* wp = &s_w[pl*480];
        for (int k = 0; k < KNBR; k++) {
            const float val = x1[(size_t)(brow + s_idx[pl*KNBR + k])*64 + lane];
            #pragma unroll
            for (int K = 0; K < NKP; K++) ag[K] = fmaf(wp[K*32 + k], val, ag[K]);
        }
        #pragma unroll
        for (int K = 0; K < NKP; K++) s_agg[pl*964 + K*64 + lane] = ag[K];
    }
    __syncthreads();

    for (int i = tid; i < 8*CIN; i += 256) {
        const int p = i / CIN, j = i % CIN;
        s_featf[p*FS + j] = feat_in[(size_t)pbase*CIN + i];
    }

    const int nlane = lane & 15, q = lane >> 4;
    {
        fx4 acc = {0.f,0.f,0.f,0.f};
        const float* arow = &s_agg[(nlane & 7)*964];
        const short* brw  = &WkT[(size_t)(w*16 + nlane)*960];
        for (int t = 0; t < 30; t++) {
            const int k0 = t*32 + q*8;
            const fx4 lo = *(const fx4*)&arow[k0];
            const fx4 hi = *(const fx4*)&arow[k0+4];
            const bf16x8 af = to_bf8(lo, hi);
            const bf16x8 bf = *(const bf16x8*)&brw[k0];
            acc = __builtin_amdgcn_mfma_f32_16x16x32_bf16(af, bf, acc, 0, 0, 0);
        }
        if (q < 2) {
            #pragma unroll
            for (int r = 0; r < 4; r++)
                s_x2f[(q*4+r)*68 + w*16 + nlane] = lrelu(acc[r]);
        }
    }
    __syncthreads();

    {
        fx4 acc0 = {0.f,0.f,0.f,0.f}, acc1 = {0.f,0.f,0.f,0.f};
        const short* b0r = &WcatT[(size_t)(w*32 + nlane)*KC];
        const short* b1r = &WcatT[(size_t)(w*32 + 16 + nlane)*KC];
        const int pt = nlane & 7;
        #pragma unroll
        for (int t = 0; t < KC/32; t++) {
            const int k0 = t*32 + q*8;
            const float* src = (t < 2) ? &s_x2f[pt*68 + k0] : &s_featf[pt*FS + (k0 - 64)];
            const fx4 lo = *(const fx4*)&src[0];
            const fx4 hi = *(const fx4*)&src[4];
            const bf16x8 af = to_bf8(lo, hi);
            const bf16x8 b0 = *(const bf16x8*)&b0r[k0];
            const bf16x8 b1 = *(const bf16x8*)&b1r[k0];
            acc0 = __builtin_amdgcn_mfma_f32_16x16x32_bf16(af, b0, acc0, 0, 0, 0);
            acc1 = __builtin_amdgcn_mfma_f32_16x16x32_bf16(af, b1, acc1, 0, 0, 0);
        }
        if (q < 2) {
            #pragma unroll
            for (int r = 0; r < 4; r++) {
                const size_t p = (size_t)(pbase + q*4 + r)*128;
                out[p + w*32 + nlane]      = lrelu(acc0[r]);
                out[p + w*32 + 16 + nlane] = lrelu(acc1[r]);
            }
        }
    }
}

// ---------------------------------------------------------------------------
__global__ __launch_bounds__(256) void k_vlad_a(
    const float* __restrict__ f, const float* __restrict__ wa,
    const int* __restrict__ m, float* __restrict__ a, float* __restrict__ sumA)
{
    __shared__ __align__(16) float s_fT[128*36 + 8];
    __shared__ float s_m[32];
    const int tid = threadIdx.x;
    const int pbase = blockIdx.x * 32;
    const int b = pbase >> 11;
    for (int i = tid; i < 32*128; i += 256) {
        const int p = i >> 7, j = i & 127;
        s_fT[j*36 + p] = f[(size_t)pbase*128 + i];
    }
    if (tid < 32) s_m[tid] = (m[pbase + tid] != 0) ? 0.f : 1.f;
    __syncthreads();
    const int w = tid >> 6, kc = tid & 63;
    const int pb = w * 8;
    float acc[8] = {0.f,0.f,0.f,0.f,0.f,0.f,0.f,0.f};
    for (int j = 0; j < 128; j++) {
        const float wv = wa[j*64 + kc];
        const float4 f0 = *(const float4*)&s_fT[j*36 + pb];
        const float4 f1 = *(const float4*)&s_fT[j*36 + pb + 4];
        acc[0] = fmaf(f0.x, wv, acc[0]); acc[1] = fmaf(f0.y, wv, acc[1]);
        acc[2] = fmaf(f0.z, wv, acc[2]); acc[3] = fmaf(f0.w, wv, acc[3]);
        acc[4] = fmaf(f1.x, wv, acc[4]); acc[5] = fmaf(f1.y, wv, acc[5]);
        acc[6] = fmaf(f1.z, wv, acc[6]); acc[7] = fmaf(f1.w, wv, acc[7]);
    }
    float part = 0.f;
    #pragma unroll
    for (int pl = 0; pl < 8; pl++) {
        float mx = acc[pl];
        #pragma unroll
        for (int off = 32; off > 0; off >>= 1) mx = fmaxf(mx, __shfl_xor(mx, off, 64));
        const float e = expf(acc[pl] - mx);
        float se = e;
        #pragma unroll
        for (int off = 32; off > 0; off >>= 1) se += __shfl_xor(se, off, 64);
        const float av = (e / se) * s_m[pb + pl];
        a[(size_t)(pbase + pb + pl)*64 + kc] = av;
        part += av;
    }
    atomicAdd(&sumA[b*64 + kc], part);
}

// ---------------------------------------------------------------------------
__global__ __launch_bounds__(256) void k_vlad_acc(
    const float* __restrict__ a, const float* __restrict__ f,
    float* __restrict__ vpart)
{
    __shared__ __align__(16) float s_a[32*64];
    __shared__ __align__(16) float s_f[32*128];
    const int b  = blockIdx.x >> 4;
    const int ch = blockIdx.x & 15;
    const int n0 = ch * (N / VCH);
    const int tid = threadIdx.x;
    const int kc0 = (tid >> 5) * 8;
    const int d0  = (tid & 31) * 4;
    float acc[8][4];
    #pragma unroll
    for (int i = 0; i < 8; i++)
        #pragma unroll
        for (int j = 0; j < 4; j++) acc[i][j] = 0.f;
    for (int t = 0; t < N/VCH; t += 32) {
        __syncthreads();
        const size_t base = (size_t)(b*N + n0 + t);
        for (int i = tid; i < 32*64; i += 256)  s_a[i] = a[(base << 6) + i];
        for (int i = tid; i < 32*128; i += 256) s_f[i] = f[(base << 7) + i];
        __syncthreads();
        for (int n = 0; n < 32; n++) {
            const float4 a0 = *(const float4*)&s_a[n*64 + kc0];
            const float4 a1 = *(const float4*)&s_a[n*64 + kc0 + 4];
            const float4 fv = *(const float4*)&s_f[n*128 + d0];
            const float av[8] = {a0.x,a0.y,a0.z,a0.w,a1.x,a1.y,a1.z,a1.w};
            const float fw[4] = {fv.x,fv.y,fv.z,fv.w};
            #pragma unroll
            for (int i = 0; i < 8; i++)
                #pragma unroll
                for (int j = 0; j < 4; j++) acc[i][j] = fmaf(av[i], fw[j], acc[i][j]);
        }
    }
    float* vp = vpart + ((size_t)ch*B + b)*8192;
    #pragma unroll
    for (int i = 0; i < 8; i++)
        #pragma unroll
        for (int j = 0; j < 4; j++) vp[(kc0+i)*128 + d0 + j] = acc[i][j];
}

// ---------------------------------------------------------------------------
__global__ __launch_bounds__(128) void k_vlad_norm(
    const float* __restrict__ vpart, const float* __restrict__ sumA,
    const float* __restrict__ centers, float* __restrict__ v)
{
    const int b = blockIdx.x >> 6, kc = blockIdx.x & 63, d = threadIdx.x;
    float acc = 0.f;
    #pragma unroll
    for (int c = 0; c < VCH; c++)
        acc += vpart[((size_t)c*B + b)*8192 + kc*128 + d];
    const float vv = acc - sumA[b*64 + kc] * centers[kc*128 + d];
    float s2 = vv*vv;
    #pragma unroll
    for (int off = 32; off > 0; off >>= 1) s2 += __shfl_xor(s2, off, 64);
    __shared__ float red[2];
    if ((d & 63) == 0) red[d >> 6] = s2;
    __syncthreads();
    const float tot = red[0] + red[1];
    v[((size_t)b*64 + kc)*128 + d] = vv / (sqrtf(tot) + 1e-8f);
}

__global__ __launch_bounds__(256) void k_vnorm(
    const float* __restrict__ v, float* __restrict__ scale)
{
    const int b = blockIdx.x;
    float s = 0.f;
    for (int i = threadIdx.x; i < 8192; i += 256) { const float t = v[(size_t)b*8192 + i]; s = fmaf(t, t, s); }
    #pragma unroll
    for (int off = 32; off > 0; off >>= 1) s += __shfl_xor(s, off, 64);
    __shared__ float red[4];
    if ((threadIdx.x & 63) == 0) red[threadIdx.x >> 6] = s;
    __syncthreads();
    if (threadIdx.x == 0) {
        const float tot = red[0] + red[1] + red[2] + red[3];
        scale[b] = 1.f / (sqrtf(tot) + 1e-8f);
    }
}

__global__ __launch_bounds__(256) void k_zero(float* __restrict__ p, int n)
{
    const int i = blockIdx.x * 256 + threadIdx.x;
    if (i < n) p[i] = 0.f;
}

__global__ __launch_bounds__(256) void k_proj(
    const float* __restrict__ v, const float* __restrict__ scale,
    const float* __restrict__ proj, float* __restrict__ outacc)
{
    __shared__ __align__(16) float s_v[8*256];
    __shared__ float s_sc[8];
    const int jc = blockIdx.x, o = threadIdx.x;
    const int j0 = jc * 256;
    for (int i = o; i < 8*256; i += 256) {
        const int bb = i >> 8, jj = i & 255;
        s_v[i] = v[(size_t)bb*8192 + j0 + jj];
    }
    if (o < 8) s_sc[o] = scale[o];
    __syncthreads();
    float acc[8] = {0.f,0.f,0.f,0.f,0.f,0.f,0.f,0.f};
    for (int jj = 0; jj < 256; jj += 4) {
        float pv[4];
        #pragma unroll
        for (int q = 0; q < 4; q++) pv[q] = proj[(size_t)(j0+jj+q)*256 + o];
        #pragma unroll
        for (int bb = 0; bb < 8; bb++) {
            const float4 vv = *(const float4*)&s_v[bb*256 + jj];
            acc[bb] = fmaf(vv.x, pv[0], acc[bb]);
            acc[bb] = fmaf(vv.y, pv[1], acc[bb]);
            acc[bb] = fmaf(vv.z, pv[2], acc[bb]);
            acc[bb] = fmaf(vv.w, pv[3], acc[bb]);
        }
    }
    #pragma unroll
    for (int bb = 0; bb < 8; bb++) atomicAdd(&outacc[bb*256 + o], acc[bb] * s_sc[bb]);
}

__global__ __launch_bounds__(256) void k_outnorm(
    const float* __restrict__ outacc, float* __restrict__ out)
{
    const int b = blockIdx.x, o = threadIdx.x;
    const float val = outacc[b*256 + o];
    float s = val*val;
    #pragma unroll
    for (int off = 32; off > 0; off >>= 1) s += __shfl_xor(s, off, 64);
    __shared__ float red[4];
    if ((o & 63) == 0) red[o >> 6] = s;
    __syncthreads();
    const float tot = red[0] + red[1] + red[2] + red[3];
    out[b*256 + o] = val / (sqrtf(tot) + 1e-12f);
}

// ---------------------------------------------------------------------------
extern "C" void kernel_launch(void* const* d_in, const int* in_sizes, int n_in,
                              void* d_out, int out_size, void* d_ws, size_t ws_size,
                              hipStream_t stream)
{
    (void)in_sizes; (void)n_in; (void)out_size; (void)ws_size;
    const float* x     = (const float*)d_in[0];
    const int*   m     = (const int*)  d_in[1];
    const float* pn_w1 = (const float*)d_in[2];
    const float* pn_b1 = (const float*)d_in[3];
    const float* pn_w2 = (const float*)d_in[4];
    const float* pn_b2 = (const float*)d_in[5];
    const float* kp    = (const float*)d_in[6];
    const float* bw1[3] = {(const float*)d_in[7],  (const float*)d_in[11], (const float*)d_in[15]};
    const float* bwk[3] = {(const float*)d_in[8],  (const float*)d_in[12], (const float*)d_in[16]};
    const float* bw2[3] = {(const float*)d_in[9],  (const float*)d_in[13], (const float*)d_in[17]};
    const float* bws[3] = {(const float*)d_in[10], (const float*)d_in[14], (const float*)d_in[18]};
    const float* vlad_wa      = (const float*)d_in[19];
    const float* vlad_centers = (const float*)d_in[20];
    const float* vlad_proj    = (const float*)d_in[21];
    float* out = (float*)d_out;

    char* ws = (char*)d_ws;
    size_t off = 0;
    auto alloc = [&](size_t bytes) -> void* {
        void* p = ws + off;
        off = (off + bytes + 255) & ~(size_t)255;
        return p;
    };
    float4* coords4 = (float4*)alloc((size_t)BN*16);
    float*  feat0   = (float*)alloc((size_t)BN*64*4);
    int*    idxb    = (int*)  alloc((size_t)BN*KNBR*4);
    float*  x1b     = (float*)alloc((size_t)BN*64*4);     // aliased by vpart later
    float*  fA      = (float*)alloc((size_t)BN*128*4);
    float*  fB      = (float*)alloc((size_t)BN*128*4);
    float*  abuf    = (float*)alloc((size_t)BN*64*4);
    float*  vbuf    = (float*)alloc((size_t)B*8192*4);
    float*  scaleb  = (float*)alloc((size_t)B*4);
    // sumA(512f)+outacc(2048f)+cnt(8i) contiguous (sizes multiples of 256B) ->
    // zeroed by one k_zero of 2568 elements.
    float*  sumA    = (float*)alloc((size_t)B*64*4);
    float*  outacc  = (float*)alloc((size_t)B*256*4);
    int*    cntb    = (int*)  alloc((size_t)B*4);
    int*    compact = (int*)  alloc((size_t)BN*4);
    short*  wkT[3]  = {(short*)alloc(64*960*2), (short*)alloc(64*960*2), (short*)alloc(64*960*2)};
    short*  catT[3] = {(short*)alloc(128*192*2), (short*)alloc(128*192*2), (short*)alloc(128*192*2)};
    float*  vpart   = x1b;

    for (int l = 0; l < 3; l++)
        k_prep_wkT<<<(64*960 + 255)/256, 256, 0, stream>>>(bwk[l], wkT[l]);
    k_prep_catT<128><<<(128*128 + 255)/256, 256, 0, stream>>>(bw2[0], bws[0], catT[0]);
    k_prep_catT<192><<<(128*192 + 255)/256, 256, 0, stream>>>(bw2[1], bws[1], catT[1]);
    k_prep_catT<192><<<(128*192 + 255)/256, 256, 0, stream>>>(bw2[2], bws[2], catT[2]);

    k_zero<<<(B*64 + B*256 + B + 255)/256, 256, 0, stream>>>(sumA, B*64 + B*256 + B);
    k_compact<<<BN/256, 256, 0, stream>>>(m, compact, cntb, idxb);
    k_pointnet<<<BN/32, 256, 0, stream>>>(x, m, pn_w1, pn_b1, pn_w2, pn_b2, feat0, coords4);
    k_knn<<<B*512, 256, 0, stream>>>(coords4, compact, cntb, idxb);

    k_unary1<64> <<<BN/32, 256, 0, stream>>>(feat0, bw1[0], x1b);
    k_kpconv<64> <<<BN/8, 256, 0, stream>>>(x1b, coords4, kp, idxb, feat0, wkT[0], catT[0], fA);
    k_unary1<128><<<BN/32, 256, 0, stream>>>(fA, bw1[1], x1b);
    k_kpconv<128><<<BN/8, 256, 0, stream>>>(x1b, coords4, kp, idxb, fA, wkT[1], catT[1], fB);
    k_unary1<128><<<BN/32, 256, 0, stream>>>(fB, bw1[2], x1b);
    k_kpconv<128><<<BN/8, 256, 0, stream>>>(x1b, coords4, kp, idxb, fB, wkT[2], catT[2], fA);

    k_vlad_a<<<BN/32, 256, 0, stream>>>(fA, vlad_wa, m, abuf, sumA);
    k_vlad_acc<<<B*VCH, 256, 0, stream>>>(abuf, fA, vpart);
    k_vlad_norm<<<B*64, 128, 0, stream>>>(vpart, sumA, vlad_centers, vbuf);
    k_vnorm<<<B, 256, 0, stream>>>(vbuf, scaleb);
    k_proj<<<32, 256, 0, stream>>>(vbuf, scaleb, vlad_proj, outacc);
    k_outnorm<<<B, 256, 0, stream>>>(outacc, out);
}

// Round 11
// 456.796 us; speedup vs baseline: 1.2960x; 1.0933x over previous
//
#include <hip/hip_runtime.h>
#include <hip/hip_bf16.h>

#define B 8
#define N 2048
#define BN (B*N)
#define KNBR 32
#define NKP 15
#define VCH 16   // n-chunks per batch in VLAD accumulation

__device__ __forceinline__ float lrelu(float x){ return x > 0.f ? x : 0.1f*x; }
__device__ __forceinline__ unsigned umin_(unsigned a, unsigned b){ return a < b ? a : b; }
__device__ __forceinline__ unsigned umax_(unsigned a, unsigned b){ return a < b ? b : a; }

// MFMA fragment types (per guide: short8 = 8 bf16 = 4 VGPRs)
typedef __attribute__((ext_vector_type(8))) short bf16x8;
typedef __attribute__((ext_vector_type(4))) float fx4;

__device__ __forceinline__ short bfr(float f){
    union { __hip_bfloat16 h; short s; } u;
    u.h = __float2bfloat16(f);
    return u.s;
}

// ---------------------------------------------------------------------------
// Weight prep: WkT[n][k] = bf16(Wk[k][n])  (n<64, k<960)
__global__ __launch_bounds__(256) void k_prep_wkT(
    const float* __restrict__ wk, short* __restrict__ wkT)
{
    const int i = blockIdx.x * 256 + threadIdx.x;
    if (i < 64*960) {
        const int n = i / 960, k = i % 960;
        wkT[i] = bfr(wk[k*64 + n]);
    }
}
// WcatT[n][k] = bf16( k<64 ? W2[k][n] : Ws[k-64][n] )  (n<128, k<KC)
template<int KC>
__global__ __launch_bounds__(256) void k_prep_catT(
    const float* __restrict__ w2, const float* __restrict__ ws_, short* __restrict__ catT)
{
    const int i = blockIdx.x * 256 + threadIdx.x;
    if (i < 128*KC) {
        const int n = i / KC, k = i % KC;
        catT[i] = bfr(k < 64 ? w2[k*128 + n] : ws_[(k-64)*128 + n]);
    }
}

// ---------------------------------------------------------------------------
// Compaction with wave-aggregated atomics (round-10 verified).
__global__ __launch_bounds__(256) void k_compact(
    const int* __restrict__ m, int* __restrict__ compact, int* __restrict__ cnt,
    int* __restrict__ idx)
{
    const int p = blockIdx.x * 256 + threadIdx.x;
    const int b = p >> 11, n = p & (N-1);
    const int lane = threadIdx.x & 63;
    const bool unm = (m[p] == 0);
    const unsigned long long mask = __ballot(unm);
    int base = 0;
    if (lane == 0) base = atomicAdd(&cnt[b], __popcll(mask));
    base = __shfl(base, 0, 64);
    if (unm) {
        const int pos = base + __popcll(mask & ((1ull << lane) - 1ull));
        compact[b*N + pos] = n;
    } else {
        #pragma unroll
        for (int k = 0; k < KNBR; k++) idx[(size_t)p*KNBR + k] = k;
    }
}

// ---------------------------------------------------------------------------
// PointNet: f = relu(relu(x@W1+b1)@W2+b2); emits coords4 = (masked xyz, sq).
__global__ __launch_bounds__(256) void k_pointnet(
    const float* __restrict__ x, const int* __restrict__ m,
    const float* __restrict__ w1, const float* __restrict__ b1,
    const float* __restrict__ w2, const float* __restrict__ b2,
    float* __restrict__ feat, float4* __restrict__ coords4)
{
    __shared__ float s_x[32][3];
    __shared__ __align__(16) float s_hT[64*40];
    const int tid = threadIdx.x;
    const int pbase = blockIdx.x * 32;
    if (tid < 32) {
        const int p = pbase + tid;
        const float x0 = x[p*3+0], x1v = x[p*3+1], x2v = x[p*3+2];
        s_x[tid][0] = x0; s_x[tid][1] = x1v; s_x[tid][2] = x2v;
        const bool mm = (m[p] != 0);
        const float cx = mm ? 1e6f : x0, cy = mm ? 1e6f : x1v, cz = mm ? 1e6f : x2v;
        coords4[p] = make_float4(cx, cy, cz, cx*cx + cy*cy + cz*cz);
    }
    __syncthreads();
    const int w = tid >> 6, c = tid & 63;
    const int pb = w * 8;
    {
        const float w10 = w1[c], w11 = w1[64+c], w12 = w1[128+c], bb = b1[c];
        #pragma unroll
        for (int pl = 0; pl < 8; pl++) {
            float s = bb;
            s = fmaf(s_x[pb+pl][0], w10, s);
            s = fmaf(s_x[pb+pl][1], w11, s);
            s = fmaf(s_x[pb+pl][2], w12, s);
            s_hT[c*40 + pb + pl] = fmaxf(s, 0.f);
        }
    }
    {
        float acc[8];
        const float bb = b2[c];
        #pragma unroll
        for (int pl = 0; pl < 8; pl++) acc[pl] = bb;
        for (int j = 0; j < 64; j++) {
            const float wv = w2[j*64 + c];
            const float4 h0 = *(const float4*)&s_hT[j*40 + pb];
            const float4 h1 = *(const float4*)&s_hT[j*40 + pb + 4];
            acc[0] = fmaf(h0.x, wv, acc[0]); acc[1] = fmaf(h0.y, wv, acc[1]);
            acc[2] = fmaf(h0.z, wv, acc[2]); acc[3] = fmaf(h0.w, wv, acc[3]);
            acc[4] = fmaf(h1.x, wv, acc[4]); acc[5] = fmaf(h1.y, wv, acc[5]);
            acc[6] = fmaf(h1.z, wv, acc[6]); acc[7] = fmaf(h1.w, wv, acc[7]);
        }
        #pragma unroll
        for (int pl = 0; pl < 8; pl++)
            feat[(size_t)(pbase + pb + pl)*64 + c] = fmaxf(acc[pl], 0.f);
    }
}

// ---------------------------------------------------------------------------
// KNN on COMPACTED unmasked queries (round-9 verified fast path).
__global__ __launch_bounds__(256, 2) void k_knn(
    const float4* __restrict__ c4, const int* __restrict__ compact,
    const int* __restrict__ cnt, int* __restrict__ idx)
{
    const int b = blockIdx.x >> 9;
    const int slot0 = (blockIdx.x & 511) * 4;
    const int cn = cnt[b];
    if (slot0 >= cn) return;                 // uniform whole-block early exit
    __shared__ float4 s_c[N];
    const int tid = threadIdx.x;
    const int w = tid >> 6, lane = tid & 63;
    for (int i = tid; i < N; i += 256) s_c[i] = c4[(size_t)b*N + i];
    __syncthreads();
    const int slot = slot0 + w;
    const bool active = slot < cn;
    const int n = active ? compact[b*N + slot] : 0;
    const float4 me = s_c[n];

    unsigned A[32];
    #pragma unroll
    for (int j = 0; j < 32; j++) {
        const float4 s = s_c[j*64 + lane];
        float d2 = me.w + s.w - 2.f*(me.x*s.x + me.y*s.y + me.z*s.z);
        d2 = fmaxf(d2, 0.f);
        A[j] = (__float_as_uint(d2) & 0xFFFFF800u) | (unsigned)(j*64 + lane);
    }
    #pragma unroll
    for (int k = 2; k <= 32; k <<= 1) {
        #pragma unroll
        for (int j = k >> 1; j > 0; j >>= 1) {
            #pragma unroll
            for (int i = 0; i < 32; i++) {
                const int l = i ^ j;
                if (l > i) {
                    const unsigned lo = umin_(A[i], A[l]);
                    const unsigned hi = umax_(A[i], A[l]);
                    const bool up = ((i & k) == 0);
                    A[i] = up ? lo : hi;
                    A[l] = up ? hi : lo;
                }
            }
        }
    }
    #pragma unroll
    for (int r = 0; r < 6; r++) {
        const int mask = 1 << r;
        #pragma unroll
        for (int i = 0; i < 16; i++) {
            const unsigned t1 = (unsigned)__shfl_xor((int)A[31-i], mask, 64);
            const unsigned t2 = (unsigned)__shfl_xor((int)A[i],    mask, 64);
            A[i]    = umin_(A[i],    t1);
            A[31-i] = umin_(A[31-i], t2);
        }
        if (r < 5) {
            #pragma unroll
            for (int j = 16; j > 0; j >>= 1) {
                #pragma unroll
                for (int i = 0; i < 32; i++) {
                    const int l = i ^ j;
                    if (l > i) {
                        const unsigned lo = umin_(A[i], A[l]);
                        A[l] = umax_(A[i], A[l]);
                        A[i] = lo;
                    }
                }
            }
        }
    }
    #pragma unroll
    for (int s = 16; s >= 1; s >>= 1) {
        #pragma unroll
        for (int i = 0; i < s; i++)
            A[i] = (lane & s) ? A[i+s] : A[i];
    }
    if (active && lane < 32)
        idx[(size_t)(b*N + n)*KNBR + lane] = (int)(A[0] & 0x7FFu);
}

// ---------------------------------------------------------------------------
// x1 = lrelu(feat @ W1) : [BN,CIN] -> [BN,64]. 32 points/block, 8/wave.
template<int CIN>
__global__ __launch_bounds__(256) void k_unary1(
    const float* __restrict__ feat, const float* __restrict__ w1,
    float* __restrict__ x1)
{
    __shared__ __align__(16) float s_fT[128*36 + 8];
    const int tid = threadIdx.x;
    const int pbase = blockIdx.x * 32;
    for (int i = tid; i < 32*CIN; i += 256) {
        const int p = i / CIN, j = i % CIN;
        s_fT[j*36 + p] = feat[(size_t)pbase*CIN + i];
    }
    __syncthreads();
    const int w = tid >> 6, c = tid & 63;
    const int pb = w * 8;
    float acc[8] = {0.f,0.f,0.f,0.f,0.f,0.f,0.f,0.f};
    for (int j = 0; j < CIN; j++) {
        const float wv = w1[j*64 + c];
        const float4 f0 = *(const float4*)&s_fT[j*36 + pb];
        const float4 f1 = *(const float4*)&s_fT[j*36 + pb + 4];
        acc[0] = fmaf(f0.x, wv, acc[0]); acc[1] = fmaf(f0.y, wv, acc[1]);
        acc[2] = fmaf(f0.z, wv, acc[2]); acc[3] = fmaf(f0.w, wv, acc[3]);
        acc[4] = fmaf(f1.x, wv, acc[4]); acc[5] = fmaf(f1.y, wv, acc[5]);
        acc[6] = fmaf(f1.z, wv, acc[6]); acc[7] = fmaf(f1.w, wv, acc[7]);
    }
    #pragma unroll
    for (int pl = 0; pl < 8; pl++)
        x1[(size_t)(pbase + pb + pl)*64 + c] = lrelu(acc[pl]);
}

// ---------------------------------------------------------------------------
// KPConv with MFMA phases 2+3; A-operands stored in LDS as bf16 ONCE
// (round-10's f32 staging forced each of the 4 waves to re-convert the same
// values -> ~290 scalar cvts/lane + 2x LDS bytes). LDS ~33 KB -> 4 blocks/CU.
template<int CIN>
__global__ __launch_bounds__(256) void k_kpconv(
    const float* __restrict__ x1, const float4* __restrict__ c4,
    const float* __restrict__ kp,
    const int* __restrict__ idx, const float* __restrict__ feat_in,
    const short* __restrict__ WkT, const short* __restrict__ WcatT,
    float* __restrict__ out)
{
    constexpr int KC = 64 + CIN;   // phase-3 K extent
    constexpr int AS = 976;        // agg row stride (shorts); 976*2B, 16B-mult
    constexpr int XS = 72;         // x2 row stride (shorts); 144B
    constexpr int FS = CIN + 8;    // feat row stride (shorts); 144/272B
    __shared__ __align__(16) short s_aggT[8*AS];   // 15616B, bf16 A-operand
    __shared__ __align__(16) float s_w[8*480];     // 15360B union region
    __shared__ int   s_idx[256];
    __shared__ float skp[48];
    short* s_x2bf   = (short*)s_w;                 // [8*XS] = 1152B (ph2->3)
    short* s_featbf = (short*)s_w + 8*XS;          // [8*FS] <= 2176B (ph2->3)

    const int tid   = threadIdx.x;
    const int pbase = blockIdx.x * 8;
    const int brow  = pbase & ~(N-1);

    if (tid < NKP*3) skp[tid] = kp[tid];
    s_idx[tid] = idx[(size_t)pbase*KNBR + tid];
    __syncthreads();

    // phase 0: kp influence weights (tid -> pl=tid>>5, k=tid&31)
    {
        const int pl = tid >> 5, k = tid & 31;
        const float4 cp = c4[pbase + pl];
        const float4 cn = c4[brow + s_idx[pl*KNBR + k]];
        const float dx = cn.x - cp.x, dy = cn.y - cp.y, dz = cn.z - cp.z;
        #pragma unroll
        for (int K = 0; K < NKP; K++) {
            const float ex = dx - skp[K*3+0], ey = dy - skp[K*3+1], ez = dz - skp[K*3+2];
            const float dist = sqrtf(ex*ex + ey*ey + ez*ez);
            s_w[pl*480 + K*32 + k] = fmaxf(0.f, 1.f - dist*2.f);
        }
    }
    __syncthreads();

    const int w = tid >> 6, lane = tid & 63;
    // phase 1: neighbor aggregation; agg written to LDS as bf16 (once)
    #pragma unroll
    for (int sub = 0; sub < 2; sub++) {
        const int pl = w*2 + sub;
        float ag[NKP];
        #pragma unroll
        for (int K = 0; K < NKP; K++) ag[K] = 0.f;
        const float* wp = &s_w[pl*480];
        for (int k = 0; k < KNBR; k++) {
            const float val = x1[(size_t)(brow + s_idx[pl*KNBR + k])*64 + lane];
            #pragma unroll
            for (int K = 0; K < NKP; K++) ag[K] = fmaf(wp[K*32 + k], val, ag[K]);
        }
        #pragma unroll
        for (int K = 0; K < NKP; K++) s_aggT[pl*AS + K*64 + lane] = bfr(ag[K]);
    }
    __syncthreads();   // s_w dead; union region becomes x2bf/featbf

    // stage feat as bf16 (converted once here, not per-wave in phase 3)
    for (int i = tid; i < 8*CIN; i += 256) {
        const int p = i / CIN, j = i % CIN;
        s_featbf[p*FS + j] = bfr(feat_in[(size_t)pbase*CIN + i]);
    }

    const int nlane = lane & 15, q = lane >> 4;
    // phase 2: x2 = lrelu(agg @ Wk) via MFMA; A read directly as bf16x8.
    {
        fx4 acc = {0.f,0.f,0.f,0.f};
        const short* arow = &s_aggT[(nlane & 7)*AS];
        const short* brw  = &WkT[(size_t)(w*16 + nlane)*960];
        for (int t = 0; t < 30; t++) {
            const int k0 = t*32 + q*8;
            const bf16x8 af = *(const bf16x8*)&arow[k0];
            const bf16x8 bf = *(const bf16x8*)&brw[k0];
            acc = __builtin_amdgcn_mfma_f32_16x16x32_bf16(af, bf, acc, 0, 0, 0);
        }
        if (q < 2) {           // rows 8-15 are duplicates of 0-7
            #pragma unroll
            for (int r = 0; r < 4; r++)
                s_x2bf[(q*4+r)*XS + w*16 + nlane] = bfr(lrelu(acc[r]));
        }
    }
    __syncthreads();

    // phase 3: out = lrelu([x2|feat] @ [W2;Ws]) via MFMA; bf16 A-reads.
    {
        fx4 acc0 = {0.f,0.f,0.f,0.f}, acc1 = {0.f,0.f,0.f,0.f};
        const short* b0r = &WcatT[(size_t)(w*32 + nlane)*KC];
        const short* b1r = &WcatT[(size_t)(w*32 + 16 + nlane)*KC];
        const int pt = nlane & 7;
        const short* xrow = &s_x2bf[pt*XS];
        const short* frow = &s_featbf[pt*FS];
        #pragma unroll
        for (int t = 0; t < KC/32; t++) {
            const int k0 = t*32 + q*8;
            const short* src = (t < 2) ? &xrow[k0] : &frow[k0 - 64];
            const bf16x8 af = *(const bf16x8*)src;
            const bf16x8 b0 = *(const bf16x8*)&b0r[k0];
            const bf16x8 b1 = *(const bf16x8*)&b1r[k0];
            acc0 = __builtin_amdgcn_mfma_f32_16x16x32_bf16(af, b0, acc0, 0, 0, 0);
            acc1 = __builtin_amdgcn_mfma_f32_16x16x32_bf16(af, b1, acc1, 0, 0, 0);
        }
        if (q < 2) {
            #pragma unroll
            for (int r = 0; r < 4; r++) {
                const size_t p = (size_t)(pbase + q*4 + r)*128;
                out[p + w*32 + nlane]      = lrelu(acc0[r]);
                out[p + w*32 + 16 + nlane] = lrelu(acc1[r]);
            }
        }
    }
}

// ---------------------------------------------------------------------------
__global__ __launch_bounds__(256) void k_vlad_a(
    const float* __restrict__ f, const float* __restrict__ wa,
    const int* __restrict__ m, float* __restrict__ a, float* __restrict__ sumA)
{
    __shared__ __align__(16) float s_fT[128*36 + 8];
    __shared__ float s_m[32];
    const int tid = threadIdx.x;
    const int pbase = blockIdx.x * 32;
    const int b = pbase >> 11;
    for (int i = tid; i < 32*128; i += 256) {
        const int p = i >> 7, j = i & 127;
        s_fT[j*36 + p] = f[(size_t)pbase*128 + i];
    }
    if (tid < 32) s_m[tid] = (m[pbase + tid] != 0) ? 0.f : 1.f;
    __syncthreads();
    const int w = tid >> 6, kc = tid & 63;
    const int pb = w * 8;
    float acc[8] = {0.f,0.f,0.f,0.f,0.f,0.f,0.f,0.f};
    for (int j = 0; j < 128; j++) {
        const float wv = wa[j*64 + kc];
        const float4 f0 = *(const float4*)&s_fT[j*36 + pb];
        const float4 f1 = *(const float4*)&s_fT[j*36 + pb + 4];
        acc[0] = fmaf(f0.x, wv, acc[0]); acc[1] = fmaf(f0.y, wv, acc[1]);
        acc[2] = fmaf(f0.z, wv, acc[2]); acc[3] = fmaf(f0.w, wv, acc[3]);
        acc[4] = fmaf(f1.x, wv, acc[4]); acc[5] = fmaf(f1.y, wv, acc[5]);
        acc[6] = fmaf(f1.z, wv, acc[6]); acc[7] = fmaf(f1.w, wv, acc[7]);
    }
    float part = 0.f;
    #pragma unroll
    for (int pl = 0; pl < 8; pl++) {
        float mx = acc[pl];
        #pragma unroll
        for (int off = 32; off > 0; off >>= 1) mx = fmaxf(mx, __shfl_xor(mx, off, 64));
        const float e = expf(acc[pl] - mx);
        float se = e;
        #pragma unroll
        for (int off = 32; off > 0; off >>= 1) se += __shfl_xor(se, off, 64);
        const float av = (e / se) * s_m[pb + pl];
        a[(size_t)(pbase + pb + pl)*64 + kc] = av;
        part += av;
    }
    atomicAdd(&sumA[b*64 + kc], part);
}

// ---------------------------------------------------------------------------
__global__ __launch_bounds__(256) void k_vlad_acc(
    const float* __restrict__ a, const float* __restrict__ f,
    float* __restrict__ vpart)
{
    __shared__ __align__(16) float s_a[32*64];
    __shared__ __align__(16) float s_f[32*128];
    const int b  = blockIdx.x >> 4;
    const int ch = blockIdx.x & 15;
    const int n0 = ch * (N / VCH);
    const int tid = threadIdx.x;
    const int kc0 = (tid >> 5) * 8;
    const int d0  = (tid & 31) * 4;
    float acc[8][4];
    #pragma unroll
    for (int i = 0; i < 8; i++)
        #pragma unroll
        for (int j = 0; j < 4; j++) acc[i][j] = 0.f;
    for (int t = 0; t < N/VCH; t += 32) {
        __syncthreads();
        const size_t base = (size_t)(b*N + n0 + t);
        for (int i = tid; i < 32*64; i += 256)  s_a[i] = a[(base << 6) + i];
        for (int i = tid; i < 32*128; i += 256) s_f[i] = f[(base << 7) + i];
        __syncthreads();
        for (int n = 0; n < 32; n++) {
            const float4 a0 = *(const float4*)&s_a[n*64 + kc0];
            const float4 a1 = *(const float4*)&s_a[n*64 + kc0 + 4];
            const float4 fv = *(const float4*)&s_f[n*128 + d0];
            const float av[8] = {a0.x,a0.y,a0.z,a0.w,a1.x,a1.y,a1.z,a1.w};
            const float fw[4] = {fv.x,fv.y,fv.z,fv.w};
            #pragma unroll
            for (int i = 0; i < 8; i++)
                #pragma unroll
                for (int j = 0; j < 4; j++) acc[i][j] = fmaf(av[i], fw[j], acc[i][j]);
        }
    }
    float* vp = vpart + ((size_t)ch*B + b)*8192;
    #pragma unroll
    for (int i = 0; i < 8; i++)
        #pragma unroll
        for (int j = 0; j < 4; j++) vp[(kc0+i)*128 + d0 + j] = acc[i][j];
}

// ---------------------------------------------------------------------------
__global__ __launch_bounds__(128) void k_vlad_norm(
    const float* __restrict__ vpart, const float* __restrict__ sumA,
    const float* __restrict__ centers, float* __restrict__ v)
{
    const int b = blockIdx.x >> 6, kc = blockIdx.x & 63, d = threadIdx.x;
    float acc = 0.f;
    #pragma unroll
    for (int c = 0; c < VCH; c++)
        acc += vpart[((size_t)c*B + b)*8192 + kc*128 + d];
    const float vv = acc - sumA[b*64 + kc] * centers[kc*128 + d];
    float s2 = vv*vv;
    #pragma unroll
    for (int off = 32; off > 0; off >>= 1) s2 += __shfl_xor(s2, off, 64);
    __shared__ float red[2];
    if ((d & 63) == 0) red[d >> 6] = s2;
    __syncthreads();
    const float tot = red[0] + red[1];
    v[((size_t)b*64 + kc)*128 + d] = vv / (sqrtf(tot) + 1e-8f);
}

__global__ __launch_bounds__(256) void k_vnorm(
    const float* __restrict__ v, float* __restrict__ scale)
{
    const int b = blockIdx.x;
    float s = 0.f;
    for (int i = threadIdx.x; i < 8192; i += 256) { const float t = v[(size_t)b*8192 + i]; s = fmaf(t, t, s); }
    #pragma unroll
    for (int off = 32; off > 0; off >>= 1) s += __shfl_xor(s, off, 64);
    __shared__ float red[4];
    if ((threadIdx.x & 63) == 0) red[threadIdx.x >> 6] = s;
    __syncthreads();
    if (threadIdx.x == 0) {
        const float tot = red[0] + red[1] + red[2] + red[3];
        scale[b] = 1.f / (sqrtf(tot) + 1e-8f);
    }
}

__global__ __launch_bounds__(256) void k_zero(float* __restrict__ p, int n)
{
    const int i = blockIdx.x * 256 + threadIdx.x;
    if (i < n) p[i] = 0.f;
}

__global__ __launch_bounds__(256) void k_proj(
    const float* __restrict__ v, const float* __restrict__ scale,
    const float* __restrict__ proj, float* __restrict__ outacc)
{
    __shared__ __align__(16) float s_v[8*256];
    __shared__ float s_sc[8];
    const int jc = blockIdx.x, o = threadIdx.x;
    const int j0 = jc * 256;
    for (int i = o; i < 8*256; i += 256) {
        const int bb = i >> 8, jj = i & 255;
        s_v[i] = v[(size_t)bb*8192 + j0 + jj];
    }
    if (o < 8) s_sc[o] = scale[o];
    __syncthreads();
    float acc[8] = {0.f,0.f,0.f,0.f,0.f,0.f,0.f,0.f};
    for (int jj = 0; jj < 256; jj += 4) {
        float pv[4];
        #pragma unroll
        for (int q = 0; q < 4; q++) pv[q] = proj[(size_t)(j0+jj+q)*256 + o];
        #pragma unroll
        for (int bb = 0; bb < 8; bb++) {
            const float4 vv = *(const float4*)&s_v[bb*256 + jj];
            acc[bb] = fmaf(vv.x, pv[0], acc[bb]);
            acc[bb] = fmaf(vv.y, pv[1], acc[bb]);
            acc[bb] = fmaf(vv.z, pv[2], acc[bb]);
            acc[bb] = fmaf(vv.w, pv[3], acc[bb]);
        }
    }
    #pragma unroll
    for (int bb = 0; bb < 8; bb++) atomicAdd(&outacc[bb*256 + o], acc[bb] * s_sc[bb]);
}

__global__ __launch_bounds__(256) void k_outnorm(
    const float* __restrict__ outacc, float* __restrict__ out)
{
    const int b = blockIdx.x, o = threadIdx.x;
    const float val = outacc[b*256 + o];
    float s = val*val;
    #pragma unroll
    for (int off = 32; off > 0; off >>= 1) s += __shfl_xor(s, off, 64);
    __shared__ float red[4];
    if ((o & 63) == 0) red[o >> 6] = s;
    __syncthreads();
    const float tot = red[0] + red[1] + red[2] + red[3];
    out[b*256 + o] = val / (sqrtf(tot) + 1e-12f);
}

// ---------------------------------------------------------------------------
extern "C" void kernel_launch(void* const* d_in, const int* in_sizes, int n_in,
                              void* d_out, int out_size, void* d_ws, size_t ws_size,
                              hipStream_t stream)
{
    (void)in_sizes; (void)n_in; (void)out_size; (void)ws_size;
    const float* x     = (const float*)d_in[0];
    const int*   m     = (const int*)  d_in[1];
    const float* pn_w1 = (const float*)d_in[2];
    const float* pn_b1 = (const float*)d_in[3];
    const float* pn_w2 = (const float*)d_in[4];
    const float* pn_b2 = (const float*)d_in[5];
    const float* kp    = (const float*)d_in[6];
    const float* bw1[3] = {(const float*)d_in[7],  (const float*)d_in[11], (const float*)d_in[15]};
    const float* bwk[3] = {(const float*)d_in[8],  (const float*)d_in[12], (const float*)d_in[16]};
    const float* bw2[3] = {(const float*)d_in[9],  (const float*)d_in[13], (const float*)d_in[17]};
    const float* bws[3] = {(const float*)d_in[10], (const float*)d_in[14], (const float*)d_in[18]};
    const float* vlad_wa      = (const float*)d_in[19];
    const float* vlad_centers = (const float*)d_in[20];
    const float* vlad_proj    = (const float*)d_in[21];
    float* out = (float*)d_out;

    char* ws = (char*)d_ws;
    size_t off = 0;
    auto alloc = [&](size_t bytes) -> void* {
        void* p = ws + off;
        off = (off + bytes + 255) & ~(size_t)255;
        return p;
    };
    float4* coords4 = (float4*)alloc((size_t)BN*16);
    float*  feat0   = (float*)alloc((size_t)BN*64*4);
    int*    idxb    = (int*)  alloc((size_t)BN*KNBR*4);
    float*  x1b     = (float*)alloc((size_t)BN*64*4);     // aliased by vpart later
    float*  fA      = (float*)alloc((size_t)BN*128*4);
    float*  fB      = (float*)alloc((size_t)BN*128*4);
    float*  abuf    = (float*)alloc((size_t)BN*64*4);
    float*  vbuf    = (float*)alloc((size_t)B*8192*4);
    float*  scaleb  = (float*)alloc((size_t)B*4);
    // sumA(512f)+outacc(2048f)+cnt(8i) contiguous (sizes multiples of 256B) ->
    // zeroed by one k_zero of 2568 elements.
    float*  sumA    = (float*)alloc((size_t)B*64*4);
    float*  outacc  = (float*)alloc((size_t)B*256*4);
    int*    cntb    = (int*)  alloc((size_t)B*4);
    int*    compact = (int*)  alloc((size_t)BN*4);
    short*  wkT[3]  = {(short*)alloc(64*960*2), (short*)alloc(64*960*2), (short*)alloc(64*960*2)};
    short*  catT[3] = {(short*)alloc(128*192*2), (short*)alloc(128*192*2), (short*)alloc(128*192*2)};
    float*  vpart   = x1b;

    for (int l = 0; l < 3; l++)
        k_prep_wkT<<<(64*960 + 255)/256, 256, 0, stream>>>(bwk[l], wkT[l]);
    k_prep_catT<128><<<(128*128 + 255)/256, 256, 0, stream>>>(bw2[0], bws[0], catT[0]);
    k_prep_catT<192><<<(128*192 + 255)/256, 256, 0, stream>>>(bw2[1], bws[1], catT[1]);
    k_prep_catT<192><<<(128*192 + 255)/256, 256, 0, stream>>>(bw2[2], bws[2], catT[2]);

    k_zero<<<(B*64 + B*256 + B + 255)/256, 256, 0, stream>>>(sumA, B*64 + B*256 + B);
    k_compact<<<BN/256, 256, 0, stream>>>(m, compact, cntb, idxb);
    k_pointnet<<<BN/32, 256, 0, stream>>>(x, m, pn_w1, pn_b1, pn_w2, pn_b2, feat0, coords4);
    k_knn<<<B*512, 256, 0, stream>>>(coords4, compact, cntb, idxb);

    k_unary1<64> <<<BN/32, 256, 0, stream>>>(feat0, bw1[0], x1b);
    k_kpconv<64> <<<BN/8, 256, 0, stream>>>(x1b, coords4, kp, idxb, feat0, wkT[0], catT[0], fA);
    k_unary1<128><<<BN/32, 256, 0, stream>>>(fA, bw1[1], x1b);
    k_kpconv<128><<<BN/8, 256, 0, stream>>>(x1b, coords4, kp, idxb, fA, wkT[1], catT[1], fB);
    k_unary1<128><<<BN/32, 256, 0, stream>>>(fB, bw1[2], x1b);
    k_kpconv<128><<<BN/8, 256, 0, stream>>>(x1b, coords4, kp, idxb, fB, wkT[2], catT[2], fA);

    k_vlad_a<<<BN/32, 256, 0, stream>>>(fA, vlad_wa, m, abuf, sumA);
    k_vlad_acc<<<B*VCH, 256, 0, stream>>>(abuf, fA, vpart);
    k_vlad_norm<<<B*64, 128, 0, stream>>>(vpart, sumA, vlad_centers, vbuf);
    k_vnorm<<<B, 256, 0, stream>>>(vbuf, scaleb);
    k_proj<<<32, 256, 0, stream>>>(vbuf, scaleb, vlad_proj, outacc);
    k_outnorm<<<B, 256, 0, stream>>>(outacc, out);
}

// Round 12
// 451.500 us; speedup vs baseline: 1.3112x; 1.0117x over previous
//
#include <hip/hip_runtime.h>
#include <hip/hip_bf16.h>

#define B 8
#define N 2048
#define BN (B*N)
#define KNBR 32
#define NKP 15
#define VCH 16   // n-chunks per batch in VLAD accumulation

__device__ __forceinline__ float lrelu(float x){ return x > 0.f ? x : 0.1f*x; }
__device__ __forceinline__ unsigned umin_(unsigned a, unsigned b){ return __builtin_elementwise_min(a, b); }
__device__ __forceinline__ unsigned umax_(unsigned a, unsigned b){ return __builtin_elementwise_max(a, b); }

// MFMA fragment types (per guide: short8 = 8 bf16 = 4 VGPRs)
typedef __attribute__((ext_vector_type(8))) short bf16x8;
typedef __attribute__((ext_vector_type(4))) float fx4;

__device__ __forceinline__ short bfr(float f){
    union { __hip_bfloat16 h; short s; } u;
    u.h = __float2bfloat16(f);
    return u.s;
}

// ---------------------------------------------------------------------------
// Fused weight prep (was 6 launches): 3x wkT + 3x catT.
// wkT[n][k] = bf16(Wk[k][n]) (n<64,k<960); catT[n][k] = bf16(k<64?W2[k][n]:Ws[k-64][n])
__global__ __launch_bounds__(256) void k_prep(
    const float* __restrict__ wk0, const float* __restrict__ wk1, const float* __restrict__ wk2,
    const float* __restrict__ w20, const float* __restrict__ ws0,
    const float* __restrict__ w21, const float* __restrict__ ws1,
    const float* __restrict__ w22, const float* __restrict__ ws2,
    short* __restrict__ wkT0, short* __restrict__ wkT1, short* __restrict__ wkT2,
    short* __restrict__ cat0, short* __restrict__ cat1, short* __restrict__ cat2)
{
    const int i = blockIdx.x * 256 + threadIdx.x;
    if (i < 3*61440) {
        const int l = i / 61440, r = i % 61440;
        const int n = r / 960, k = r % 960;
        const float* wk = (l == 0) ? wk0 : (l == 1) ? wk1 : wk2;
        short* dst = (l == 0) ? wkT0 : (l == 1) ? wkT1 : wkT2;
        dst[r] = bfr(wk[k*64 + n]);
    } else {
        int j = i - 3*61440;
        if (j < 16384) {                       // catT0, KC=128
            const int n = j / 128, k = j % 128;
            cat0[j] = bfr(k < 64 ? w20[k*128 + n] : ws0[(k-64)*128 + n]);
        } else if (j < 16384 + 24576) {        // catT1, KC=192
            j -= 16384;
            const int n = j / 192, k = j % 192;
            cat1[j] = bfr(k < 64 ? w21[k*128 + n] : ws1[(k-64)*128 + n]);
        } else if (j < 16384 + 49152) {        // catT2, KC=192
            j -= 16384 + 24576;
            const int n = j / 192, k = j % 192;
            cat2[j] = bfr(k < 64 ? w22[k*128 + n] : ws2[(k-64)*128 + n]);
        }
    }
}

// ---------------------------------------------------------------------------
// Compaction with wave-aggregated atomics (round-10 verified).
__global__ __launch_bounds__(256) void k_compact(
    const int* __restrict__ m, int* __restrict__ compact, int* __restrict__ cnt,
    int* __restrict__ idx)
{
    const int p = blockIdx.x * 256 + threadIdx.x;
    const int b = p >> 11, n = p & (N-1);
    const int lane = threadIdx.x & 63;
    const bool unm = (m[p] == 0);
    const unsigned long long mask = __ballot(unm);
    int base = 0;
    if (lane == 0) base = atomicAdd(&cnt[b], __popcll(mask));
    base = __shfl(base, 0, 64);
    if (unm) {
        const int pos = base + __popcll(mask & ((1ull << lane) - 1ull));
        compact[b*N + pos] = n;
    } else {
        #pragma unroll
        for (int k = 0; k < KNBR; k++) idx[(size_t)p*KNBR + k] = k;
    }
}

// ---------------------------------------------------------------------------
// PointNet: f = relu(relu(x@W1+b1)@W2+b2); emits coords4 = (masked xyz, sq).
__global__ __launch_bounds__(256) void k_pointnet(
    const float* __restrict__ x, const int* __restrict__ m,
    const float* __restrict__ w1, const float* __restrict__ b1,
    const float* __restrict__ w2, const float* __restrict__ b2,
    float* __restrict__ feat, float4* __restrict__ coords4)
{
    __shared__ float s_x[32][3];
    __shared__ __align__(16) float s_hT[64*40];
    const int tid = threadIdx.x;
    const int pbase = blockIdx.x * 32;
    if (tid < 32) {
        const int p = pbase + tid;
        const float x0 = x[p*3+0], x1v = x[p*3+1], x2v = x[p*3+2];
        s_x[tid][0] = x0; s_x[tid][1] = x1v; s_x[tid][2] = x2v;
        const bool mm = (m[p] != 0);
        const float cx = mm ? 1e6f : x0, cy = mm ? 1e6f : x1v, cz = mm ? 1e6f : x2v;
        coords4[p] = make_float4(cx, cy, cz, cx*cx + cy*cy + cz*cz);
    }
    __syncthreads();
    const int w = tid >> 6, c = tid & 63;
    const int pb = w * 8;
    {
        const float w10 = w1[c], w11 = w1[64+c], w12 = w1[128+c], bb = b1[c];
        #pragma unroll
        for (int pl = 0; pl < 8; pl++) {
            float s = bb;
            s = fmaf(s_x[pb+pl][0], w10, s);
            s = fmaf(s_x[pb+pl][1], w11, s);
            s = fmaf(s_x[pb+pl][2], w12, s);
            s_hT[c*40 + pb + pl] = fmaxf(s, 0.f);
        }
    }
    {
        float acc[8];
        const float bb = b2[c];
        #pragma unroll
        for (int pl = 0; pl < 8; pl++) acc[pl] = bb;
        for (int j = 0; j < 64; j++) {
            const float wv = w2[j*64 + c];
            const float4 h0 = *(const float4*)&s_hT[j*40 + pb];
            const float4 h1 = *(const float4*)&s_hT[j*40 + pb + 4];
            acc[0] = fmaf(h0.x, wv, acc[0]); acc[1] = fmaf(h0.y, wv, acc[1]);
            acc[2] = fmaf(h0.z, wv, acc[2]); acc[3] = fmaf(h0.w, wv, acc[3]);
            acc[4] = fmaf(h1.x, wv, acc[4]); acc[5] = fmaf(h1.y, wv, acc[5]);
            acc[6] = fmaf(h1.z, wv, acc[6]); acc[7] = fmaf(h1.w, wv, acc[7]);
        }
        #pragma unroll
        for (int pl = 0; pl < 8; pl++)
            feat[(size_t)(pbase + pb + pl)*64 + c] = fmaxf(acc[pl], 0.f);
    }
}

// ---------------------------------------------------------------------------
// KNN on compacted queries. 512-thread blocks = 8 query-waves sharing ONE
// 32 KB coordinate stage (round-11's 4 waves/stage gave only 10 waves/CU —
// latency-starved). Same per-wave algorithm (round-9 verified).
__global__ __launch_bounds__(512) void k_knn(
    const float4* __restrict__ c4, const int* __restrict__ compact,
    const int* __restrict__ cnt, int* __restrict__ idx)
{
    const int b = blockIdx.x >> 8;
    const int slot0 = (blockIdx.x & 255) * 8;
    const int cn = cnt[b];
    if (slot0 >= cn) return;                 // uniform whole-block early exit
    __shared__ float4 s_c[N];
    const int tid = threadIdx.x;
    const int w = tid >> 6, lane = tid & 63;
    for (int i = tid; i < N; i += 512) s_c[i] = c4[(size_t)b*N + i];
    __syncthreads();
    const int slot = slot0 + w;
    const bool active = slot < cn;
    const int n = active ? compact[b*N + slot] : 0;
    const float4 me = s_c[n];

    unsigned A[32];
    #pragma unroll
    for (int j = 0; j < 32; j++) {
        const float4 s = s_c[j*64 + lane];
        float d2 = me.w + s.w - 2.f*(me.x*s.x + me.y*s.y + me.z*s.z);
        d2 = fmaxf(d2, 0.f);
        A[j] = (__float_as_uint(d2) & 0xFFFFF800u) | (unsigned)(j*64 + lane);
    }
    // in-lane bitonic sort ascending
    #pragma unroll
    for (int k = 2; k <= 32; k <<= 1) {
        #pragma unroll
        for (int j = k >> 1; j > 0; j >>= 1) {
            #pragma unroll
            for (int i = 0; i < 32; i++) {
                const int l = i ^ j;
                if (l > i) {
                    const unsigned lo = umin_(A[i], A[l]);
                    const unsigned hi = umax_(A[i], A[l]);
                    const bool up = ((i & k) == 0);
                    A[i] = up ? lo : hi;
                    A[l] = up ? hi : lo;
                }
            }
        }
    }
    // hypercube merge; last round keeps lowest-32 only (set semantics)
    #pragma unroll
    for (int r = 0; r < 6; r++) {
        const int mask = 1 << r;
        #pragma unroll
        for (int i = 0; i < 16; i++) {
            const unsigned t1 = (unsigned)__shfl_xor((int)A[31-i], mask, 64);
            const unsigned t2 = (unsigned)__shfl_xor((int)A[i],    mask, 64);
            A[i]    = umin_(A[i],    t1);
            A[31-i] = umin_(A[31-i], t2);
        }
        if (r < 5) {
            #pragma unroll
            for (int j = 16; j > 0; j >>= 1) {
                #pragma unroll
                for (int i = 0; i < 32; i++) {
                    const int l = i ^ j;
                    if (l > i) {
                        const unsigned lo = umin_(A[i], A[l]);
                        A[l] = umax_(A[i], A[l]);
                        A[i] = lo;
                    }
                }
            }
        }
    }
    // lanes 0-31 hold identical sets; pick A[lane] via cndmask tree
    #pragma unroll
    for (int s = 16; s >= 1; s >>= 1) {
        #pragma unroll
        for (int i = 0; i < s; i++)
            A[i] = (lane & s) ? A[i+s] : A[i];
    }
    if (active && lane < 32)
        idx[(size_t)(b*N + n)*KNBR + lane] = (int)(A[0] & 0x7FFu);
}

// ---------------------------------------------------------------------------
// x1 = lrelu(feat @ W1) : [BN,CIN] -> [BN,64]. 32 points/block, 8/wave.
template<int CIN>
__global__ __launch_bounds__(256) void k_unary1(
    const float* __restrict__ feat, const float* __restrict__ w1,
    float* __restrict__ x1)
{
    __shared__ __align__(16) float s_fT[128*36 + 8];
    const int tid = threadIdx.x;
    const int pbase = blockIdx.x * 32;
    for (int i = tid; i < 32*CIN; i += 256) {
        const int p = i / CIN, j = i % CIN;
        s_fT[j*36 + p] = feat[(size_t)pbase*CIN + i];
    }
    __syncthreads();
    const int w = tid >> 6, c = tid & 63;
    const int pb = w * 8;
    float acc[8] = {0.f,0.f,0.f,0.f,0.f,0.f,0.f,0.f};
    for (int j = 0; j < CIN; j++) {
        const float wv = w1[j*64 + c];
        const float4 f0 = *(const float4*)&s_fT[j*36 + pb];
        const float4 f1 = *(const float4*)&s_fT[j*36 + pb + 4];
        acc[0] = fmaf(f0.x, wv, acc[0]); acc[1] = fmaf(f0.y, wv, acc[1]);
        acc[2] = fmaf(f0.z, wv, acc[2]); acc[3] = fmaf(f0.w, wv, acc[3]);
        acc[4] = fmaf(f1.x, wv, acc[4]); acc[5] = fmaf(f1.y, wv, acc[5]);
        acc[6] = fmaf(f1.z, wv, acc[6]); acc[7] = fmaf(f1.w, wv, acc[7]);
    }
    #pragma unroll
    for (int pl = 0; pl < 8; pl++)
        x1[(size_t)(pbase + pb + pl)*64 + c] = lrelu(acc[pl]);
}

// ---------------------------------------------------------------------------
// KPConv with MFMA phases 2+3; bf16 A-operands in LDS (round-11 verified).
template<int CIN>
__global__ __launch_bounds__(256) void k_kpconv(
    const float* __restrict__ x1, const float4* __restrict__ c4,
    const float* __restrict__ kp,
    const int* __restrict__ idx, const float* __restrict__ feat_in,
    const short* __restrict__ WkT, const short* __restrict__ WcatT,
    float* __restrict__ out)
{
    constexpr int KC = 64 + CIN;
    constexpr int AS = 976;
    constexpr int XS = 72;
    constexpr int FS = CIN + 8;
    __shared__ __align__(16) short s_aggT[8*AS];
    __shared__ __align__(16) float s_w[8*480];
    __shared__ int   s_idx[256];
    __shared__ float skp[48];
    short* s_x2bf   = (short*)s_w;
    short* s_featbf = (short*)s_w + 8*XS;

    const int tid   = threadIdx.x;
    const int pbase = blockIdx.x * 8;
    const int brow  = pbase & ~(N-1);

    if (tid < NKP*3) skp[tid] = kp[tid];
    s_idx[tid] = idx[(size_t)pbase*KNBR + tid];
    __syncthreads();

    {
        const int pl = tid >> 5, k = tid & 31;
        const float4 cp = c4[pbase + pl];
        const float4 cn = c4[brow + s_idx[pl*KNBR + k]];
        const float dx = cn.x - cp.x, dy = cn.y - cp.y, dz = cn.z - cp.z;
        #pragma unroll
        for (int K = 0; K < NKP; K++) {
            const float ex = dx - skp[K*3+0], ey = dy - skp[K*3+1], ez = dz - skp[K*3+2];
            const float dist = sqrtf(ex*ex + ey*ey + ez*ez);
            s_w[pl*480 + K*32 + k] = fmaxf(0.f, 1.f - dist*2.f);
        }
    }
    __syncthreads();

    const int w = tid >> 6, lane = tid & 63;
    #pragma unroll
    for (int sub = 0; sub < 2; sub++) {
        const int pl = w*2 + sub;
        float ag[NKP];
        #pragma unroll
        for (int K = 0; K < NKP; K++) ag[K] = 0.f;
        const float* wp = &s_w[pl*480];
        for (int k = 0; k < KNBR; k++) {
            const float val = x1[(size_t)(brow + s_idx[pl*KNBR + k])*64 + lane];
            #pragma unroll
            for (int K = 0; K < NKP; K++) ag[K] = fmaf(wp[K*32 + k], val, ag[K]);
        }
        #pragma unroll
        for (int K = 0; K < NKP; K++) s_aggT[pl*AS + K*64 + lane] = bfr(ag[K]);
    }
    __syncthreads();

    for (int i = tid; i < 8*CIN; i += 256) {
        const int p = i / CIN, j = i % CIN;
        s_featbf[p*FS + j] = bfr(feat_in[(size_t)pbase*CIN + i]);
    }

    const int nlane = lane & 15, q = lane >> 4;
    {
        fx4 acc = {0.f,0.f,0.f,0.f};
        const short* arow = &s_aggT[(nlane & 7)*AS];
        const short* brw  = &WkT[(size_t)(w*16 + nlane)*960];
        for (int t = 0; t < 30; t++) {
            const int k0 = t*32 + q*8;
            const bf16x8 af = *(const bf16x8*)&arow[k0];
            const bf16x8 bf = *(const bf16x8*)&brw[k0];
            acc = __builtin_amdgcn_mfma_f32_16x16x32_bf16(af, bf, acc, 0, 0, 0);
        }
        if (q < 2) {
            #pragma unroll
            for (int r = 0; r < 4; r++)
                s_x2bf[(q*4+r)*XS + w*16 + nlane] = bfr(lrelu(acc[r]));
        }
    }
    __syncthreads();

    {
        fx4 acc0 = {0.f,0.f,0.f,0.f}, acc1 = {0.f,0.f,0.f,0.f};
        const short* b0r = &WcatT[(size_t)(w*32 + nlane)*KC];
        const short* b1r = &WcatT[(size_t)(w*32 + 16 + nlane)*KC];
        const int pt = nlane & 7;
        const short* xrow = &s_x2bf[pt*XS];
        const short* frow = &s_featbf[pt*FS];
        #pragma unroll
        for (int t = 0; t < KC/32; t++) {
            const int k0 = t*32 + q*8;
            const short* src = (t < 2) ? &xrow[k0] : &frow[k0 - 64];
            const bf16x8 af = *(const bf16x8*)src;
            const bf16x8 b0 = *(const bf16x8*)&b0r[k0];
            const bf16x8 b1 = *(const bf16x8*)&b1r[k0];
            acc0 = __builtin_amdgcn_mfma_f32_16x16x32_bf16(af, b0, acc0, 0, 0, 0);
            acc1 = __builtin_amdgcn_mfma_f32_16x16x32_bf16(af, b1, acc1, 0, 0, 0);
        }
        if (q < 2) {
            #pragma unroll
            for (int r = 0; r < 4; r++) {
                const size_t p = (size_t)(pbase + q*4 + r)*128;
                out[p + w*32 + nlane]      = lrelu(acc0[r]);
                out[p + w*32 + 16 + nlane] = lrelu(acc1[r]);
            }
        }
    }
}

// ---------------------------------------------------------------------------
__global__ __launch_bounds__(256) void k_vlad_a(
    const float* __restrict__ f, const float* __restrict__ wa,
    const int* __restrict__ m, float* __restrict__ a, float* __restrict__ sumA)
{
    __shared__ __align__(16) float s_fT[128*36 + 8];
    __shared__ float s_m[32];
    const int tid = threadIdx.x;
    const int pbase = blockIdx.x * 32;
    const int b = pbase >> 11;
    for (int i = tid; i < 32*128; i += 256) {
        const int p = i >> 7, j = i & 127;
        s_fT[j*36 + p] = f[(size_t)pbase*128 + i];
    }
    if (tid < 32) s_m[tid] = (m[pbase + tid] != 0) ? 0.f : 1.f;
    __syncthreads();
    const int w = tid >> 6, kc = tid & 63;
    const int pb = w * 8;
    float acc[8] = {0.f,0.f,0.f,0.f,0.f,0.f,0.f,0.f};
    for (int j = 0; j < 128; j++) {
        const float wv = wa[j*64 + kc];
        const float4 f0 = *(const float4*)&s_fT[j*36 + pb];
        const float4 f1 = *(const float4*)&s_fT[j*36 + pb + 4];
        acc[0] = fmaf(f0.x, wv, acc[0]); acc[1] = fmaf(f0.y, wv, acc[1]);
        acc[2] = fmaf(f0.z, wv, acc[2]); acc[3] = fmaf(f0.w, wv, acc[3]);
        acc[4] = fmaf(f1.x, wv, acc[4]); acc[5] = fmaf(f1.y, wv, acc[5]);
        acc[6] = fmaf(f1.z, wv, acc[6]); acc[7] = fmaf(f1.w, wv, acc[7]);
    }
    float part = 0.f;
    #pragma unroll
    for (int pl = 0; pl < 8; pl++) {
        float mx = acc[pl];
        #pragma unroll
        for (int off = 32; off > 0; off >>= 1) mx = fmaxf(mx, __shfl_xor(mx, off, 64));
        const float e = expf(acc[pl] - mx);
        float se = e;
        #pragma unroll
        for (int off = 32; off > 0; off >>= 1) se += __shfl_xor(se, off, 64);
        const float av = (e / se) * s_m[pb + pl];
        a[(size_t)(pbase + pb + pl)*64 + kc] = av;
        part += av;
    }
    atomicAdd(&sumA[b*64 + kc], part);
}

// ---------------------------------------------------------------------------
__global__ __launch_bounds__(256) void k_vlad_acc(
    const float* __restrict__ a, const float* __restrict__ f,
    float* __restrict__ vpart)
{
    __shared__ __align__(16) float s_a[32*64];
    __shared__ __align__(16) float s_f[32*128];
    const int b  = blockIdx.x >> 4;
    const int ch = blockIdx.x & 15;
    const int n0 = ch * (N / VCH);
    const int tid = threadIdx.x;
    const int kc0 = (tid >> 5) * 8;
    const int d0  = (tid & 31) * 4;
    float acc[8][4];
    #pragma unroll
    for (int i = 0; i < 8; i++)
        #pragma unroll
        for (int j = 0; j < 4; j++) acc[i][j] = 0.f;
    for (int t = 0; t < N/VCH; t += 32) {
        __syncthreads();
        const size_t base = (size_t)(b*N + n0 + t);
        for (int i = tid; i < 32*64; i += 256)  s_a[i] = a[(base << 6) + i];
        for (int i = tid; i < 32*128; i += 256) s_f[i] = f[(base << 7) + i];
        __syncthreads();
        for (int n = 0; n < 32; n++) {
            const float4 a0 = *(const float4*)&s_a[n*64 + kc0];
            const float4 a1 = *(const float4*)&s_a[n*64 + kc0 + 4];
            const float4 fv = *(const float4*)&s_f[n*128 + d0];
            const float av[8] = {a0.x,a0.y,a0.z,a0.w,a1.x,a1.y,a1.z,a1.w};
            const float fw[4] = {fv.x,fv.y,fv.z,fv.w};
            #pragma unroll
            for (int i = 0; i < 8; i++)
                #pragma unroll
                for (int j = 0; j < 4; j++) acc[i][j] = fmaf(av[i], fw[j], acc[i][j]);
        }
    }
    float* vp = vpart + ((size_t)ch*B + b)*8192;
    #pragma unroll
    for (int i = 0; i < 8; i++)
        #pragma unroll
        for (int j = 0; j < 4; j++) vp[(kc0+i)*128 + d0 + j] = acc[i][j];
}

// ---------------------------------------------------------------------------
__global__ __launch_bounds__(128) void k_vlad_norm(
    const float* __restrict__ vpart, const float* __restrict__ sumA,
    const float* __restrict__ centers, float* __restrict__ v)
{
    const int b = blockIdx.x >> 6, kc = blockIdx.x & 63, d = threadIdx.x;
    float acc = 0.f;
    #pragma unroll
    for (int c = 0; c < VCH; c++)
        acc += vpart[((size_t)c*B + b)*8192 + kc*128 + d];
    const float vv = acc - sumA[b*64 + kc] * centers[kc*128 + d];
    float s2 = vv*vv;
    #pragma unroll
    for (int off = 32; off > 0; off >>= 1) s2 += __shfl_xor(s2, off, 64);
    __shared__ float red[2];
    if ((d & 63) == 0) red[d >> 6] = s2;
    __syncthreads();
    const float tot = red[0] + red[1];
    v[((size_t)b*64 + kc)*128 + d] = vv / (sqrtf(tot) + 1e-8f);
}

__global__ __launch_bounds__(256) void k_vnorm(
    const float* __restrict__ v, float* __restrict__ scale)
{
    const int b = blockIdx.x;
    float s = 0.f;
    for (int i = threadIdx.x; i < 8192; i += 256) { const float t = v[(size_t)b*8192 + i]; s = fmaf(t, t, s); }
    #pragma unroll
    for (int off = 32; off > 0; off >>= 1) s += __shfl_xor(s, off, 64);
    __shared__ float red[4];
    if ((threadIdx.x & 63) == 0) red[threadIdx.x >> 6] = s;
    __syncthreads();
    if (threadIdx.x == 0) {
        const float tot = red[0] + red[1] + red[2] + red[3];
        scale[b] = 1.f / (sqrtf(tot) + 1e-8f);
    }
}

__global__ __launch_bounds__(256) void k_zero(float* __restrict__ p, int n)
{
    const int i = blockIdx.x * 256 + threadIdx.x;
    if (i < n) p[i] = 0.f;
}

__global__ __launch_bounds__(256) void k_proj(
    const float* __restrict__ v, const float* __restrict__ scale,
    const float* __restrict__ proj, float* __restrict__ outacc)
{
    __shared__ __align__(16) float s_v[8*256];
    __shared__ float s_sc[8];
    const int jc = blockIdx.x, o = threadIdx.x;
    const int j0 = jc * 256;
    for (int i = o; i < 8*256; i += 256) {
        const int bb = i >> 8, jj = i & 255;
        s_v[i] = v[(size_t)bb*8192 + j0 + jj];
    }
    if (o < 8) s_sc[o] = scale[o];
    __syncthreads();
    float acc[8] = {0.f,0.f,0.f,0.f,0.f,0.f,0.f,0.f};
    for (int jj = 0; jj < 256; jj += 4) {
        float pv[4];
        #pragma unroll
        for (int q = 0; q < 4; q++) pv[q] = proj[(size_t)(j0+jj+q)*256 + o];
        #pragma unroll
        for (int bb = 0; bb < 8; bb++) {
            const float4 vv = *(const float4*)&s_v[bb*256 + jj];
            acc[bb] = fmaf(vv.x, pv[0], acc[bb]);
            acc[bb] = fmaf(vv.y, pv[1], acc[bb]);
            acc[bb] = fmaf(vv.z, pv[2], acc[bb]);
            acc[bb] = fmaf(vv.w, pv[3], acc[bb]);
        }
    }
    #pragma unroll
    for (int bb = 0; bb < 8; bb++) atomicAdd(&outacc[bb*256 + o], acc[bb] * s_sc[bb]);
}

__global__ __launch_bounds__(256) void k_outnorm(
    const float* __restrict__ outacc, float* __restrict__ out)
{
    const int b = blockIdx.x, o = threadIdx.x;
    const float val = outacc[b*256 + o];
    float s = val*val;
    #pragma unroll
    for (int off = 32; off > 0; off >>= 1) s += __shfl_xor(s, off, 64);
    __shared__ float red[4];
    if ((o & 63) == 0) red[o >> 6] = s;
    __syncthreads();
    const float tot = red[0] + red[1] + red[2] + red[3];
    out[b*256 + o] = val / (sqrtf(tot) + 1e-12f);
}

// ---------------------------------------------------------------------------
extern "C" void kernel_launch(void* const* d_in, const int* in_sizes, int n_in,
                              void* d_out, int out_size, void* d_ws, size_t ws_size,
                              hipStream_t stream)
{
    (void)in_sizes; (void)n_in; (void)out_size; (void)ws_size;
    const float* x     = (const float*)d_in[0];
    const int*   m     = (const int*)  d_in[1];
    const float* pn_w1 = (const float*)d_in[2];
    const float* pn_b1 = (const float*)d_in[3];
    const float* pn_w2 = (const float*)d_in[4];
    const float* pn_b2 = (const float*)d_in[5];
    const float* kp    = (const float*)d_in[6];
    const float* bw1[3] = {(const float*)d_in[7],  (const float*)d_in[11], (const float*)d_in[15]};
    const float* bwk[3] = {(const float*)d_in[8],  (const float*)d_in[12], (const float*)d_in[16]};
    const float* bw2[3] = {(const float*)d_in[9],  (const float*)d_in[13], (const float*)d_in[17]};
    const float* bws[3] = {(const float*)d_in[10], (const float*)d_in[14], (const float*)d_in[18]};
    const float* vlad_wa      = (const float*)d_in[19];
    const float* vlad_centers = (const float*)d_in[20];
    const float* vlad_proj    = (const float*)d_in[21];
    float* out = (float*)d_out;

    char* ws = (char*)d_ws;
    size_t off = 0;
    auto alloc = [&](size_t bytes) -> void* {
        void* p = ws + off;
        off = (off + bytes + 255) & ~(size_t)255;
        return p;
    };
    float4* coords4 = (float4*)alloc((size_t)BN*16);
    float*  feat0   = (float*)alloc((size_t)BN*64*4);
    int*    idxb    = (int*)  alloc((size_t)BN*KNBR*4);
    float*  x1b     = (float*)alloc((size_t)BN*64*4);     // aliased by vpart later
    float*  fA      = (float*)alloc((size_t)BN*128*4);
    float*  fB      = (float*)alloc((size_t)BN*128*4);
    float*  abuf    = (float*)alloc((size_t)BN*64*4);
    float*  vbuf    = (float*)alloc((size_t)B*8192*4);
    float*  scaleb  = (float*)alloc((size_t)B*4);
    float*  sumA    = (float*)alloc((size_t)B*64*4);
    float*  outacc  = (float*)alloc((size_t)B*256*4);
    int*    cntb    = (int*)  alloc((size_t)B*4);
    int*    compact = (int*)  alloc((size_t)BN*4);
    short*  wkT[3]  = {(short*)alloc(64*960*2), (short*)alloc(64*960*2), (short*)alloc(64*960*2)};
    short*  catT[3] = {(short*)alloc(128*192*2), (short*)alloc(128*192*2), (short*)alloc(128*192*2)};
    float*  vpart   = x1b;

    k_prep<<<(3*61440 + 16384 + 2*24576 + 255)/256, 256, 0, stream>>>(
        bwk[0], bwk[1], bwk[2], bw2[0], bws[0], bw2[1], bws[1], bw2[2], bws[2],
        wkT[0], wkT[1], wkT[2], catT[0], catT[1], catT[2]);

    k_zero<<<(B*64 + B*256 + B + 255)/256, 256, 0, stream>>>(sumA, B*64 + B*256 + B);
    k_compact<<<BN/256, 256, 0, stream>>>(m, compact, cntb, idxb);
    k_pointnet<<<BN/32, 256, 0, stream>>>(x, m, pn_w1, pn_b1, pn_w2, pn_b2, feat0, coords4);
    k_knn<<<B*256, 512, 0, stream>>>(coords4, compact, cntb, idxb);

    k_unary1<64> <<<BN/32, 256, 0, stream>>>(feat0, bw1[0], x1b);
    k_kpconv<64> <<<BN/8, 256, 0, stream>>>(x1b, coords4, kp, idxb, feat0, wkT[0], catT[0], fA);
    k_unary1<128><<<BN/32, 256, 0, stream>>>(fA, bw1[1], x1b);
    k_kpconv<128><<<BN/8, 256, 0, stream>>>(x1b, coords4, kp, idxb, fA, wkT[1], catT[1], fB);
    k_unary1<128><<<BN/32, 256, 0, stream>>>(fB, bw1[2], x1b);
    k_kpconv<128><<<BN/8, 256, 0, stream>>>(x1b, coords4, kp, idxb, fB, wkT[2], catT[2], fA);

    k_vlad_a<<<BN/32, 256, 0, stream>>>(fA, vlad_wa, m, abuf, sumA);
    k_vlad_acc<<<B*VCH, 256, 0, stream>>>(abuf, fA, vpart);
    k_vlad_norm<<<B*64, 128, 0, stream>>>(vpart, sumA, vlad_centers, vbuf);
    k_vnorm<<<B, 256, 0, stream>>>(vbuf, scaleb);
    k_proj<<<32, 256, 0, stream>>>(vbuf, scaleb, vlad_proj, outacc);
    k_outnorm<<<B, 256, 0, stream>>>(outacc, out);
}

// Round 13
// 437.260 us; speedup vs baseline: 1.3539x; 1.0326x over previous
//
#include <hip/hip_runtime.h>
#include <hip/hip_bf16.h>

#define B 8
#define N 2048
#define BN (B*N)
#define KNBR 32
#define NKP 15
#define VCH 16   // n-chunks per batch in VLAD accumulation

__device__ __forceinline__ float lrelu(float x){ return x > 0.f ? x : 0.1f*x; }
__device__ __forceinline__ unsigned umin_(unsigned a, unsigned b){ return __builtin_elementwise_min(a, b); }
__device__ __forceinline__ unsigned umax_(unsigned a, unsigned b){ return __builtin_elementwise_max(a, b); }

// MFMA fragment types (per guide: short8 = 8 bf16 = 4 VGPRs)
typedef __attribute__((ext_vector_type(8))) short bf16x8;
typedef __attribute__((ext_vector_type(4))) float fx4;

__device__ __forceinline__ short bfr(float f){
    union { __hip_bfloat16 h; short s; } u;
    u.h = __float2bfloat16(f);
    return u.s;
}
__device__ __forceinline__ unsigned pk2(float a, float b){
    return ((unsigned)(unsigned short)bfr(b) << 16) | (unsigned)(unsigned short)bfr(a);
}

// ---------------------------------------------------------------------------
// Fused weight prep: 3x wkT + 3x catT (round-12 verified).
__global__ __launch_bounds__(256) void k_prep(
    const float* __restrict__ wk0, const float* __restrict__ wk1, const float* __restrict__ wk2,
    const float* __restrict__ w20, const float* __restrict__ ws0,
    const float* __restrict__ w21, const float* __restrict__ ws1,
    const float* __restrict__ w22, const float* __restrict__ ws2,
    short* __restrict__ wkT0, short* __restrict__ wkT1, short* __restrict__ wkT2,
    short* __restrict__ cat0, short* __restrict__ cat1, short* __restrict__ cat2)
{
    const int i = blockIdx.x * 256 + threadIdx.x;
    if (i < 3*61440) {
        const int l = i / 61440, r = i % 61440;
        const int n = r / 960, k = r % 960;
        const float* wk = (l == 0) ? wk0 : (l == 1) ? wk1 : wk2;
        short* dst = (l == 0) ? wkT0 : (l == 1) ? wkT1 : wkT2;
        dst[r] = bfr(wk[k*64 + n]);
    } else {
        int j = i - 3*61440;
        if (j < 16384) {
            const int n = j / 128, k = j % 128;
            cat0[j] = bfr(k < 64 ? w20[k*128 + n] : ws0[(k-64)*128 + n]);
        } else if (j < 16384 + 24576) {
            j -= 16384;
            const int n = j / 192, k = j % 192;
            cat1[j] = bfr(k < 64 ? w21[k*128 + n] : ws1[(k-64)*128 + n]);
        } else if (j < 16384 + 49152) {
            j -= 16384 + 24576;
            const int n = j / 192, k = j % 192;
            cat2[j] = bfr(k < 64 ? w22[k*128 + n] : ws2[(k-64)*128 + n]);
        }
    }
}

// ---------------------------------------------------------------------------
// Compaction with wave-aggregated atomics (round-10 verified).
__global__ __launch_bounds__(256) void k_compact(
    const int* __restrict__ m, int* __restrict__ compact, int* __restrict__ cnt,
    int* __restrict__ idx)
{
    const int p = blockIdx.x * 256 + threadIdx.x;
    const int b = p >> 11, n = p & (N-1);
    const int lane = threadIdx.x & 63;
    const bool unm = (m[p] == 0);
    const unsigned long long mask = __ballot(unm);
    int base = 0;
    if (lane == 0) base = atomicAdd(&cnt[b], __popcll(mask));
    base = __shfl(base, 0, 64);
    if (unm) {
        const int pos = base + __popcll(mask & ((1ull << lane) - 1ull));
        compact[b*N + pos] = n;
    } else {
        #pragma unroll
        for (int k = 0; k < KNBR; k++) idx[(size_t)p*KNBR + k] = k;
    }
}

// ---------------------------------------------------------------------------
// PointNet (round-5 verified shape).
__global__ __launch_bounds__(256) void k_pointnet(
    const float* __restrict__ x, const int* __restrict__ m,
    const float* __restrict__ w1, const float* __restrict__ b1,
    const float* __restrict__ w2, const float* __restrict__ b2,
    float* __restrict__ feat, float4* __restrict__ coords4)
{
    __shared__ float s_x[32][3];
    __shared__ __align__(16) float s_hT[64*40];
    const int tid = threadIdx.x;
    const int pbase = blockIdx.x * 32;
    if (tid < 32) {
        const int p = pbase + tid;
        const float x0 = x[p*3+0], x1v = x[p*3+1], x2v = x[p*3+2];
        s_x[tid][0] = x0; s_x[tid][1] = x1v; s_x[tid][2] = x2v;
        const bool mm = (m[p] != 0);
        const float cx = mm ? 1e6f : x0, cy = mm ? 1e6f : x1v, cz = mm ? 1e6f : x2v;
        coords4[p] = make_float4(cx, cy, cz, cx*cx + cy*cy + cz*cz);
    }
    __syncthreads();
    const int w = tid >> 6, c = tid & 63;
    const int pb = w * 8;
    {
        const float w10 = w1[c], w11 = w1[64+c], w12 = w1[128+c], bb = b1[c];
        #pragma unroll
        for (int pl = 0; pl < 8; pl++) {
            float s = bb;
            s = fmaf(s_x[pb+pl][0], w10, s);
            s = fmaf(s_x[pb+pl][1], w11, s);
            s = fmaf(s_x[pb+pl][2], w12, s);
            s_hT[c*40 + pb + pl] = fmaxf(s, 0.f);
        }
    }
    {
        float acc[8];
        const float bb = b2[c];
        #pragma unroll
        for (int pl = 0; pl < 8; pl++) acc[pl] = bb;
        for (int j = 0; j < 64; j++) {
            const float wv = w2[j*64 + c];
            const float4 h0 = *(const float4*)&s_hT[j*40 + pb];
            const float4 h1 = *(const float4*)&s_hT[j*40 + pb + 4];
            acc[0] = fmaf(h0.x, wv, acc[0]); acc[1] = fmaf(h0.y, wv, acc[1]);
            acc[2] = fmaf(h0.z, wv, acc[2]); acc[3] = fmaf(h0.w, wv, acc[3]);
            acc[4] = fmaf(h1.x, wv, acc[4]); acc[5] = fmaf(h1.y, wv, acc[5]);
            acc[6] = fmaf(h1.z, wv, acc[6]); acc[7] = fmaf(h1.w, wv, acc[7]);
        }
        #pragma unroll
        for (int pl = 0; pl < 8; pl++)
            feat[(size_t)(pbase + pb + pl)*64 + c] = fmaxf(acc[pl], 0.f);
    }
}

// ---------------------------------------------------------------------------
// KNN — reverted to round-11 measured-best config (256 threads, 4 waves).
__global__ __launch_bounds__(256, 2) void k_knn(
    const float4* __restrict__ c4, const int* __restrict__ compact,
    const int* __restrict__ cnt, int* __restrict__ idx)
{
    const int b = blockIdx.x >> 9;
    const int slot0 = (blockIdx.x & 511) * 4;
    const int cn = cnt[b];
    if (slot0 >= cn) return;
    __shared__ float4 s_c[N];
    const int tid = threadIdx.x;
    const int w = tid >> 6, lane = tid & 63;
    for (int i = tid; i < N; i += 256) s_c[i] = c4[(size_t)b*N + i];
    __syncthreads();
    const int slot = slot0 + w;
    const bool active = slot < cn;
    const int n = active ? compact[b*N + slot] : 0;
    const float4 me = s_c[n];

    unsigned A[32];
    #pragma unroll
    for (int j = 0; j < 32; j++) {
        const float4 s = s_c[j*64 + lane];
        float d2 = me.w + s.w - 2.f*(me.x*s.x + me.y*s.y + me.z*s.z);
        d2 = fmaxf(d2, 0.f);
        A[j] = (__float_as_uint(d2) & 0xFFFFF800u) | (unsigned)(j*64 + lane);
    }
    #pragma unroll
    for (int k = 2; k <= 32; k <<= 1) {
        #pragma unroll
        for (int j = k >> 1; j > 0; j >>= 1) {
            #pragma unroll
            for (int i = 0; i < 32; i++) {
                const int l = i ^ j;
                if (l > i) {
                    const unsigned lo = umin_(A[i], A[l]);
                    const unsigned hi = umax_(A[i], A[l]);
                    const bool up = ((i & k) == 0);
                    A[i] = up ? lo : hi;
                    A[l] = up ? hi : lo;
                }
            }
        }
    }
    #pragma unroll
    for (int r = 0; r < 6; r++) {
        const int mask = 1 << r;
        #pragma unroll
        for (int i = 0; i < 16; i++) {
            const unsigned t1 = (unsigned)__shfl_xor((int)A[31-i], mask, 64);
            const unsigned t2 = (unsigned)__shfl_xor((int)A[i],    mask, 64);
            A[i]    = umin_(A[i],    t1);
            A[31-i] = umin_(A[31-i], t2);
        }
        if (r < 5) {
            #pragma unroll
            for (int j = 16; j > 0; j >>= 1) {
                #pragma unroll
                for (int i = 0; i < 32; i++) {
                    const int l = i ^ j;
                    if (l > i) {
                        const unsigned lo = umin_(A[i], A[l]);
                        A[l] = umax_(A[i], A[l]);
                        A[i] = lo;
                    }
                }
            }
        }
    }
    #pragma unroll
    for (int s = 16; s >= 1; s >>= 1) {
        #pragma unroll
        for (int i = 0; i < s; i++)
            A[i] = (lane & s) ? A[i+s] : A[i];
    }
    if (active && lane < 32)
        idx[(size_t)(b*N + n)*KNBR + lane] = (int)(A[0] & 0x7FFu);
}

// ---------------------------------------------------------------------------
// x1 = lrelu(feat @ W1) (round-6 verified shape).
template<int CIN>
__global__ __launch_bounds__(256) void k_unary1(
    const float* __restrict__ feat, const float* __restrict__ w1,
    float* __restrict__ x1)
{
    __shared__ __align__(16) float s_fT[128*36 + 8];
    const int tid = threadIdx.x;
    const int pbase = blockIdx.x * 32;
    for (int i = tid; i < 32*CIN; i += 256) {
        const int p = i / CIN, j = i % CIN;
        s_fT[j*36 + p] = feat[(size_t)pbase*CIN + i];
    }
    __syncthreads();
    const int w = tid >> 6, c = tid & 63;
    const int pb = w * 8;
    float acc[8] = {0.f,0.f,0.f,0.f,0.f,0.f,0.f,0.f};
    for (int j = 0; j < CIN; j++) {
        const float wv = w1[j*64 + c];
        const float4 f0 = *(const float4*)&s_fT[j*36 + pb];
        const float4 f1 = *(const float4*)&s_fT[j*36 + pb + 4];
        acc[0] = fmaf(f0.x, wv, acc[0]); acc[1] = fmaf(f0.y, wv, acc[1]);
        acc[2] = fmaf(f0.z, wv, acc[2]); acc[3] = fmaf(f0.w, wv, acc[3]);
        acc[4] = fmaf(f1.x, wv, acc[4]); acc[5] = fmaf(f1.y, wv, acc[5]);
        acc[6] = fmaf(f1.z, wv, acc[6]); acc[7] = fmaf(f1.w, wv, acc[7]);
    }
    #pragma unroll
    for (int pl = 0; pl < 8; pl++)
        x1[(size_t)(pbase + pb + pl)*64 + c] = lrelu(acc[pl]);
}

// ---------------------------------------------------------------------------
// KPConv: ALL THREE GEMM phases via MFMA. Phase 1 (neighbor aggregation) is
// now agg[ch][kp] = x1T(16ch x 32nbr) @ w(32nbr x 16kp), 4 MFMA per point,
// replacing 960 scalar FMA/wave. D layout (col=kp, rows=4 consecutive ch)
// writes one b64 per tile into the SAME flat aggT layout (kp*64+ch) that
// phase 2 consumes (verified since round 8). LDS 39.4 KB -> 4 blocks/CU.
template<int CIN>
__global__ __launch_bounds__(256) void k_kpconv(
    const float* __restrict__ x1, const float4* __restrict__ c4,
    const float* __restrict__ kp,
    const int* __restrict__ idx, const float* __restrict__ feat_in,
    const short* __restrict__ WkT, const short* __restrict__ WcatT,
    float* __restrict__ out)
{
    constexpr int KC = 64 + CIN;
    constexpr int AS = 976;        // aggT row stride (shorts)
    constexpr int XS = 72;         // x2 row stride (shorts)
    constexpr int FS = CIN + 8;    // feat row stride (shorts)
    __shared__ __align__(16) short s_aggT[8*AS];       // 15616 B
    __shared__ __align__(16) unsigned s_un[5632];      // 22528 B union region
    __shared__ int   s_idx[256];
    __shared__ float skp[48];

    const int tid   = threadIdx.x;
    const int pbase = blockIdx.x * 8;
    const int brow  = pbase & ~(N-1);
    const int w = tid >> 6, lane = tid & 63;

    if (tid < NKP*3) skp[tid] = kp[tid];
    s_idx[tid] = idx[(size_t)pbase*KNBR + tid];
    __syncthreads();

    // ---- phase 1: per-wave, no cross-wave barriers ----
    unsigned* xg  = s_un + w*1152;                    // [64 ch][18 dwords]
    short*    wbf = (short*)(s_un + 4608) + w*512;    // [16 kp][32 nbr]

    for (int sub = 0; sub < 2; sub++) {
        const int pl = w*2 + sub;
        // (a) kernel-point influence weights -> wbf (bf16)
        {
            const int k = lane & 31, h = lane >> 5;
            const float4 cp = c4[pbase + pl];
            const float4 cn = c4[brow + s_idx[pl*KNBR + k]];
            const float dx = cn.x - cp.x, dy = cn.y - cp.y, dz = cn.z - cp.z;
            #pragma unroll
            for (int j = 0; j < 8; j++) {
                const int kpi = h*8 + j;
                if (kpi < NKP) {
                    const float ex = dx - skp[kpi*3], ey = dy - skp[kpi*3+1], ez = dz - skp[kpi*3+2];
                    const float dist = sqrtf(ex*ex + ey*ey + ez*ez);
                    wbf[kpi*32 + k] = bfr(fmaxf(0.f, 1.f - dist*2.f));
                }
            }
        }
        // (b) gather x1 rows (lane = channel), pack bf16 -> xg[ch][nbr]
        {
            float g[KNBR];
            #pragma unroll
            for (int k = 0; k < KNBR; k++)
                g[k] = x1[(size_t)(brow + s_idx[pl*KNBR + k])*64 + lane];
            #pragma unroll
            for (int i = 0; i < 16; i++)
                xg[lane*18 + i] = pk2(g[2*i], g[2*i+1]);
        }
        // (c) agg = x1T @ w via 4 MFMA (one per 16-channel tile)
        {
            const int n = lane & 15, q = lane >> 4;
            const bf16x8 bw = *(const bf16x8*)&wbf[n*32 + q*8];
            #pragma unroll
            for (int t = 0; t < 4; t++) {
                union { unsigned u[4]; bf16x8 v; } af;
                const unsigned* src = &xg[(t*16 + n)*18 + q*4];
                af.u[0] = src[0]; af.u[1] = src[1]; af.u[2] = src[2]; af.u[3] = src[3];
                fx4 d = {0.f,0.f,0.f,0.f};
                d = __builtin_amdgcn_mfma_f32_16x16x32_bf16(af.v, bw, d, 0, 0, 0);
                if (n < NKP) {   // col 15 is kp padding
                    const uint2 o = make_uint2(pk2(d[0], d[1]), pk2(d[2], d[3]));
                    *(uint2*)&s_aggT[pl*AS + n*64 + t*16 + q*4] = o;
                }
            }
        }
    }
    __syncthreads();   // phase-1 region dead; union becomes x2bf/featbf

    short* s_x2bf   = (short*)s_un;            // [8][XS]
    short* s_featbf = (short*)s_un + 8*XS;     // [8][FS]

    // stage feat as bf16 (overlaps phase 2)
    for (int i = tid; i < 8*CIN; i += 256) {
        const int p = i / CIN, j = i % CIN;
        s_featbf[p*FS + j] = bfr(feat_in[(size_t)pbase*CIN + i]);
    }

    const int nlane = lane & 15, q = lane >> 4;
    // phase 2: x2 = lrelu(agg @ Wk) via MFMA (round-11 verified)
    {
        fx4 acc = {0.f,0.f,0.f,0.f};
        const short* arow = &s_aggT[(nlane & 7)*AS];
        const short* brw  = &WkT[(size_t)(w*16 + nlane)*960];
        for (int t = 0; t < 30; t++) {
            const int k0 = t*32 + q*8;
            const bf16x8 af = *(const bf16x8*)&arow[k0];
            const bf16x8 bf = *(const bf16x8*)&brw[k0];
            acc = __builtin_amdgcn_mfma_f32_16x16x32_bf16(af, bf, acc, 0, 0, 0);
        }
        if (q < 2) {
            #pragma unroll
            for (int r = 0; r < 4; r++)
                s_x2bf[(q*4+r)*XS + w*16 + nlane] = bfr(lrelu(acc[r]));
        }
    }
    __syncthreads();

    // phase 3: out = lrelu([x2|feat] @ [W2;Ws]) via MFMA (round-11 verified)
    {
        fx4 acc0 = {0.f,0.f,0.f,0.f}, acc1 = {0.f,0.f,0.f,0.f};
        const short* b0r = &WcatT[(size_t)(w*32 + nlane)*KC];
        const short* b1r = &WcatT[(size_t)(w*32 + 16 + nlane)*KC];
        const int pt = nlane & 7;
        const short* xrow = &s_x2bf[pt*XS];
        const short* frow = &s_featbf[pt*FS];
        #pragma unroll
        for (int t = 0; t < KC/32; t++) {
            const int k0 = t*32 + q*8;
            const short* src = (t < 2) ? &xrow[k0] : &frow[k0 - 64];
            const bf16x8 af = *(const bf16x8*)src;
            const bf16x8 b0 = *(const bf16x8*)&b0r[k0];
            const bf16x8 b1 = *(const bf16x8*)&b1r[k0];
            acc0 = __builtin_amdgcn_mfma_f32_16x16x32_bf16(af, b0, acc0, 0, 0, 0);
            acc1 = __builtin_amdgcn_mfma_f32_16x16x32_bf16(af, b1, acc1, 0, 0, 0);
        }
        if (q < 2) {
            #pragma unroll
            for (int r = 0; r < 4; r++) {
                const size_t p = (size_t)(pbase + q*4 + r)*128;
                out[p + w*32 + nlane]      = lrelu(acc0[r]);
                out[p + w*32 + 16 + nlane] = lrelu(acc1[r]);
            }
        }
    }
}

// ---------------------------------------------------------------------------
__global__ __launch_bounds__(256) void k_vlad_a(
    const float* __restrict__ f, const float* __restrict__ wa,
    const int* __restrict__ m, float* __restrict__ a, float* __restrict__ sumA)
{
    __shared__ __align__(16) float s_fT[128*36 + 8];
    __shared__ float s_m[32];
    const int tid = threadIdx.x;
    const int pbase = blockIdx.x * 32;
    const int b = pbase >> 11;
    for (int i = tid; i < 32*128; i += 256) {
        const int p = i >> 7, j = i & 127;
        s_fT[j*36 + p] = f[(size_t)pbase*128 + i];
    }
    if (tid < 32) s_m[tid] = (m[pbase + tid] != 0) ? 0.f : 1.f;
    __syncthreads();
    const int w = tid >> 6, kc = tid & 63;
    const int pb = w * 8;
    float acc[8] = {0.f,0.f,0.f,0.f,0.f,0.f,0.f,0.f};
    for (int j = 0; j < 128; j++) {
        const float wv = wa[j*64 + kc];
        const float4 f0 = *(const float4*)&s_fT[j*36 + pb];
        const float4 f1 = *(const float4*)&s_fT[j*36 + pb + 4];
        acc[0] = fmaf(f0.x, wv, acc[0]); acc[1] = fmaf(f0.y, wv, acc[1]);
        acc[2] = fmaf(f0.z, wv, acc[2]); acc[3] = fmaf(f0.w, wv, acc[3]);
        acc[4] = fmaf(f1.x, wv, acc[4]); acc[5] = fmaf(f1.y, wv, acc[5]);
        acc[6] = fmaf(f1.z, wv, acc[6]); acc[7] = fmaf(f1.w, wv, acc[7]);
    }
    float part = 0.f;
    #pragma unroll
    for (int pl = 0; pl < 8; pl++) {
        float mx = acc[pl];
        #pragma unroll
        for (int off = 32; off > 0; off >>= 1) mx = fmaxf(mx, __shfl_xor(mx, off, 64));
        const float e = expf(acc[pl] - mx);
        float se = e;
        #pragma unroll
        for (int off = 32; off > 0; off >>= 1) se += __shfl_xor(se, off, 64);
        const float av = (e / se) * s_m[pb + pl];
        a[(size_t)(pbase + pb + pl)*64 + kc] = av;
        part += av;
    }
    atomicAdd(&sumA[b*64 + kc], part);
}

// ---------------------------------------------------------------------------
__global__ __launch_bounds__(256) void k_vlad_acc(
    const float* __restrict__ a, const float* __restrict__ f,
    float* __restrict__ vpart)
{
    __shared__ __align__(16) float s_a[32*64];
    __shared__ __align__(16) float s_f[32*128];
    const int b  = blockIdx.x >> 4;
    const int ch = blockIdx.x & 15;
    const int n0 = ch * (N / VCH);
    const int tid = threadIdx.x;
    const int kc0 = (tid >> 5) * 8;
    const int d0  = (tid & 31) * 4;
    float acc[8][4];
    #pragma unroll
    for (int i = 0; i < 8; i++)
        #pragma unroll
        for (int j = 0; j < 4; j++) acc[i][j] = 0.f;
    for (int t = 0; t < N/VCH; t += 32) {
        __syncthreads();
        const size_t base = (size_t)(b*N + n0 + t);
        for (int i = tid; i < 32*64; i += 256)  s_a[i] = a[(base << 6) + i];
        for (int i = tid; i < 32*128; i += 256) s_f[i] = f[(base << 7) + i];
        __syncthreads();
        for (int n = 0; n < 32; n++) {
            const float4 a0 = *(const float4*)&s_a[n*64 + kc0];
            const float4 a1 = *(const float4*)&s_a[n*64 + kc0 + 4];
            const float4 fv = *(const float4*)&s_f[n*128 + d0];
            const float av[8] = {a0.x,a0.y,a0.z,a0.w,a1.x,a1.y,a1.z,a1.w};
            const float fw[4] = {fv.x,fv.y,fv.z,fv.w};
            #pragma unroll
            for (int i = 0; i < 8; i++)
                #pragma unroll
                for (int j = 0; j < 4; j++) acc[i][j] = fmaf(av[i], fw[j], acc[i][j]);
        }
    }
    float* vp = vpart + ((size_t)ch*B + b)*8192;
    #pragma unroll
    for (int i = 0; i < 8; i++)
        #pragma unroll
        for (int j = 0; j < 4; j++) vp[(kc0+i)*128 + d0 + j] = acc[i][j];
}

// ---------------------------------------------------------------------------
__global__ __launch_bounds__(128) void k_vlad_norm(
    const float* __restrict__ vpart, const float* __restrict__ sumA,
    const float* __restrict__ centers, float* __restrict__ v)
{
    const int b = blockIdx.x >> 6, kc = blockIdx.x & 63, d = threadIdx.x;
    float acc = 0.f;
    #pragma unroll
    for (int c = 0; c < VCH; c++)
        acc += vpart[((size_t)c*B + b)*8192 + kc*128 + d];
    const float vv = acc - sumA[b*64 + kc] * centers[kc*128 + d];
    float s2 = vv*vv;
    #pragma unroll
    for (int off = 32; off > 0; off >>= 1) s2 += __shfl_xor(s2, off, 64);
    __shared__ float red[2];
    if ((d & 63) == 0) red[d >> 6] = s2;
    __syncthreads();
    const float tot = red[0] + red[1];
    v[((size_t)b*64 + kc)*128 + d] = vv / (sqrtf(tot) + 1e-8f);
}

__global__ __launch_bounds__(256) void k_vnorm(
    const float* __restrict__ v, float* __restrict__ scale)
{
    const int b = blockIdx.x;
    float s = 0.f;
    for (int i = threadIdx.x; i < 8192; i += 256) { const float t = v[(size_t)b*8192 + i]; s = fmaf(t, t, s); }
    #pragma unroll
    for (int off = 32; off > 0; off >>= 1) s += __shfl_xor(s, off, 64);
    __shared__ float red[4];
    if ((threadIdx.x & 63) == 0) red[threadIdx.x >> 6] = s;
    __syncthreads();
    if (threadIdx.x == 0) {
        const float tot = red[0] + red[1] + red[2] + red[3];
        scale[b] = 1.f / (sqrtf(tot) + 1e-8f);
    }
}

__global__ __launch_bounds__(256) void k_zero(float* __restrict__ p, int n)
{
    const int i = blockIdx.x * 256 + threadIdx.x;
    if (i < n) p[i] = 0.f;
}

__global__ __launch_bounds__(256) void k_proj(
    const float* __restrict__ v, const float* __restrict__ scale,
    const float* __restrict__ proj, float* __restrict__ outacc)
{
    __shared__ __align__(16) float s_v[8*256];
    __shared__ float s_sc[8];
    const int jc = blockIdx.x, o = threadIdx.x;
    const int j0 = jc * 256;
    for (int i = o; i < 8*256; i += 256) {
        const int bb = i >> 8, jj = i & 255;
        s_v[i] = v[(size_t)bb*8192 + j0 + jj];
    }
    if (o < 8) s_sc[o] = scale[o];
    __syncthreads();
    float acc[8] = {0.f,0.f,0.f,0.f,0.f,0.f,0.f,0.f};
    for (int jj = 0; jj < 256; jj += 4) {
        float pv[4];
        #pragma unroll
        for (int q = 0; q < 4; q++) pv[q] = proj[(size_t)(j0+jj+q)*256 + o];
        #pragma unroll
        for (int bb = 0; bb < 8; bb++) {
            const float4 vv = *(const float4*)&s_v[bb*256 + jj];
            acc[bb] = fmaf(vv.x, pv[0], acc[bb]);
            acc[bb] = fmaf(vv.y, pv[1], acc[bb]);
            acc[bb] = fmaf(vv.z, pv[2], acc[bb]);
            acc[bb] = fmaf(vv.w, pv[3], acc[bb]);
        }
    }
    #pragma unroll
    for (int bb = 0; bb < 8; bb++) atomicAdd(&outacc[bb*256 + o], acc[bb] * s_sc[bb]);
}

__global__ __launch_bounds__(256) void k_outnorm(
    const float* __restrict__ outacc, float* __restrict__ out)
{
    const int b = blockIdx.x, o = threadIdx.x;
    const float val = outacc[b*256 + o];
    float s = val*val;
    #pragma unroll
    for (int off = 32; off > 0; off >>= 1) s += __shfl_xor(s, off, 64);
    __shared__ float red[4];
    if ((o & 63) == 0) red[o >> 6] = s;
    __syncthreads();
    const float tot = red[0] + red[1] + red[2] + red[3];
    out[b*256 + o] = val / (sqrtf(tot) + 1e-12f);
}

// ---------------------------------------------------------------------------
extern "C" void kernel_launch(void* const* d_in, const int* in_sizes, int n_in,
                              void* d_out, int out_size, void* d_ws, size_t ws_size,
                              hipStream_t stream)
{
    (void)in_sizes; (void)n_in; (void)out_size; (void)ws_size;
    const float* x     = (const float*)d_in[0];
    const int*   m     = (const int*)  d_in[1];
    const float* pn_w1 = (const float*)d_in[2];
    const float* pn_b1 = (const float*)d_in[3];
    const float* pn_w2 = (const float*)d_in[4];
    const float* pn_b2 = (const float*)d_in[5];
    const float* kp    = (const float*)d_in[6];
    const float* bw1[3] = {(const float*)d_in[7],  (const float*)d_in[11], (const float*)d_in[15]};
    const float* bwk[3] = {(const float*)d_in[8],  (const float*)d_in[12], (const float*)d_in[16]};
    const float* bw2[3] = {(const float*)d_in[9],  (const float*)d_in[13], (const float*)d_in[17]};
    const float* bws[3] = {(const float*)d_in[10], (const float*)d_in[14], (const float*)d_in[18]};
    const float* vlad_wa      = (const float*)d_in[19];
    const float* vlad_centers = (const float*)d_in[20];
    const float* vlad_proj    = (const float*)d_in[21];
    float* out = (float*)d_out;

    char* ws = (char*)d_ws;
    size_t off = 0;
    auto alloc = [&](size_t bytes) -> void* {
        void* p = ws + off;
        off = (off + bytes + 255) & ~(size_t)255;
        return p;
    };
    float4* coords4 = (float4*)alloc((size_t)BN*16);
    float*  feat0   = (float*)alloc((size_t)BN*64*4);
    int*    idxb    = (int*)  alloc((size_t)BN*KNBR*4);
    float*  x1b     = (float*)alloc((size_t)BN*64*4);     // aliased by vpart later
    float*  fA      = (float*)alloc((size_t)BN*128*4);
    float*  fB      = (float*)alloc((size_t)BN*128*4);
    float*  abuf    = (float*)alloc((size_t)BN*64*4);
    float*  vbuf    = (float*)alloc((size_t)B*8192*4);
    float*  scaleb  = (float*)alloc((size_t)B*4);
    float*  sumA    = (float*)alloc((size_t)B*64*4);
    float*  outacc  = (float*)alloc((size_t)B*256*4);
    int*    cntb    = (int*)  alloc((size_t)B*4);
    int*    compact = (int*)  alloc((size_t)BN*4);
    short*  wkT[3]  = {(short*)alloc(64*960*2), (short*)alloc(64*960*2), (short*)alloc(64*960*2)};
    short*  catT[3] = {(short*)alloc(128*192*2), (short*)alloc(128*192*2), (short*)alloc(128*192*2)};
    float*  vpart   = x1b;

    k_prep<<<(3*61440 + 16384 + 2*24576 + 255)/256, 256, 0, stream>>>(
        bwk[0], bwk[1], bwk[2], bw2[0], bws[0], bw2[1], bws[1], bw2[2], bws[2],
        wkT[0], wkT[1], wkT[2], catT[0], catT[1], catT[2]);

    k_zero<<<(B*64 + B*256 + B + 255)/256, 256, 0, stream>>>(sumA, B*64 + B*256 + B);
    k_compact<<<BN/256, 256, 0, stream>>>(m, compact, cntb, idxb);
    k_pointnet<<<BN/32, 256, 0, stream>>>(x, m, pn_w1, pn_b1, pn_w2, pn_b2, feat0, coords4);
    k_knn<<<B*512, 256, 0, stream>>>(coords4, compact, cntb, idxb);

    k_unary1<64> <<<BN/32, 256, 0, stream>>>(feat0, bw1[0], x1b);
    k_kpconv<64> <<<BN/8, 256, 0, stream>>>(x1b, coords4, kp, idxb, feat0, wkT[0], catT[0], fA);
    k_unary1<128><<<BN/32, 256, 0, stream>>>(fA, bw1[1], x1b);
    k_kpconv<128><<<BN/8, 256, 0, stream>>>(x1b, coords4, kp, idxb, fA, wkT[1], catT[1], fB);
    k_unary1<128><<<BN/32, 256, 0, stream>>>(fB, bw1[2], x1b);
    k_kpconv<128><<<BN/8, 256, 0, stream>>>(x1b, coords4, kp, idxb, fB, wkT[2], catT[2], fA);

    k_vlad_a<<<BN/32, 256, 0, stream>>>(fA, vlad_wa, m, abuf, sumA);
    k_vlad_acc<<<B*VCH, 256, 0, stream>>>(abuf, fA, vpart);
    k_vlad_norm<<<B*64, 128, 0, stream>>>(vpart, sumA, vlad_centers, vbuf);
    k_vnorm<<<B, 256, 0, stream>>>(vbuf, scaleb);
    k_proj<<<32, 256, 0, stream>>>(vbuf, scaleb, vlad_proj, outacc);
    k_outnorm<<<B, 256, 0, stream>>>(outacc, out);
}

// Round 14
// 392.414 us; speedup vs baseline: 1.5086x; 1.1143x over previous
//
#include <hip/hip_runtime.h>
#include <hip/hip_bf16.h>

#define B 8
#define N 2048
#define BN (B*N)
#define KNBR 32
#define NKP 15
#define VCH 16   // n-chunks per batch in VLAD accumulation

__device__ __forceinline__ float lrelu(float x){ return x > 0.f ? x : 0.1f*x; }
__device__ __forceinline__ unsigned umin_(unsigned a, unsigned b){ return __builtin_elementwise_min(a, b); }
__device__ __forceinline__ unsigned umax_(unsigned a, unsigned b){ return __builtin_elementwise_max(a, b); }

// MFMA fragment types (per guide: short8 = 8 bf16 = 4 VGPRs)
typedef __attribute__((ext_vector_type(8))) short bf16x8;
typedef __attribute__((ext_vector_type(4))) float fx4;

__device__ __forceinline__ short bfr(float f){
    union { __hip_bfloat16 h; short s; } u;
    u.h = __float2bfloat16(f);
    return u.s;
}
__device__ __forceinline__ unsigned pk2(float a, float b){
    return ((unsigned)(unsigned short)bfr(b) << 16) | (unsigned)(unsigned short)bfr(a);
}

// ---------------------------------------------------------------------------
// Fused weight prep: 3x wkT + 3x catT (round-12 verified).
__global__ __launch_bounds__(256) void k_prep(
    const float* __restrict__ wk0, const float* __restrict__ wk1, const float* __restrict__ wk2,
    const float* __restrict__ w20, const float* __restrict__ ws0,
    const float* __restrict__ w21, const float* __restrict__ ws1,
    const float* __restrict__ w22, const float* __restrict__ ws2,
    short* __restrict__ wkT0, short* __restrict__ wkT1, short* __restrict__ wkT2,
    short* __restrict__ cat0, short* __restrict__ cat1, short* __restrict__ cat2)
{
    const int i = blockIdx.x * 256 + threadIdx.x;
    if (i < 3*61440) {
        const int l = i / 61440, r = i % 61440;
        const int n = r / 960, k = r % 960;
        const float* wk = (l == 0) ? wk0 : (l == 1) ? wk1 : wk2;
        short* dst = (l == 0) ? wkT0 : (l == 1) ? wkT1 : wkT2;
        dst[r] = bfr(wk[k*64 + n]);
    } else {
        int j = i - 3*61440;
        if (j < 16384) {
            const int n = j / 128, k = j % 128;
            cat0[j] = bfr(k < 64 ? w20[k*128 + n] : ws0[(k-64)*128 + n]);
        } else if (j < 16384 + 24576) {
            j -= 16384;
            const int n = j / 192, k = j % 192;
            cat1[j] = bfr(k < 64 ? w21[k*128 + n] : ws1[(k-64)*128 + n]);
        } else if (j < 16384 + 49152) {
            j -= 16384 + 24576;
            const int n = j / 192, k = j % 192;
            cat2[j] = bfr(k < 64 ? w22[k*128 + n] : ws2[(k-64)*128 + n]);
        }
    }
}

// ---------------------------------------------------------------------------
// Compaction with wave-aggregated atomics (round-10 verified).
__global__ __launch_bounds__(256) void k_compact(
    const int* __restrict__ m, int* __restrict__ compact, int* __restrict__ cnt,
    int* __restrict__ idx)
{
    const int p = blockIdx.x * 256 + threadIdx.x;
    const int b = p >> 11, n = p & (N-1);
    const int lane = threadIdx.x & 63;
    const bool unm = (m[p] == 0);
    const unsigned long long mask = __ballot(unm);
    int base = 0;
    if (lane == 0) base = atomicAdd(&cnt[b], __popcll(mask));
    base = __shfl(base, 0, 64);
    if (unm) {
        const int pos = base + __popcll(mask & ((1ull << lane) - 1ull));
        compact[b*N + pos] = n;
    } else {
        #pragma unroll
        for (int k = 0; k < KNBR; k++) idx[(size_t)p*KNBR + k] = k;
    }
}

// ---------------------------------------------------------------------------
// PointNet (round-5 verified shape).
__global__ __launch_bounds__(256) void k_pointnet(
    const float* __restrict__ x, const int* __restrict__ m,
    const float* __restrict__ w1, const float* __restrict__ b1,
    const float* __restrict__ w2, const float* __restrict__ b2,
    float* __restrict__ feat, float4* __restrict__ coords4)
{
    __shared__ float s_x[32][3];
    __shared__ __align__(16) float s_hT[64*40];
    const int tid = threadIdx.x;
    const int pbase = blockIdx.x * 32;
    if (tid < 32) {
        const int p = pbase + tid;
        const float x0 = x[p*3+0], x1v = x[p*3+1], x2v = x[p*3+2];
        s_x[tid][0] = x0; s_x[tid][1] = x1v; s_x[tid][2] = x2v;
        const bool mm = (m[p] != 0);
        const float cx = mm ? 1e6f : x0, cy = mm ? 1e6f : x1v, cz = mm ? 1e6f : x2v;
        coords4[p] = make_float4(cx, cy, cz, cx*cx + cy*cy + cz*cz);
    }
    __syncthreads();
    const int w = tid >> 6, c = tid & 63;
    const int pb = w * 8;
    {
        const float w10 = w1[c], w11 = w1[64+c], w12 = w1[128+c], bb = b1[c];
        #pragma unroll
        for (int pl = 0; pl < 8; pl++) {
            float s = bb;
            s = fmaf(s_x[pb+pl][0], w10, s);
            s = fmaf(s_x[pb+pl][1], w11, s);
            s = fmaf(s_x[pb+pl][2], w12, s);
            s_hT[c*40 + pb + pl] = fmaxf(s, 0.f);
        }
    }
    {
        float acc[8];
        const float bb = b2[c];
        #pragma unroll
        for (int pl = 0; pl < 8; pl++) acc[pl] = bb;
        for (int j = 0; j < 64; j++) {
            const float wv = w2[j*64 + c];
            const float4 h0 = *(const float4*)&s_hT[j*40 + pb];
            const float4 h1 = *(const float4*)&s_hT[j*40 + pb + 4];
            acc[0] = fmaf(h0.x, wv, acc[0]); acc[1] = fmaf(h0.y, wv, acc[1]);
            acc[2] = fmaf(h0.z, wv, acc[2]); acc[3] = fmaf(h0.w, wv, acc[3]);
            acc[4] = fmaf(h1.x, wv, acc[4]); acc[5] = fmaf(h1.y, wv, acc[5]);
            acc[6] = fmaf(h1.z, wv, acc[6]); acc[7] = fmaf(h1.w, wv, acc[7]);
        }
        #pragma unroll
        for (int pl = 0; pl < 8; pl++)
            feat[(size_t)(pbase + pb + pl)*64 + c] = fmaxf(acc[pl], 0.f);
    }
}

// ---------------------------------------------------------------------------
// KNN — round-11 measured-best config (256 threads, 4 waves).
__global__ __launch_bounds__(256, 2) void k_knn(
    const float4* __restrict__ c4, const int* __restrict__ compact,
    const int* __restrict__ cnt, int* __restrict__ idx)
{
    const int b = blockIdx.x >> 9;
    const int slot0 = (blockIdx.x & 511) * 4;
    const int cn = cnt[b];
    if (slot0 >= cn) return;
    __shared__ float4 s_c[N];
    const int tid = threadIdx.x;
    const int w = tid >> 6, lane = tid & 63;
    for (int i = tid; i < N; i += 256) s_c[i] = c4[(size_t)b*N + i];
    __syncthreads();
    const int slot = slot0 + w;
    const bool active = slot < cn;
    const int n = active ? compact[b*N + slot] : 0;
    const float4 me = s_c[n];

    unsigned A[32];
    #pragma unroll
    for (int j = 0; j < 32; j++) {
        const float4 s = s_c[j*64 + lane];
        float d2 = me.w + s.w - 2.f*(me.x*s.x + me.y*s.y + me.z*s.z);
        d2 = fmaxf(d2, 0.f);
        A[j] = (__float_as_uint(d2) & 0xFFFFF800u) | (unsigned)(j*64 + lane);
    }
    #pragma unroll
    for (int k = 2; k <= 32; k <<= 1) {
        #pragma unroll
        for (int j = k >> 1; j > 0; j >>= 1) {
            #pragma unroll
            for (int i = 0; i < 32; i++) {
                const int l = i ^ j;
                if (l > i) {
                    const unsigned lo = umin_(A[i], A[l]);
                    const unsigned hi = umax_(A[i], A[l]);
                    const bool up = ((i & k) == 0);
                    A[i] = up ? lo : hi;
                    A[l] = up ? hi : lo;
                }
            }
        }
    }
    #pragma unroll
    for (int r = 0; r < 6; r++) {
        const int mask = 1 << r;
        #pragma unroll
        for (int i = 0; i < 16; i++) {
            const unsigned t1 = (unsigned)__shfl_xor((int)A[31-i], mask, 64);
            const unsigned t2 = (unsigned)__shfl_xor((int)A[i],    mask, 64);
            A[i]    = umin_(A[i],    t1);
            A[31-i] = umin_(A[31-i], t2);
        }
        if (r < 5) {
            #pragma unroll
            for (int j = 16; j > 0; j >>= 1) {
                #pragma unroll
                for (int i = 0; i < 32; i++) {
                    const int l = i ^ j;
                    if (l > i) {
                        const unsigned lo = umin_(A[i], A[l]);
                        A[l] = umax_(A[i], A[l]);
                        A[i] = lo;
                    }
                }
            }
        }
    }
    #pragma unroll
    for (int s = 16; s >= 1; s >>= 1) {
        #pragma unroll
        for (int i = 0; i < s; i++)
            A[i] = (lane & s) ? A[i+s] : A[i];
    }
    if (active && lane < 32)
        idx[(size_t)(b*N + n)*KNBR + lane] = (int)(A[0] & 0x7FFu);
}

// ---------------------------------------------------------------------------
// x1 = lrelu(feat @ W1) (round-6 verified shape).
template<int CIN>
__global__ __launch_bounds__(256) void k_unary1(
    const float* __restrict__ feat, const float* __restrict__ w1,
    float* __restrict__ x1)
{
    __shared__ __align__(16) float s_fT[128*36 + 8];
    const int tid = threadIdx.x;
    const int pbase = blockIdx.x * 32;
    for (int i = tid; i < 32*CIN; i += 256) {
        const int p = i / CIN, j = i % CIN;
        s_fT[j*36 + p] = feat[(size_t)pbase*CIN + i];
    }
    __syncthreads();
    const int w = tid >> 6, c = tid & 63;
    const int pb = w * 8;
    float acc[8] = {0.f,0.f,0.f,0.f,0.f,0.f,0.f,0.f};
    for (int j = 0; j < CIN; j++) {
        const float wv = w1[j*64 + c];
        const float4 f0 = *(const float4*)&s_fT[j*36 + pb];
        const float4 f1 = *(const float4*)&s_fT[j*36 + pb + 4];
        acc[0] = fmaf(f0.x, wv, acc[0]); acc[1] = fmaf(f0.y, wv, acc[1]);
        acc[2] = fmaf(f0.z, wv, acc[2]); acc[3] = fmaf(f0.w, wv, acc[3]);
        acc[4] = fmaf(f1.x, wv, acc[4]); acc[5] = fmaf(f1.y, wv, acc[5]);
        acc[6] = fmaf(f1.z, wv, acc[6]); acc[7] = fmaf(f1.w, wv, acc[7]);
    }
    #pragma unroll
    for (int pl = 0; pl < 8; pl++)
        x1[(size_t)(pbase + pb + pl)*64 + c] = lrelu(acc[pl]);
}

// ---------------------------------------------------------------------------
// KPConv, 16 points/block, 512 threads (8 waves). All GEMM phases MFMA with
// FULL M=16 tiles (round-13's 8-pt blocks wasted half of every MFMA on
// duplicated rows and streamed Wk/Wcat per 8 points). Phase 2 split across
// (4 col-tiles x 2 K-halves); f32 partials reduced in LDS (stride 65).
// LDS ~78.5 KB -> 2 blocks/CU = 16 waves/CU (same as round 13).
template<int CIN>
__global__ __launch_bounds__(512) void k_kpconv(
    const float* __restrict__ x1, const float4* __restrict__ c4,
    const float* __restrict__ kp,
    const int* __restrict__ idx, const float* __restrict__ feat_in,
    const short* __restrict__ WkT, const short* __restrict__ WcatT,
    float* __restrict__ out)
{
    constexpr int KC = 64 + CIN;   // phase-3 K extent
    constexpr int AS = 976;        // aggT row stride (shorts), rows 16B-aligned
    constexpr int XS = 72;         // x2 row stride (shorts)
    constexpr int FS = CIN + 8;    // feat row stride (shorts)
    constexpr int PS = 65;         // partial row stride (floats) — conflict-free
    __shared__ __align__(16) short s_aggT[16*AS];      // 31232 B
    __shared__ __align__(16) unsigned s_un[11264];     // 45056 B union region
    __shared__ int   s_idx[512];
    __shared__ float skp[48];

    const int tid   = threadIdx.x;
    const int pbase = blockIdx.x * 16;
    const int brow  = pbase & ~(N-1);
    const int w = tid >> 6, lane = tid & 63;

    if (tid < NKP*3) skp[tid] = kp[tid];
    s_idx[tid] = idx[(size_t)pbase*KNBR + tid];
    __syncthreads();

    // ---- phase 1: wave w -> points 2w, 2w+1 (per-wave, no barriers) ----
    unsigned* xg  = s_un + w*1408;                    // [64 ch][18 dwords]
    short*    wbf = (short*)(s_un + w*1408 + 1152);   // [16 kp][32 nbr]

    for (int sub = 0; sub < 2; sub++) {
        const int pl = w*2 + sub;
        // (a) kernel-point influence weights -> wbf (bf16)
        {
            const int k = lane & 31, h = lane >> 5;
            const float4 cp = c4[pbase + pl];
            const float4 cn = c4[brow + s_idx[pl*KNBR + k]];
            const float dx = cn.x - cp.x, dy = cn.y - cp.y, dz = cn.z - cp.z;
            #pragma unroll
            for (int j = 0; j < 8; j++) {
                const int kpi = h*8 + j;
                if (kpi < NKP) {
                    const float ex = dx - skp[kpi*3], ey = dy - skp[kpi*3+1], ez = dz - skp[kpi*3+2];
                    const float dist = sqrtf(ex*ex + ey*ey + ez*ez);
                    wbf[kpi*32 + k] = bfr(fmaxf(0.f, 1.f - dist*2.f));
                }
            }
        }
        // (b) gather x1 rows (lane = channel), pack bf16 -> xg[ch][nbr]
        {
            float g[KNBR];
            #pragma unroll
            for (int k = 0; k < KNBR; k++)
                g[k] = x1[(size_t)(brow + s_idx[pl*KNBR + k])*64 + lane];
            #pragma unroll
            for (int i = 0; i < 16; i++)
                xg[lane*18 + i] = pk2(g[2*i], g[2*i+1]);
        }
        // (c) agg = x1T @ w via 4 MFMA (one per 16-channel tile)
        {
            const int n = lane & 15, q = lane >> 4;
            const bf16x8 bw = *(const bf16x8*)&wbf[n*32 + q*8];
            #pragma unroll
            for (int t = 0; t < 4; t++) {
                union { unsigned u[4]; bf16x8 v; } af;
                const unsigned* src = &xg[(t*16 + n)*18 + q*4];
                af.u[0] = src[0]; af.u[1] = src[1]; af.u[2] = src[2]; af.u[3] = src[3];
                fx4 d = {0.f,0.f,0.f,0.f};
                d = __builtin_amdgcn_mfma_f32_16x16x32_bf16(af.v, bw, d, 0, 0, 0);
                if (n < NKP) {   // col 15 is kp padding
                    const uint2 o = make_uint2(pk2(d[0], d[1]), pk2(d[2], d[3]));
                    *(uint2*)&s_aggT[pl*AS + n*64 + t*16 + q*4] = o;
                }
            }
        }
    }
    __syncthreads();   // phase-1 region dead; union re-partitioned:

    short* s_x2bf   = (short*)s_un;                        // [16][XS]  = 2304 B
    short* s_featbf = (short*)s_un + 16*XS;                // [16][FS] <= 4352 B
    float* s_part   = (float*)((char*)s_un + 6656);        // [2][16][PS] = 8320 B

    // stage feat as bf16 (overlaps phase 2)
    for (int i = tid; i < 16*CIN; i += 512) {
        const int p = i / CIN, j = i % CIN;
        s_featbf[p*FS + j] = bfr(feat_in[(size_t)pbase*CIN + i]);
    }

    const int nlane = lane & 15, q = lane >> 4;
    // phase 2: x2 = lrelu(agg @ Wk). wave w -> col-tile (w&3), K-half (w>>2).
    {
        const int ct = w & 3, kh = w >> 2;
        fx4 acc = {0.f,0.f,0.f,0.f};
        const short* arow = &s_aggT[nlane*AS + kh*480];
        const short* brw  = &WkT[(size_t)(ct*16 + nlane)*960 + kh*480];
        for (int t = 0; t < 15; t++) {
            const int k0 = t*32 + q*8;
            const bf16x8 af = *(const bf16x8*)&arow[k0];
            const bf16x8 bf = *(const bf16x8*)&brw[k0];
            acc = __builtin_amdgcn_mfma_f32_16x16x32_bf16(af, bf, acc, 0, 0, 0);
        }
        float* pp = s_part + kh*(16*PS);
        #pragma unroll
        for (int r = 0; r < 4; r++)
            pp[(q*4+r)*PS + ct*16 + nlane] = acc[r];
    }
    __syncthreads();
    // reduce K-halves, lrelu, store bf16 x2
    for (int i = tid; i < 1024; i += 512) {
        const int pt = i >> 6, c = i & 63;
        const float v = s_part[pt*PS + c] + s_part[16*PS + pt*PS + c];
        s_x2bf[pt*XS + c] = bfr(lrelu(v));
    }
    __syncthreads();

    // phase 3: out = lrelu([x2|feat] @ [W2;Ws]). wave w -> cols [16w,16w+16).
    {
        fx4 acc0 = {0.f,0.f,0.f,0.f};
        const short* b0r = &WcatT[(size_t)(w*16 + nlane)*KC];
        const short* xrow = &s_x2bf[nlane*XS];
        const short* frow = &s_featbf[nlane*FS];
        #pragma unroll
        for (int t = 0; t < KC/32; t++) {
            const int k0 = t*32 + q*8;
            const short* src = (t < 2) ? &xrow[k0] : &frow[k0 - 64];
            const bf16x8 af = *(const bf16x8*)src;
            const bf16x8 b0 = *(const bf16x8*)&b0r[k0];
            acc0 = __builtin_amdgcn_mfma_f32_16x16x32_bf16(af, b0, acc0, 0, 0, 0);
        }
        #pragma unroll
        for (int r = 0; r < 4; r++)
            out[(size_t)(pbase + q*4 + r)*128 + w*16 + nlane] = lrelu(acc0[r]);
    }
}

// ---------------------------------------------------------------------------
__global__ __launch_bounds__(256) void k_vlad_a(
    const float* __restrict__ f, const float* __restrict__ wa,
    const int* __restrict__ m, float* __restrict__ a, float* __restrict__ sumA)
{
    __shared__ __align__(16) float s_fT[128*36 + 8];
    __shared__ float s_m[32];
    const int tid = threadIdx.x;
    const int pbase = blockIdx.x * 32;
    const int b = pbase >> 11;
    for (int i = tid; i < 32*128; i += 256) {
        const int p = i >> 7, j = i & 127;
        s_fT[j*36 + p] = f[(size_t)pbase*128 + i];
    }
    if (tid < 32) s_m[tid] = (m[pbase + tid] != 0) ? 0.f : 1.f;
    __syncthreads();
    const int w = tid >> 6, kc = tid & 63;
    const int pb = w * 8;
    float acc[8] = {0.f,0.f,0.f,0.f,0.f,0.f,0.f,0.f};
    for (int j = 0; j < 128; j++) {
        const float wv = wa[j*64 + kc];
        const float4 f0 = *(const float4*)&s_fT[j*36 + pb];
        const float4 f1 = *(const float4*)&s_fT[j*36 + pb + 4];
        acc[0] = fmaf(f0.x, wv, acc[0]); acc[1] = fmaf(f0.y, wv, acc[1]);
        acc[2] = fmaf(f0.z, wv, acc[2]); acc[3] = fmaf(f0.w, wv, acc[3]);
        acc[4] = fmaf(f1.x, wv, acc[4]); acc[5] = fmaf(f1.y, wv, acc[5]);
        acc[6] = fmaf(f1.z, wv, acc[6]); acc[7] = fmaf(f1.w, wv, acc[7]);
    }
    float part = 0.f;
    #pragma unroll
    for (int pl = 0; pl < 8; pl++) {
        float mx = acc[pl];
        #pragma unroll
        for (int off = 32; off > 0; off >>= 1) mx = fmaxf(mx, __shfl_xor(mx, off, 64));
        const float e = expf(acc[pl] - mx);
        float se = e;
        #pragma unroll
        for (int off = 32; off > 0; off >>= 1) se += __shfl_xor(se, off, 64);
        const float av = (e / se) * s_m[pb + pl];
        a[(size_t)(pbase + pb + pl)*64 + kc] = av;
        part += av;
    }
    atomicAdd(&sumA[b*64 + kc], part);
}

// ---------------------------------------------------------------------------
__global__ __launch_bounds__(256) void k_vlad_acc(
    const float* __restrict__ a, const float* __restrict__ f,
    float* __restrict__ vpart)
{
    __shared__ __align__(16) float s_a[32*64];
    __shared__ __align__(16) float s_f[32*128];
    const int b  = blockIdx.x >> 4;
    const int ch = blockIdx.x & 15;
    const int n0 = ch * (N / VCH);
    const int tid = threadIdx.x;
    const int kc0 = (tid >> 5) * 8;
    const int d0  = (tid & 31) * 4;
    float acc[8][4];
    #pragma unroll
    for (int i = 0; i < 8; i++)
        #pragma unroll
        for (int j = 0; j < 4; j++) acc[i][j] = 0.f;
    for (int t = 0; t < N/VCH; t += 32) {
        __syncthreads();
        const size_t base = (size_t)(b*N + n0 + t);
        for (int i = tid; i < 32*64; i += 256)  s_a[i] = a[(base << 6) + i];
        for (int i = tid; i < 32*128; i += 256) s_f[i] = f[(base << 7) + i];
        __syncthreads();
        for (int n = 0; n < 32; n++) {
            const float4 a0 = *(const float4*)&s_a[n*64 + kc0];
            const float4 a1 = *(const float4*)&s_a[n*64 + kc0 + 4];
            const float4 fv = *(const float4*)&s_f[n*128 + d0];
            const float av[8] = {a0.x,a0.y,a0.z,a0.w,a1.x,a1.y,a1.z,a1.w};
            const float fw[4] = {fv.x,fv.y,fv.z,fv.w};
            #pragma unroll
            for (int i = 0; i < 8; i++)
                #pragma unroll
                for (int j = 0; j < 4; j++) acc[i][j] = fmaf(av[i], fw[j], acc[i][j]);
        }
    }
    float* vp = vpart + ((size_t)ch*B + b)*8192;
    #pragma unroll
    for (int i = 0; i < 8; i++)
        #pragma unroll
        for (int j = 0; j < 4; j++) vp[(kc0+i)*128 + d0 + j] = acc[i][j];
}

// ---------------------------------------------------------------------------
__global__ __launch_bounds__(128) void k_vlad_norm(
    const float* __restrict__ vpart, const float* __restrict__ sumA,
    const float* __restrict__ centers, float* __restrict__ v)
{
    const int b = blockIdx.x >> 6, kc = blockIdx.x & 63, d = threadIdx.x;
    float acc = 0.f;
    #pragma unroll
    for (int c = 0; c < VCH; c++)
        acc += vpart[((size_t)c*B + b)*8192 + kc*128 + d];
    const float vv = acc - sumA[b*64 + kc] * centers[kc*128 + d];
    float s2 = vv*vv;
    #pragma unroll
    for (int off = 32; off > 0; off >>= 1) s2 += __shfl_xor(s2, off, 64);
    __shared__ float red[2];
    if ((d & 63) == 0) red[d >> 6] = s2;
    __syncthreads();
    const float tot = red[0] + red[1];
    v[((size_t)b*64 + kc)*128 + d] = vv / (sqrtf(tot) + 1e-8f);
}

__global__ __launch_bounds__(256) void k_vnorm(
    const float* __restrict__ v, float* __restrict__ scale)
{
    const int b = blockIdx.x;
    float s = 0.f;
    for (int i = threadIdx.x; i < 8192; i += 256) { const float t = v[(size_t)b*8192 + i]; s = fmaf(t, t, s); }
    #pragma unroll
    for (int off = 32; off > 0; off >>= 1) s += __shfl_xor(s, off, 64);
    __shared__ float red[4];
    if ((threadIdx.x & 63) == 0) red[threadIdx.x >> 6] = s;
    __syncthreads();
    if (threadIdx.x == 0) {
        const float tot = red[0] + red[1] + red[2] + red[3];
        scale[b] = 1.f / (sqrtf(tot) + 1e-8f);
    }
}

__global__ __launch_bounds__(256) void k_zero(float* __restrict__ p, int n)
{
    const int i = blockIdx.x * 256 + threadIdx.x;
    if (i < n) p[i] = 0.f;
}

__global__ __launch_bounds__(256) void k_proj(
    const float* __restrict__ v, const float* __restrict__ scale,
    const float* __restrict__ proj, float* __restrict__ outacc)
{
    __shared__ __align__(16) float s_v[8*256];
    __shared__ float s_sc[8];
    const int jc = blockIdx.x, o = threadIdx.x;
    const int j0 = jc * 256;
    for (int i = o; i < 8*256; i += 256) {
        const int bb = i >> 8, jj = i & 255;
        s_v[i] = v[(size_t)bb*8192 + j0 + jj];
    }
    if (o < 8) s_sc[o] = scale[o];
    __syncthreads();
    float acc[8] = {0.f,0.f,0.f,0.f,0.f,0.f,0.f,0.f};
    for (int jj = 0; jj < 256; jj += 4) {
        float pv[4];
        #pragma unroll
        for (int q = 0; q < 4; q++) pv[q] = proj[(size_t)(j0+jj+q)*256 + o];
        #pragma unroll
        for (int bb = 0; bb < 8; bb++) {
            const float4 vv = *(const float4*)&s_v[bb*256 + jj];
            acc[bb] = fmaf(vv.x, pv[0], acc[bb]);
            acc[bb] = fmaf(vv.y, pv[1], acc[bb]);
            acc[bb] = fmaf(vv.z, pv[2], acc[bb]);
            acc[bb] = fmaf(vv.w, pv[3], acc[bb]);
        }
    }
    #pragma unroll
    for (int bb = 0; bb < 8; bb++) atomicAdd(&outacc[bb*256 + o], acc[bb] * s_sc[bb]);
}

__global__ __launch_bounds__(256) void k_outnorm(
    const float* __restrict__ outacc, float* __restrict__ out)
{
    const int b = blockIdx.x, o = threadIdx.x;
    const float val = outacc[b*256 + o];
    float s = val*val;
    #pragma unroll
    for (int off = 32; off > 0; off >>= 1) s += __shfl_xor(s, off, 64);
    __shared__ float red[4];
    if ((o & 63) == 0) red[o >> 6] = s;
    __syncthreads();
    const float tot = red[0] + red[1] + red[2] + red[3];
    out[b*256 + o] = val / (sqrtf(tot) + 1e-12f);
}

// ---------------------------------------------------------------------------
extern "C" void kernel_launch(void* const* d_in, const int* in_sizes, int n_in,
                              void* d_out, int out_size, void* d_ws, size_t ws_size,
                              hipStream_t stream)
{
    (void)in_sizes; (void)n_in; (void)out_size; (void)ws_size;
    const float* x     = (const float*)d_in[0];
    const int*   m     = (const int*)  d_in[1];
    const float* pn_w1 = (const float*)d_in[2];
    const float* pn_b1 = (const float*)d_in[3];
    const float* pn_w2 = (const float*)d_in[4];
    const float* pn_b2 = (const float*)d_in[5];
    const float* kp    = (const float*)d_in[6];
    const float* bw1[3] = {(const float*)d_in[7],  (const float*)d_in[11], (const float*)d_in[15]};
    const float* bwk[3] = {(const float*)d_in[8],  (const float*)d_in[12], (const float*)d_in[16]};
    const float* bw2[3] = {(const float*)d_in[9],  (const float*)d_in[13], (const float*)d_in[17]};
    const float* bws[3] = {(const float*)d_in[10], (const float*)d_in[14], (const float*)d_in[18]};
    const float* vlad_wa      = (const float*)d_in[19];
    const float* vlad_centers = (const float*)d_in[20];
    const float* vlad_proj    = (const float*)d_in[21];
    float* out = (float*)d_out;

    char* ws = (char*)d_ws;
    size_t off = 0;
    auto alloc = [&](size_t bytes) -> void* {
        void* p = ws + off;
        off = (off + bytes + 255) & ~(size_t)255;
        return p;
    };
    float4* coords4 = (float4*)alloc((size_t)BN*16);
    float*  feat0   = (float*)alloc((size_t)BN*64*4);
    int*    idxb    = (int*)  alloc((size_t)BN*KNBR*4);
    float*  x1b     = (float*)alloc((size_t)BN*64*4);     // aliased by vpart later
    float*  fA      = (float*)alloc((size_t)BN*128*4);
    float*  fB      = (float*)alloc((size_t)BN*128*4);
    float*  abuf    = (float*)alloc((size_t)BN*64*4);
    float*  vbuf    = (float*)alloc((size_t)B*8192*4);
    float*  scaleb  = (float*)alloc((size_t)B*4);
    float*  sumA    = (float*)alloc((size_t)B*64*4);
    float*  outacc  = (float*)alloc((size_t)B*256*4);
    int*    cntb    = (int*)  alloc((size_t)B*4);
    int*    compact = (int*)  alloc((size_t)BN*4);
    short*  wkT[3]  = {(short*)alloc(64*960*2), (short*)alloc(64*960*2), (short*)alloc(64*960*2)};
    short*  catT[3] = {(short*)alloc(128*192*2), (short*)alloc(128*192*2), (short*)alloc(128*192*2)};
    float*  vpart   = x1b;

    k_prep<<<(3*61440 + 16384 + 2*24576 + 255)/256, 256, 0, stream>>>(
        bwk[0], bwk[1], bwk[2], bw2[0], bws[0], bw2[1], bws[1], bw2[2], bws[2],
        wkT[0], wkT[1], wkT[2], catT[0], catT[1], catT[2]);

    k_zero<<<(B*64 + B*256 + B + 255)/256, 256, 0, stream>>>(sumA, B*64 + B*256 + B);
    k_compact<<<BN/256, 256, 0, stream>>>(m, compact, cntb, idxb);
    k_pointnet<<<BN/32, 256, 0, stream>>>(x, m, pn_w1, pn_b1, pn_w2, pn_b2, feat0, coords4);
    k_knn<<<B*512, 256, 0, stream>>>(coords4, compact, cntb, idxb);

    k_unary1<64> <<<BN/32, 256, 0, stream>>>(feat0, bw1[0], x1b);
    k_kpconv<64> <<<BN/16, 512, 0, stream>>>(x1b, coords4, kp, idxb, feat0, wkT[0], catT[0], fA);
    k_unary1<128><<<BN/32, 256, 0, stream>>>(fA, bw1[1], x1b);
    k_kpconv<128><<<BN/16, 512, 0, stream>>>(x1b, coords4, kp, idxb, fA, wkT[1], catT[1], fB);
    k_unary1<128><<<BN/32, 256, 0, stream>>>(fB, bw1[2], x1b);
    k_kpconv<128><<<BN/16, 512, 0, stream>>>(x1b, coords4, kp, idxb, fB, wkT[2], catT[2], fA);

    k_vlad_a<<<BN/32, 256, 0, stream>>>(fA, vlad_wa, m, abuf, sumA);
    k_vlad_acc<<<B*VCH, 256, 0, stream>>>(abuf, fA, vpart);
    k_vlad_norm<<<B*64, 128, 0, stream>>>(vpart, sumA, vlad_centers, vbuf);
    k_vnorm<<<B, 256, 0, stream>>>(vbuf, scaleb);
    k_proj<<<32, 256, 0, stream>>>(vbuf, scaleb, vlad_proj, outacc);
    k_outnorm<<<B, 256, 0, stream>>>(outacc, out);
}

// Round 15
// 371.263 us; speedup vs baseline: 1.5946x; 1.0570x over previous
//
#include <hip/hip_runtime.h>
#include <hip/hip_bf16.h>

#define B 8
#define N 2048
#define BN (B*N)
#define KNBR 32
#define NKP 15
#define VCH 16   // n-chunks per batch in VLAD accumulation

__device__ __forceinline__ float lrelu(float x){ return x > 0.f ? x : 0.1f*x; }
__device__ __forceinline__ unsigned umin_(unsigned a, unsigned b){ return __builtin_elementwise_min(a, b); }
__device__ __forceinline__ unsigned umax_(unsigned a, unsigned b){ return __builtin_elementwise_max(a, b); }

// MFMA fragment types (per guide: short8 = 8 bf16 = 4 VGPRs)
typedef __attribute__((ext_vector_type(8))) short bf16x8;
typedef __attribute__((ext_vector_type(4))) float fx4;

__device__ __forceinline__ short bfr(float f){
    union { __hip_bfloat16 h; short s; } u;
    u.h = __float2bfloat16(f);
    return u.s;
}
__device__ __forceinline__ unsigned pk2(float a, float b){
    return ((unsigned)(unsigned short)bfr(b) << 16) | (unsigned)(unsigned short)bfr(a);
}

// ---------------------------------------------------------------------------
// Fused weight prep: 3x wkT + 3x catT + 2x w1T (for kpconv phase-4 fusion).
__global__ __launch_bounds__(256) void k_prep(
    const float* __restrict__ wk0, const float* __restrict__ wk1, const float* __restrict__ wk2,
    const float* __restrict__ w20, const float* __restrict__ ws0,
    const float* __restrict__ w21, const float* __restrict__ ws1,
    const float* __restrict__ w22, const float* __restrict__ ws2,
    const float* __restrict__ w1_1, const float* __restrict__ w1_2,
    short* __restrict__ wkT0, short* __restrict__ wkT1, short* __restrict__ wkT2,
    short* __restrict__ cat0, short* __restrict__ cat1, short* __restrict__ cat2,
    short* __restrict__ w1T1, short* __restrict__ w1T2)
{
    const int i = blockIdx.x * 256 + threadIdx.x;
    if (i < 3*61440) {
        const int l = i / 61440, r = i % 61440;
        const int n = r / 960, k = r % 960;
        const float* wk = (l == 0) ? wk0 : (l == 1) ? wk1 : wk2;
        short* dst = (l == 0) ? wkT0 : (l == 1) ? wkT1 : wkT2;
        dst[r] = bfr(wk[k*64 + n]);
    } else {
        int j = i - 3*61440;
        if (j < 16384) {
            const int n = j / 128, k = j % 128;
            cat0[j] = bfr(k < 64 ? w20[k*128 + n] : ws0[(k-64)*128 + n]);
        } else if (j < 16384 + 24576) {
            j -= 16384;
            const int n = j / 192, k = j % 192;
            cat1[j] = bfr(k < 64 ? w21[k*128 + n] : ws1[(k-64)*128 + n]);
        } else if (j < 16384 + 49152) {
            j -= 16384 + 24576;
            const int n = j / 192, k = j % 192;
            cat2[j] = bfr(k < 64 ? w22[k*128 + n] : ws2[(k-64)*128 + n]);
        } else if (j < 16384 + 49152 + 8192) {
            j -= 16384 + 49152;
            const int n = j / 128, k = j % 128;
            w1T1[j] = bfr(w1_1[k*64 + n]);
        } else if (j < 16384 + 49152 + 16384) {
            j -= 16384 + 49152 + 8192;
            const int n = j / 128, k = j % 128;
            w1T2[j] = bfr(w1_2[k*64 + n]);
        }
    }
}

// ---------------------------------------------------------------------------
// Compaction with wave-aggregated atomics (round-10 verified).
__global__ __launch_bounds__(256) void k_compact(
    const int* __restrict__ m, int* __restrict__ compact, int* __restrict__ cnt,
    int* __restrict__ idx)
{
    const int p = blockIdx.x * 256 + threadIdx.x;
    const int b = p >> 11, n = p & (N-1);
    const int lane = threadIdx.x & 63;
    const bool unm = (m[p] == 0);
    const unsigned long long mask = __ballot(unm);
    int base = 0;
    if (lane == 0) base = atomicAdd(&cnt[b], __popcll(mask));
    base = __shfl(base, 0, 64);
    if (unm) {
        const int pos = base + __popcll(mask & ((1ull << lane) - 1ull));
        compact[b*N + pos] = n;
    } else {
        #pragma unroll
        for (int k = 0; k < KNBR; k++) idx[(size_t)p*KNBR + k] = k;
    }
}

// ---------------------------------------------------------------------------
// PointNet (round-5 verified shape).
__global__ __launch_bounds__(256) void k_pointnet(
    const float* __restrict__ x, const int* __restrict__ m,
    const float* __restrict__ w1, const float* __restrict__ b1,
    const float* __restrict__ w2, const float* __restrict__ b2,
    float* __restrict__ feat, float4* __restrict__ coords4)
{
    __shared__ float s_x[32][3];
    __shared__ __align__(16) float s_hT[64*40];
    const int tid = threadIdx.x;
    const int pbase = blockIdx.x * 32;
    if (tid < 32) {
        const int p = pbase + tid;
        const float x0 = x[p*3+0], x1v = x[p*3+1], x2v = x[p*3+2];
        s_x[tid][0] = x0; s_x[tid][1] = x1v; s_x[tid][2] = x2v;
        const bool mm = (m[p] != 0);
        const float cx = mm ? 1e6f : x0, cy = mm ? 1e6f : x1v, cz = mm ? 1e6f : x2v;
        coords4[p] = make_float4(cx, cy, cz, cx*cx + cy*cy + cz*cz);
    }
    __syncthreads();
    const int w = tid >> 6, c = tid & 63;
    const int pb = w * 8;
    {
        const float w10 = w1[c], w11 = w1[64+c], w12 = w1[128+c], bb = b1[c];
        #pragma unroll
        for (int pl = 0; pl < 8; pl++) {
            float s = bb;
            s = fmaf(s_x[pb+pl][0], w10, s);
            s = fmaf(s_x[pb+pl][1], w11, s);
            s = fmaf(s_x[pb+pl][2], w12, s);
            s_hT[c*40 + pb + pl] = fmaxf(s, 0.f);
        }
    }
    {
        float acc[8];
        const float bb = b2[c];
        #pragma unroll
        for (int pl = 0; pl < 8; pl++) acc[pl] = bb;
        for (int j = 0; j < 64; j++) {
            const float wv = w2[j*64 + c];
            const float4 h0 = *(const float4*)&s_hT[j*40 + pb];
            const float4 h1 = *(const float4*)&s_hT[j*40 + pb + 4];
            acc[0] = fmaf(h0.x, wv, acc[0]); acc[1] = fmaf(h0.y, wv, acc[1]);
            acc[2] = fmaf(h0.z, wv, acc[2]); acc[3] = fmaf(h0.w, wv, acc[3]);
            acc[4] = fmaf(h1.x, wv, acc[4]); acc[5] = fmaf(h1.y, wv, acc[5]);
            acc[6] = fmaf(h1.z, wv, acc[6]); acc[7] = fmaf(h1.w, wv, acc[7]);
        }
        #pragma unroll
        for (int pl = 0; pl < 8; pl++)
            feat[(size_t)(pbase + pb + pl)*64 + c] = fmaxf(acc[pl], 0.f);
    }
}

// ---------------------------------------------------------------------------
// KNN — round-11 measured-best config (256 threads, 4 waves).
__global__ __launch_bounds__(256, 2) void k_knn(
    const float4* __restrict__ c4, const int* __restrict__ compact,
    const int* __restrict__ cnt, int* __restrict__ idx)
{
    const int b = blockIdx.x >> 9;
    const int slot0 = (blockIdx.x & 511) * 4;
    const int cn = cnt[b];
    if (slot0 >= cn) return;
    __shared__ float4 s_c[N];
    const int tid = threadIdx.x;
    const int w = tid >> 6, lane = tid & 63;
    for (int i = tid; i < N; i += 256) s_c[i] = c4[(size_t)b*N + i];
    __syncthreads();
    const int slot = slot0 + w;
    const bool active = slot < cn;
    const int n = active ? compact[b*N + slot] : 0;
    const float4 me = s_c[n];

    unsigned A[32];
    #pragma unroll
    for (int j = 0; j < 32; j++) {
        const float4 s = s_c[j*64 + lane];
        float d2 = me.w + s.w - 2.f*(me.x*s.x + me.y*s.y + me.z*s.z);
        d2 = fmaxf(d2, 0.f);
        A[j] = (__float_as_uint(d2) & 0xFFFFF800u) | (unsigned)(j*64 + lane);
    }
    #pragma unroll
    for (int k = 2; k <= 32; k <<= 1) {
        #pragma unroll
        for (int j = k >> 1; j > 0; j >>= 1) {
            #pragma unroll
            for (int i = 0; i < 32; i++) {
                const int l = i ^ j;
                if (l > i) {
                    const unsigned lo = umin_(A[i], A[l]);
                    const unsigned hi = umax_(A[i], A[l]);
                    const bool up = ((i & k) == 0);
                    A[i] = up ? lo : hi;
                    A[l] = up ? hi : lo;
                }
            }
        }
    }
    #pragma unroll
    for (int r = 0; r < 6; r++) {
        const int mask = 1 << r;
        #pragma unroll
        for (int i = 0; i < 16; i++) {
            const unsigned t1 = (unsigned)__shfl_xor((int)A[31-i], mask, 64);
            const unsigned t2 = (unsigned)__shfl_xor((int)A[i],    mask, 64);
            A[i]    = umin_(A[i],    t1);
            A[31-i] = umin_(A[31-i], t2);
        }
        if (r < 5) {
            #pragma unroll
            for (int j = 16; j > 0; j >>= 1) {
                #pragma unroll
                for (int i = 0; i < 32; i++) {
                    const int l = i ^ j;
                    if (l > i) {
                        const unsigned lo = umin_(A[i], A[l]);
                        A[l] = umax_(A[i], A[l]);
                        A[i] = lo;
                    }
                }
            }
        }
    }
    #pragma unroll
    for (int s = 16; s >= 1; s >>= 1) {
        #pragma unroll
        for (int i = 0; i < s; i++)
            A[i] = (lane & s) ? A[i+s] : A[i];
    }
    if (active && lane < 32)
        idx[(size_t)(b*N + n)*KNBR + lane] = (int)(A[0] & 0x7FFu);
}

// ---------------------------------------------------------------------------
// x1 = lrelu(feat @ W1) — only used for layer 0 (feat0 -> x1).
template<int CIN>
__global__ __launch_bounds__(256) void k_unary1(
    const float* __restrict__ feat, const float* __restrict__ w1,
    float* __restrict__ x1)
{
    __shared__ __align__(16) float s_fT[128*36 + 8];
    const int tid = threadIdx.x;
    const int pbase = blockIdx.x * 32;
    for (int i = tid; i < 32*CIN; i += 256) {
        const int p = i / CIN, j = i % CIN;
        s_fT[j*36 + p] = feat[(size_t)pbase*CIN + i];
    }
    __syncthreads();
    const int w = tid >> 6, c = tid & 63;
    const int pb = w * 8;
    float acc[8] = {0.f,0.f,0.f,0.f,0.f,0.f,0.f,0.f};
    for (int j = 0; j < CIN; j++) {
        const float wv = w1[j*64 + c];
        const float4 f0 = *(const float4*)&s_fT[j*36 + pb];
        const float4 f1 = *(const float4*)&s_fT[j*36 + pb + 4];
        acc[0] = fmaf(f0.x, wv, acc[0]); acc[1] = fmaf(f0.y, wv, acc[1]);
        acc[2] = fmaf(f0.z, wv, acc[2]); acc[3] = fmaf(f0.w, wv, acc[3]);
        acc[4] = fmaf(f1.x, wv, acc[4]); acc[5] = fmaf(f1.y, wv, acc[5]);
        acc[6] = fmaf(f1.z, wv, acc[6]); acc[7] = fmaf(f1.w, wv, acc[7]);
    }
    #pragma unroll
    for (int pl = 0; pl < 8; pl++)
        x1[(size_t)(pbase + pb + pl)*64 + c] = lrelu(acc[pl]);
}

// ---------------------------------------------------------------------------
// KPConv, 16 pts/block, 512 threads, all-MFMA (round-14 verified), plus
// FUSED phase 4 (when FUSE): next layer's x1 = lrelu(out @ W1) computed
// in-block from the phase-3 accumulators (out is fully block-resident) —
// eliminates the standalone k_unary1<128> dispatch + HBM round-trip.
template<int CIN, bool FUSE>
__global__ __launch_bounds__(512) void k_kpconv(
    const float* __restrict__ x1, const float4* __restrict__ c4,
    const float* __restrict__ kp,
    const int* __restrict__ idx, const float* __restrict__ feat_in,
    const short* __restrict__ WkT, const short* __restrict__ WcatT,
    const short* __restrict__ W1T, float* __restrict__ x1out,
    float* __restrict__ out)
{
    constexpr int KC = 64 + CIN;   // phase-3 K extent
    constexpr int AS = 976;        // aggT row stride (shorts)
    constexpr int XS = 72;         // x2 row stride (shorts)
    constexpr int FS = CIN + 8;    // feat row stride (shorts)
    constexpr int PS = 65;         // partial row stride (floats)
    constexpr int FOS = 136;       // fused fout row stride (shorts)
    __shared__ __align__(16) short s_aggT[16*AS];      // 31232 B
    __shared__ __align__(16) unsigned s_un[11264];     // 45056 B union region
    __shared__ int   s_idx[512];
    __shared__ float skp[48];

    const int tid   = threadIdx.x;
    const int pbase = blockIdx.x * 16;
    const int brow  = pbase & ~(N-1);
    const int w = tid >> 6, lane = tid & 63;

    if (tid < NKP*3) skp[tid] = kp[tid];
    s_idx[tid] = idx[(size_t)pbase*KNBR + tid];
    __syncthreads();

    // ---- phase 1: wave w -> points 2w, 2w+1 (per-wave, no barriers) ----
    unsigned* xg  = s_un + w*1408;                    // [64 ch][18 dwords]
    short*    wbf = (short*)(s_un + w*1408 + 1152);   // [16 kp][32 nbr]

    for (int sub = 0; sub < 2; sub++) {
        const int pl = w*2 + sub;
        {
            const int k = lane & 31, h = lane >> 5;
            const float4 cp = c4[pbase + pl];
            const float4 cn = c4[brow + s_idx[pl*KNBR + k]];
            const float dx = cn.x - cp.x, dy = cn.y - cp.y, dz = cn.z - cp.z;
            #pragma unroll
            for (int j = 0; j < 8; j++) {
                const int kpi = h*8 + j;
                if (kpi < NKP) {
                    const float ex = dx - skp[kpi*3], ey = dy - skp[kpi*3+1], ez = dz - skp[kpi*3+2];
                    const float dist = sqrtf(ex*ex + ey*ey + ez*ez);
                    wbf[kpi*32 + k] = bfr(fmaxf(0.f, 1.f - dist*2.f));
                }
            }
        }
        {
            float g[KNBR];
            #pragma unroll
            for (int k = 0; k < KNBR; k++)
                g[k] = x1[(size_t)(brow + s_idx[pl*KNBR + k])*64 + lane];
            #pragma unroll
            for (int i = 0; i < 16; i++)
                xg[lane*18 + i] = pk2(g[2*i], g[2*i+1]);
        }
        {
            const int n = lane & 15, q = lane >> 4;
            const bf16x8 bw = *(const bf16x8*)&wbf[n*32 + q*8];
            #pragma unroll
            for (int t = 0; t < 4; t++) {
                union { unsigned u[4]; bf16x8 v; } af;
                const unsigned* src = &xg[(t*16 + n)*18 + q*4];
                af.u[0] = src[0]; af.u[1] = src[1]; af.u[2] = src[2]; af.u[3] = src[3];
                fx4 d = {0.f,0.f,0.f,0.f};
                d = __builtin_amdgcn_mfma_f32_16x16x32_bf16(af.v, bw, d, 0, 0, 0);
                if (n < NKP) {
                    const uint2 o = make_uint2(pk2(d[0], d[1]), pk2(d[2], d[3]));
                    *(uint2*)&s_aggT[pl*AS + n*64 + t*16 + q*4] = o;
                }
            }
        }
    }
    __syncthreads();   // phase-1 region dead; union re-partitioned:

    short* s_x2bf   = (short*)s_un;                        // [16][XS]
    short* s_featbf = (short*)s_un + 16*XS;                // [16][FS]
    float* s_part   = (float*)((char*)s_un + 6656);        // [2][16][PS]

    for (int i = tid; i < 16*CIN; i += 512) {
        const int p = i / CIN, j = i % CIN;
        s_featbf[p*FS + j] = bfr(feat_in[(size_t)pbase*CIN + i]);
    }

    const int nlane = lane & 15, q = lane >> 4;
    // phase 2: x2 = lrelu(agg @ Wk). wave w -> col-tile (w&3), K-half (w>>2).
    {
        const int ct = w & 3, kh = w >> 2;
        fx4 acc = {0.f,0.f,0.f,0.f};
        const short* arow = &s_aggT[nlane*AS + kh*480];
        const short* brw  = &WkT[(size_t)(ct*16 + nlane)*960 + kh*480];
        for (int t = 0; t < 15; t++) {
            const int k0 = t*32 + q*8;
            const bf16x8 af = *(const bf16x8*)&arow[k0];
            const bf16x8 bf = *(const bf16x8*)&brw[k0];
            acc = __builtin_amdgcn_mfma_f32_16x16x32_bf16(af, bf, acc, 0, 0, 0);
        }
        float* pp = s_part + kh*(16*PS);
        #pragma unroll
        for (int r = 0; r < 4; r++)
            pp[(q*4+r)*PS + ct*16 + nlane] = acc[r];
    }
    __syncthreads();
    for (int i = tid; i < 1024; i += 512) {
        const int pt = i >> 6, c = i & 63;
        const float v = s_part[pt*PS + c] + s_part[16*PS + pt*PS + c];
        s_x2bf[pt*XS + c] = bfr(lrelu(v));
    }
    __syncthreads();

    // phase 3: out = lrelu([x2|feat] @ [W2;Ws]). wave w -> cols [16w,16w+16).
    fx4 acc0 = {0.f,0.f,0.f,0.f};
    {
        const short* b0r = &WcatT[(size_t)(w*16 + nlane)*KC];
        const short* xrow = &s_x2bf[nlane*XS];
        const short* frow = &s_featbf[nlane*FS];
        #pragma unroll
        for (int t = 0; t < KC/32; t++) {
            const int k0 = t*32 + q*8;
            const short* src = (t < 2) ? &xrow[k0] : &frow[k0 - 64];
            const bf16x8 af = *(const bf16x8*)src;
            const bf16x8 b0 = *(const bf16x8*)&b0r[k0];
            acc0 = __builtin_amdgcn_mfma_f32_16x16x32_bf16(af, b0, acc0, 0, 0, 0);
        }
        #pragma unroll
        for (int r = 0; r < 4; r++)
            out[(size_t)(pbase + q*4 + r)*128 + w*16 + nlane] = lrelu(acc0[r]);
    }

    if (FUSE) {
        // phase 4: x1out = lrelu(out @ W1) for the NEXT layer, in-block.
        __syncthreads();   // all phase-3 LDS reads done; re-alias s_un
        short* s_fout = (short*)s_un;   // [16][FOS]
        #pragma unroll
        for (int r = 0; r < 4; r++)
            s_fout[(q*4 + r)*FOS + w*16 + nlane] = bfr(lrelu(acc0[r]));
        __syncthreads();
        if (w < 4) {
            fx4 acc = {0.f,0.f,0.f,0.f};
            const short* arow = &s_fout[nlane*FOS];
            const short* brw  = &W1T[(size_t)(w*16 + nlane)*128];
            #pragma unroll
            for (int t = 0; t < 4; t++) {
                const int k0 = t*32 + q*8;
                const bf16x8 af = *(const bf16x8*)&arow[k0];
                const bf16x8 bf = *(const bf16x8*)&brw[k0];
                acc = __builtin_amdgcn_mfma_f32_16x16x32_bf16(af, bf, acc, 0, 0, 0);
            }
            #pragma unroll
            for (int r = 0; r < 4; r++)
                x1out[(size_t)(pbase + q*4 + r)*64 + w*16 + nlane] = lrelu(acc[r]);
        }
    }
}

// ---------------------------------------------------------------------------
__global__ __launch_bounds__(256) void k_vlad_a(
    const float* __restrict__ f, const float* __restrict__ wa,
    const int* __restrict__ m, float* __restrict__ a, float* __restrict__ sumA)
{
    __shared__ __align__(16) float s_fT[128*36 + 8];
    __shared__ float s_m[32];
    const int tid = threadIdx.x;
    const int pbase = blockIdx.x * 32;
    const int b = pbase >> 11;
    for (int i = tid; i < 32*128; i += 256) {
        const int p = i >> 7, j = i & 127;
        s_fT[j*36 + p] = f[(size_t)pbase*128 + i];
    }
    if (tid < 32) s_m[tid] = (m[pbase + tid] != 0) ? 0.f : 1.f;
    __syncthreads();
    const int w = tid >> 6, kc = tid & 63;
    const int pb = w * 8;
    float acc[8] = {0.f,0.f,0.f,0.f,0.f,0.f,0.f,0.f};
    for (int j = 0; j < 128; j++) {
        const float wv = wa[j*64 + kc];
        const float4 f0 = *(const float4*)&s_fT[j*36 + pb];
        const float4 f1 = *(const float4*)&s_fT[j*36 + pb + 4];
        acc[0] = fmaf(f0.x, wv, acc[0]); acc[1] = fmaf(f0.y, wv, acc[1]);
        acc[2] = fmaf(f0.z, wv, acc[2]); acc[3] = fmaf(f0.w, wv, acc[3]);
        acc[4] = fmaf(f1.x, wv, acc[4]); acc[5] = fmaf(f1.y, wv, acc[5]);
        acc[6] = fmaf(f1.z, wv, acc[6]); acc[7] = fmaf(f1.w, wv, acc[7]);
    }
    float part = 0.f;
    #pragma unroll
    for (int pl = 0; pl < 8; pl++) {
        float mx = acc[pl];
        #pragma unroll
        for (int off = 32; off > 0; off >>= 1) mx = fmaxf(mx, __shfl_xor(mx, off, 64));
        const float e = expf(acc[pl] - mx);
        float se = e;
        #pragma unroll
        for (int off = 32; off > 0; off >>= 1) se += __shfl_xor(se, off, 64);
        const float av = (e / se) * s_m[pb + pl];
        a[(size_t)(pbase + pb + pl)*64 + kc] = av;
        part += av;
    }
    atomicAdd(&sumA[b*64 + kc], part);
}

// ---------------------------------------------------------------------------
__global__ __launch_bounds__(256) void k_vlad_acc(
    const float* __restrict__ a, const float* __restrict__ f,
    float* __restrict__ vpart)
{
    __shared__ __align__(16) float s_a[32*64];
    __shared__ __align__(16) float s_f[32*128];
    const int b  = blockIdx.x >> 4;
    const int ch = blockIdx.x & 15;
    const int n0 = ch * (N / VCH);
    const int tid = threadIdx.x;
    const int kc0 = (tid >> 5) * 8;
    const int d0  = (tid & 31) * 4;
    float acc[8][4];
    #pragma unroll
    for (int i = 0; i < 8; i++)
        #pragma unroll
        for (int j = 0; j < 4; j++) acc[i][j] = 0.f;
    for (int t = 0; t < N/VCH; t += 32) {
        __syncthreads();
        const size_t base = (size_t)(b*N + n0 + t);
        for (int i = tid; i < 32*64; i += 256)  s_a[i] = a[(base << 6) + i];
        for (int i = tid; i < 32*128; i += 256) s_f[i] = f[(base << 7) + i];
        __syncthreads();
        for (int n = 0; n < 32; n++) {
            const float4 a0 = *(const float4*)&s_a[n*64 + kc0];
            const float4 a1 = *(const float4*)&s_a[n*64 + kc0 + 4];
            const float4 fv = *(const float4*)&s_f[n*128 + d0];
            const float av[8] = {a0.x,a0.y,a0.z,a0.w,a1.x,a1.y,a1.z,a1.w};
            const float fw[4] = {fv.x,fv.y,fv.z,fv.w};
            #pragma unroll
            for (int i = 0; i < 8; i++)
                #pragma unroll
                for (int j = 0; j < 4; j++) acc[i][j] = fmaf(av[i], fw[j], acc[i][j]);
        }
    }
    float* vp = vpart + ((size_t)ch*B + b)*8192;
    #pragma unroll
    for (int i = 0; i < 8; i++)
        #pragma unroll
        for (int j = 0; j < 4; j++) vp[(kc0+i)*128 + d0 + j] = acc[i][j];
}

// ---------------------------------------------------------------------------
__global__ __launch_bounds__(128) void k_vlad_norm(
    const float* __restrict__ vpart, const float* __restrict__ sumA,
    const float* __restrict__ centers, float* __restrict__ v)
{
    const int b = blockIdx.x >> 6, kc = blockIdx.x & 63, d = threadIdx.x;
    float acc = 0.f;
    #pragma unroll
    for (int c = 0; c < VCH; c++)
        acc += vpart[((size_t)c*B + b)*8192 + kc*128 + d];
    const float vv = acc - sumA[b*64 + kc] * centers[kc*128 + d];
    float s2 = vv*vv;
    #pragma unroll
    for (int off = 32; off > 0; off >>= 1) s2 += __shfl_xor(s2, off, 64);
    __shared__ float red[2];
    if ((d & 63) == 0) red[d >> 6] = s2;
    __syncthreads();
    const float tot = red[0] + red[1];
    v[((size_t)b*64 + kc)*128 + d] = vv / (sqrtf(tot) + 1e-8f);
}

__global__ __launch_bounds__(256) void k_vnorm(
    const float* __restrict__ v, float* __restrict__ scale)
{
    const int b = blockIdx.x;
    float s = 0.f;
    for (int i = threadIdx.x; i < 8192; i += 256) { const float t = v[(size_t)b*8192 + i]; s = fmaf(t, t, s); }
    #pragma unroll
    for (int off = 32; off > 0; off >>= 1) s += __shfl_xor(s, off, 64);
    __shared__ float red[4];
    if ((threadIdx.x & 63) == 0) red[threadIdx.x >> 6] = s;
    __syncthreads();
    if (threadIdx.x == 0) {
        const float tot = red[0] + red[1] + red[2] + red[3];
        scale[b] = 1.f / (sqrtf(tot) + 1e-8f);
    }
}

__global__ __launch_bounds__(256) void k_zero(float* __restrict__ p, int n)
{
    const int i = blockIdx.x * 256 + threadIdx.x;
    if (i < n) p[i] = 0.f;
}

__global__ __launch_bounds__(256) void k_proj(
    const float* __restrict__ v, const float* __restrict__ scale,
    const float* __restrict__ proj, float* __restrict__ outacc)
{
    __shared__ __align__(16) float s_v[8*256];
    __shared__ float s_sc[8];
    const int jc = blockIdx.x, o = threadIdx.x;
    const int j0 = jc * 256;
    for (int i = o; i < 8*256; i += 256) {
        const int bb = i >> 8, jj = i & 255;
        s_v[i] = v[(size_t)bb*8192 + j0 + jj];
    }
    if (o < 8) s_sc[o] = scale[o];
    __syncthreads();
    float acc[8] = {0.f,0.f,0.f,0.f,0.f,0.f,0.f,0.f};
    for (int jj = 0; jj < 256; jj += 4) {
        float pv[4];
        #pragma unroll
        for (int q = 0; q < 4; q++) pv[q] = proj[(size_t)(j0+jj+q)*256 + o];
        #pragma unroll
        for (int bb = 0; bb < 8; bb++) {
            const float4 vv = *(const float4*)&s_v[bb*256 + jj];
            acc[bb] = fmaf(vv.x, pv[0], acc[bb]);
            acc[bb] = fmaf(vv.y, pv[1], acc[bb]);
            acc[bb] = fmaf(vv.z, pv[2], acc[bb]);
            acc[bb] = fmaf(vv.w, pv[3], acc[bb]);
        }
    }
    #pragma unroll
    for (int bb = 0; bb < 8; bb++) atomicAdd(&outacc[bb*256 + o], acc[bb] * s_sc[bb]);
}

__global__ __launch_bounds__(256) void k_outnorm(
    const float* __restrict__ outacc, float* __restrict__ out)
{
    const int b = blockIdx.x, o = threadIdx.x;
    const float val = outacc[b*256 + o];
    float s = val*val;
    #pragma unroll
    for (int off = 32; off > 0; off >>= 1) s += __shfl_xor(s, off, 64);
    __shared__ float red[4];
    if ((o & 63) == 0) red[o >> 6] = s;
    __syncthreads();
    const float tot = red[0] + red[1] + red[2] + red[3];
    out[b*256 + o] = val / (sqrtf(tot) + 1e-12f);
}

// ---------------------------------------------------------------------------
extern "C" void kernel_launch(void* const* d_in, const int* in_sizes, int n_in,
                              void* d_out, int out_size, void* d_ws, size_t ws_size,
                              hipStream_t stream)
{
    (void)in_sizes; (void)n_in; (void)out_size; (void)ws_size;
    const float* x     = (const float*)d_in[0];
    const int*   m     = (const int*)  d_in[1];
    const float* pn_w1 = (const float*)d_in[2];
    const float* pn_b1 = (const float*)d_in[3];
    const float* pn_w2 = (const float*)d_in[4];
    const float* pn_b2 = (const float*)d_in[5];
    const float* kp    = (const float*)d_in[6];
    const float* bw1[3] = {(const float*)d_in[7],  (const float*)d_in[11], (const float*)d_in[15]};
    const float* bwk[3] = {(const float*)d_in[8],  (const float*)d_in[12], (const float*)d_in[16]};
    const float* bw2[3] = {(const float*)d_in[9],  (const float*)d_in[13], (const float*)d_in[17]};
    const float* bws[3] = {(const float*)d_in[10], (const float*)d_in[14], (const float*)d_in[18]};
    const float* vlad_wa      = (const float*)d_in[19];
    const float* vlad_centers = (const float*)d_in[20];
    const float* vlad_proj    = (const float*)d_in[21];
    float* out = (float*)d_out;

    char* ws = (char*)d_ws;
    size_t off = 0;
    auto alloc = [&](size_t bytes) -> void* {
        void* p = ws + off;
        off = (off + bytes + 255) & ~(size_t)255;
        return p;
    };
    float4* coords4 = (float4*)alloc((size_t)BN*16);
    float*  feat0   = (float*)alloc((size_t)BN*64*4);
    int*    idxb    = (int*)  alloc((size_t)BN*KNBR*4);
    float*  x1b     = (float*)alloc((size_t)BN*64*4);     // aliased by vpart later
    float*  fA      = (float*)alloc((size_t)BN*128*4);
    float*  fB      = (float*)alloc((size_t)BN*128*4);
    float*  abuf    = (float*)alloc((size_t)BN*64*4);
    float*  vbuf    = (float*)alloc((size_t)B*8192*4);
    float*  scaleb  = (float*)alloc((size_t)B*4);
    float*  sumA    = (float*)alloc((size_t)B*64*4);
    float*  outacc  = (float*)alloc((size_t)B*256*4);
    int*    cntb    = (int*)  alloc((size_t)B*4);
    int*    compact = (int*)  alloc((size_t)BN*4);
    short*  wkT[3]  = {(short*)alloc(64*960*2), (short*)alloc(64*960*2), (short*)alloc(64*960*2)};
    short*  catT[3] = {(short*)alloc(128*192*2), (short*)alloc(128*192*2), (short*)alloc(128*192*2)};
    short*  w1T1    = (short*)alloc(64*128*2);
    short*  w1T2    = (short*)alloc(64*128*2);
    float*  vpart   = x1b;

    k_prep<<<(3*61440 + 16384 + 2*24576 + 2*8192 + 255)/256, 256, 0, stream>>>(
        bwk[0], bwk[1], bwk[2], bw2[0], bws[0], bw2[1], bws[1], bw2[2], bws[2],
        bw1[1], bw1[2],
        wkT[0], wkT[1], wkT[2], catT[0], catT[1], catT[2], w1T1, w1T2);

    k_zero<<<(B*64 + B*256 + B + 255)/256, 256, 0, stream>>>(sumA, B*64 + B*256 + B);
    k_compact<<<BN/256, 256, 0, stream>>>(m, compact, cntb, idxb);
    k_pointnet<<<BN/32, 256, 0, stream>>>(x, m, pn_w1, pn_b1, pn_w2, pn_b2, feat0, coords4);
    k_knn<<<B*512, 256, 0, stream>>>(coords4, compact, cntb, idxb);

    k_unary1<64> <<<BN/32, 256, 0, stream>>>(feat0, bw1[0], x1b);
    k_kpconv<64,true>  <<<BN/16, 512, 0, stream>>>(x1b, coords4, kp, idxb, feat0, wkT[0], catT[0], w1T1, x1b, fA);
    k_kpconv<128,true> <<<BN/16, 512, 0, stream>>>(x1b, coords4, kp, idxb, fA,    wkT[1], catT[1], w1T2, x1b, fB);
    k_kpconv<128,false><<<BN/16, 512, 0, stream>>>(x1b, coords4, kp, idxb, fB,    wkT[2], catT[2], nullptr, nullptr, fA);

    k_vlad_a<<<BN/32, 256, 0, stream>>>(fA, vlad_wa, m, abuf, sumA);
    k_vlad_acc<<<B*VCH, 256, 0, stream>>>(abuf, fA, vpart);
    k_vlad_norm<<<B*64, 128, 0, stream>>>(vpart, sumA, vlad_centers, vbuf);
    k_vnorm<<<B, 256, 0, stream>>>(vbuf, scaleb);
    k_proj<<<32, 256, 0, stream>>>(vbuf, scaleb, vlad_proj, outacc);
    k_outnorm<<<B, 256, 0, stream>>>(outacc, out);
}